// Round 5
// baseline (1295.553 us; speedup 1.0000x reference)
//
#include <hip/hip_runtime.h>

#define NB 8
#define NP 8192
#define SP 1024
#define KS 32
#define CD 64
#define MROWS (NB*SP*KS)
#define NCOPY 16

typedef float v2f __attribute__((ext_vector_type(2)));
typedef unsigned long long u64;

// one DPP max step on a u64 key: pure VALU, no LDS. ctrl is a template param because
// __builtin_amdgcn_update_dpp requires an immediate. old=src + bound_ctrl=false ->
// lanes with no valid source keep their own value (identity for max).
template <int CTRL>
__device__ __forceinline__ u64 dpp_max_step(u64 x) {
    int lo = (int)(unsigned)(x & 0xffffffffull);
    int hi = (int)(unsigned)(x >> 32);
    int slo = __builtin_amdgcn_update_dpp(lo, lo, CTRL, 0xf, 0xf, false);
    int shi = __builtin_amdgcn_update_dpp(hi, hi, CTRL, 0xf, 0xf, false);
    u64 y = ((u64)(unsigned)shi << 32) | (unsigned)slo;
    return x > y ? x : y;
}

// ---------------- pre-kernel: points transpose + weight prep + zero stats/ctl ----------------
// All of this is consumed by LATER kernels only -> kernel-boundary coherence (validated r0-r3).
__global__ __launch_bounds__(512) void k_pre(const float* __restrict__ points,
                                             float* __restrict__ pts_t,
                                             const float* __restrict__ w0,
                                             const float* __restrict__ w1,
                                             const float* __restrict__ w2,
                                             float* __restrict__ Wt0,
                                             float* __restrict__ Wt1,
                                             float* __restrict__ Wt2,
                                             float* __restrict__ stats,
                                             int* __restrict__ ctl)
{
    __shared__ float tile[64][65];
    const int blk = blockIdx.x;
    const int t = threadIdx.x;
    if (blk >= NB * (NP / 64)) {
        // weight prep: zero stats + ctl, transpose weights to [kk][c]
        for (int i = t; i < 8192; i += 512) stats[i] = 0.f;
        if (t < 64) ctl[t] = 0;
        for (int i = t; i < 64 * 67; i += 512) { int c = i / 67, kk = i % 67; Wt0[kk * 64 + c] = w0[i]; }
        for (int i = t; i < 64 * 64; i += 512) { int c = i >> 6, kk = i & 63; Wt1[kk * 64 + c] = w1[i]; }
        for (int i = t; i < 128 * 64; i += 512) { int c = i >> 6, kk = i & 63; Wt2[kk * 128 + c] = w2[i]; }
        return;
    }
    // points transpose (B,64,N) -> (B,N,64), 64x64 tile, 512 threads (r0-verbatim)
    const int b = blk >> 7;
    const int n0 = (blk & 127) << 6;
    const float* pb = points + (size_t)b * CD * NP;
    const int c = t & 63;
    const int dr = t >> 6;                 // 0..7
#pragma unroll
    for (int it = 0; it < 8; ++it) {
        int d = dr + it * 8;
        tile[d][c] = pb[(size_t)d * NP + n0 + c];
    }
    __syncthreads();
#pragma unroll
    for (int it = 0; it < 8; ++it) {
        int nn = dr + it * 8;
        pts_t[((size_t)b * NP + n0 + nn) * CD + c] = tile[c][nn];
    }
}

// ---------------- mega kernel: FPS producers (blocks 0..7) + ballquery/layer1 consumers ----------
// 256 blocks x 512 thr, 128.25KB static LDS -> exactly 1 block/CU on 256 CUs, all co-resident
// (empirically validated in r4: ran to completion, no hang).
// Coherence policy (r4 lesson): ALL intra-kernel cross-block data goes through device-scope
// RMW atomics ONLY (atomicExch to write, atomicAdd(p,0) to read) — the mechanism class already
// validated by the stats atomicAdd working in r0-r3. No agent-scope plain stores/loads.
// Producers: r0-verbatim FPS loop (941us certified). Every 32 iters the 32 capture-threads
// burst their centroids via atomicExch at iteration TOP (drained by that iteration's existing
// barrier, overlapped with the distance phase); t==2 bumps prog[b] one iteration later.
// Consumers: ticket queue of 2048 units (b, 4 centroids): spin on prog[b] (RMW read), RMW-read
// the 12 q-floats into LDS, then verbatim ballquery (waves 0-3, lists in LDS) + verbatim
// layer1 gather/GEMM/stats (t<256). pts_t/Wt0/bias0 come from k_pre across the boundary.
__global__ __launch_bounds__(512, 1) void k_mega(const float* __restrict__ xyz,
                                                 float* __restrict__ fps_pts,
                                                 float* __restrict__ out_nx,
                                                 const float* __restrict__ pts_t,
                                                 const float* __restrict__ Wt0,
                                                 const float* __restrict__ bias0,
                                                 float* __restrict__ h1,
                                                 float* __restrict__ sum0,
                                                 float* __restrict__ ssq0,
                                                 int* __restrict__ ctl)
{
#pragma clang fp contract(off)
    __shared__ __align__(16) unsigned char smem[131344];
    const int blk = blockIdx.x;
    const int t = threadIdx.x;
    const int lane = t & 63, wid = t >> 6;
    unsigned int* fpu = (unsigned int*)fps_pts;

    if (blk < NB) {
        // ---- FPS producer (r0-verbatim + RMW burst publish) ----
        float4* s_p = (float4*)smem;               // 128 KB xyz mirror
        u64 (*s_wk)[8] = (u64(*)[8])(smem + 131072);
        const int b = blk;
        const float* xb = xyz + (size_t)b * 3 * NP;
        v2f px[8], py[8], pz[8], dv[8];
#pragma unroll
        for (int j = 0; j < 8; ++j) {
            const int n0 = t + (2 * j) * 512, n1 = n0 + 512;
            px[j] = (v2f){xb[n0], xb[n1]};
            py[j] = (v2f){xb[NP + n0], xb[NP + n1]};
            pz[j] = (v2f){xb[2 * NP + n0], xb[2 * NP + n1]};
            dv[j] = (v2f){1e10f, 1e10f};
            s_p[n0] = make_float4(px[j].x, py[j].x, pz[j].x, 0.f);
            s_p[n1] = make_float4(px[j].y, py[j].y, pz[j].y, 0.f);
        }
        float cx = xb[0], cy = xb[NP], cz = xb[2 * NP];
        float hx0 = 0.f, hy0 = 0.f, hz0 = 0.f;     // captured centroid of iteration i == t
        float hx1 = 0.f, hy1 = 0.f, hz1 = 0.f;     // captured centroid of iteration i == t + 512
        __syncthreads();
        for (int i = 0; i < SP; ++i) {
            if (i == t)       { hx0 = cx; hy0 = cy; hz0 = cz; }
            if (i == t + 512) { hx1 = cx; hy1 = cy; hz1 = cz; }
            // RMW burst publish at iteration top: drain lands at THIS iteration's barrier,
            // overlapped with the distance phase. One burst per 32 iterations.
            if ((i & 31) == 31) {
                if (i < 512) {
                    if (t >= i - 31 && t <= i) {
                        unsigned int* dst = fpu + ((size_t)b * SP + t) * 3;
                        atomicExch(dst + 0, __float_as_uint(hx0));
                        atomicExch(dst + 1, __float_as_uint(hy0));
                        atomicExch(dst + 2, __float_as_uint(hz0));
                    }
                } else {
                    const int s = t + 512;
                    if (s >= i - 31 && s <= i) {
                        unsigned int* dst = fpu + ((size_t)b * SP + s) * 3;
                        atomicExch(dst + 0, __float_as_uint(hx1));
                        atomicExch(dst + 1, __float_as_uint(hy1));
                        atomicExch(dst + 2, __float_as_uint(hz1));
                    }
                }
            }
            // progress one iteration AFTER the burst (its stores drained at the prior barrier)
            if ((i & 31) == 0 && i != 0 && t == 2) atomicExch(&ctl[8 + b], i);
            // distance update + in-thread argmax (EXACT fp32: sub, mul, (x2+y2)+z2, min;
            // contract(off) forbids fma; ascending gid + strict > == first-index tie-break)
            float bv = -1.f; int bg = 0;
#pragma unroll
            for (int j = 0; j < 8; ++j) {
                v2f dx = px[j] - cx;
                v2f dy = py[j] - cy;
                v2f dz = pz[j] - cz;
                v2f d  = dx * dx + dy * dy;
                d = d + dz * dz;
                v2f dm = dv[j];
                dm.x = fminf(dm.x, d.x);
                dm.y = fminf(dm.y, d.y);
                dv[j] = dm;
                if (dm.x > bv) { bv = dm.x; bg = t + (2 * j) * 512; }
                if (dm.y > bv) { bv = dm.y; bg = t + (2 * j + 1) * 512; }
            }
            u64 bk = ((u64)__float_as_uint(bv) << 32) | (unsigned int)~bg;
            // per-wave DPP max ladder (VALU only); lane 63 ends with the wave max
            bk = dpp_max_step<0x111>(bk);          // row_shr:1
            bk = dpp_max_step<0x112>(bk);          // row_shr:2
            bk = dpp_max_step<0x114>(bk);          // row_shr:4
            bk = dpp_max_step<0x118>(bk);          // row_shr:8
            bk = dpp_max_step<0x142>(bk);          // row_bcast:15
            bk = dpp_max_step<0x143>(bk);          // row_bcast:31
            const int par = i & 1;
            if (lane == 63) s_wk[par][wid] = bk;   // plain overwrite, parity-dbuf'd
            __syncthreads();
            // every wave DPP-reduces the 8 leader keys (replicated twice per 16-lane row)
            u64 rk = s_wk[par][lane & 7];
            rk = dpp_max_step<0x111>(rk);
            rk = dpp_max_step<0x112>(rk);
            rk = dpp_max_step<0x114>(rk);
            rk = dpp_max_step<0x118>(rk);
            const int wg = ~__builtin_amdgcn_readlane((int)(unsigned)(rk & 0xffffffffull), 15);
            const float4 c = s_p[wg];              // uniform broadcast ds_read_b128
            cx = c.x; cy = c.y; cz = c.z;
            // safe without 2nd barrier: next write to s_wk[par] is 2 iters away, past the next barrier
        }
        // all published (last burst drained at i=1023's barrier)
        if (t == 2) atomicExch(&ctl[8 + b], SP);
        // deferred out_nx (output 0) stores — kernel-boundary coherence
        out_nx[(size_t)b * 3 * SP + 0 * SP + t] = hx0;
        out_nx[(size_t)b * 3 * SP + 1 * SP + t] = hy0;
        out_nx[(size_t)b * 3 * SP + 2 * SP + t] = hz0;
        out_nx[(size_t)b * 3 * SP + 0 * SP + t + 512] = hx1;
        out_nx[(size_t)b * 3 * SP + 1 * SP + t + 512] = hy1;
        out_nx[(size_t)b * 3 * SP + 2 * SP + t + 512] = hz1;
        return;
    }

    // ---- consumer blocks: units of (batch b, 4 centroids): ballquery + layer1 ----
    float* Ft    = (float*)smem;                   // [67*128] floats (34304 B)
    float* Ws    = (float*)(smem + 34304);         // [67*64]  floats (17152 B)
    int*   s_idx = (int*)(smem + 51456);           // [128]
    float* s_q   = (float*)(smem + 51968);         // [12]
    int*   s_tk  = (int*)(smem + 131328);
    int*   s_rdy = (int*)(smem + 131332);

    // stage Ws once (Wt0 from k_pre across the kernel boundary; Ws region never clobbered)
    for (int i = t; i < 67 * 64; i += 512) Ws[i] = Wt0[i];

    for (;;) {
        __syncthreads();
        if (t == 0) *s_tk = atomicAdd(&ctl[1], 1);
        __syncthreads();
        const int u = *s_tk;
        if (u >= 2048) break;
        const int b = u & 7, kq = u >> 3;
        const int need = 4 * kq + 4;
        const int g0 = b * SP + kq * 4;            // global group index base
        // spin on producer progress (RMW read — always coherent)
        for (;;) {
            if (t == 0) *s_rdy = (atomicAdd(&ctl[8 + b], 0) >= need);
            __syncthreads();
            const int ok = *s_rdy;
            __syncthreads();
            if (ok) break;
            __builtin_amdgcn_s_sleep(32);
        }
        // RMW-read the 4 query centroids (12 floats) into LDS
        if (t < 12) {
            unsigned int uv = atomicAdd(fpu + (size_t)g0 * 3 + t, 0u);
            s_q[t] = __uint_as_float(uv);
        }
        __syncthreads();
        // ballquery: waves 0..3 handle one query each (verbatim k_ballquery math)
        if (wid < 4) {
            const float qx = s_q[wid * 3 + 0];
            const float qy = s_q[wid * 3 + 1];
            const float qz = s_q[wid * 3 + 2];
            const float* xbq = xyz + (size_t)b * 3 * NP;
            int* list = s_idx + wid * KS;
            const float r2 = (float)(0.2 * 0.2);   // 0.039999999f — matches python double->f32
            int found = 0;
            for (int base2 = 0; base2 < NP && found < KS; base2 += 64) {
                int n = base2 + lane;
                float dx = __fsub_rn(qx, xbq[n]);
                float dy = __fsub_rn(qy, xbq[NP + n]);
                float dz = __fsub_rn(qz, xbq[2 * NP + n]);
                float d = __fadd_rn(__fadd_rn(__fmul_rn(dx, dx), __fmul_rn(dy, dy)), __fmul_rn(dz, dz));
                bool in = !(d > r2);
                unsigned long long m = __ballot(in);
                int before = __popcll(m & ((1ull << lane) - 1ull));
                int pos = found + before;
                if (in && pos < KS) list[pos] = n;
                found += __popcll(m);
            }
            int first = list[0];
            if (lane < KS) { int v = (lane < found) ? list[lane] : first; list[lane] = v; }
        }
        __syncthreads();
        // layer1 gather (verbatim k_layer1, threads 0..255 active)
        const size_t m0 = (size_t)g0 * KS;
        if (t < 256) {
            const int r = t >> 1, half = t & 1;
            const int n = s_idx[r];
            const float* prow = pts_t + ((size_t)b * NP + n) * CD;
#pragma unroll
            for (int rep = 0; rep < 8; ++rep) {
                const int c4 = half * 4 + rep * 8;
                float4 v = *(const float4*)(prow + c4);
                Ft[(3 + c4 + 0) * 128 + r] = v.x;
                Ft[(3 + c4 + 1) * 128 + r] = v.y;
                Ft[(3 + c4 + 2) * 128 + r] = v.z;
                Ft[(3 + c4 + 3) * 128 + r] = v.w;
            }
            if (t < 128) {
                const int n2 = s_idx[t];
                const int g = t >> 5;
                const float* xbg = xyz + (size_t)b * 3 * NP;
                Ft[0 * 128 + t] = __fsub_rn(xbg[n2],          s_q[g * 3 + 0]);
                Ft[1 * 128 + t] = __fsub_rn(xbg[NP + n2],     s_q[g * 3 + 1]);
                Ft[2 * 128 + t] = __fsub_rn(xbg[2 * NP + n2], s_q[g * 3 + 2]);
            }
        }
        __syncthreads();
        const int rg = t >> 3;   // 0..31 -> rows rg*4..+3 (t<256)
        const int cg = t & 7;    // 0..7  -> cols cg*8..+7
        float ls[8] = {0,0,0,0,0,0,0,0}, lq[8] = {0,0,0,0,0,0,0,0};
        if (t < 256) {
            float4 ba = *(const float4*)(bias0 + cg * 8);
            float4 bb = *(const float4*)(bias0 + cg * 8 + 4);
            float acc[4][8];
#pragma unroll
            for (int j = 0; j < 4; ++j) {
                acc[j][0] = ba.x; acc[j][1] = ba.y; acc[j][2] = ba.z; acc[j][3] = ba.w;
                acc[j][4] = bb.x; acc[j][5] = bb.y; acc[j][6] = bb.z; acc[j][7] = bb.w;
            }
            for (int kk = 0; kk < 67; ++kk) {
                float4 f = *(const float4*)(Ft + kk * 128 + rg * 4);
                float4 wa = *(const float4*)(Ws + kk * 64 + cg * 8);
                float4 wb = *(const float4*)(Ws + kk * 64 + cg * 8 + 4);
                float fv[4] = {f.x, f.y, f.z, f.w};
                float wv[8] = {wa.x, wa.y, wa.z, wa.w, wb.x, wb.y, wb.z, wb.w};
#pragma unroll
                for (int j = 0; j < 4; ++j)
#pragma unroll
                    for (int i = 0; i < 8; ++i) acc[j][i] = fmaf(fv[j], wv[i], acc[j][i]);
            }
#pragma unroll
            for (int j = 0; j < 4; ++j) {
                size_t m = m0 + rg * 4 + j;
                float4 oa = {acc[j][0], acc[j][1], acc[j][2], acc[j][3]};
                float4 ob = {acc[j][4], acc[j][5], acc[j][6], acc[j][7]};
                *(float4*)(h1 + m * 64 + cg * 8) = oa;
                *(float4*)(h1 + m * 64 + cg * 8 + 4) = ob;
#pragma unroll
                for (int i = 0; i < 8; ++i) { float v = acc[j][i]; ls[i] += v; lq[i] += v * v; }
            }
        }
        __syncthreads();           // Ft reuse for stats partials
        float* part_s = Ft;        // [32][64]
        float* part_q = Ft + 2048; // [32][64]
        if (t < 256) {
#pragma unroll
            for (int i = 0; i < 8; ++i) { part_s[rg * 64 + cg * 8 + i] = ls[i]; part_q[rg * 64 + cg * 8 + i] = lq[i]; }
        }
        __syncthreads();
        if (t < 64) {
            float s = 0.f, q = 0.f;
#pragma unroll
            for (int rgi = 0; rgi < 32; ++rgi) { s += part_s[rgi * 64 + t]; q += part_q[rgi * 64 + t]; }
            int cp = kq & (NCOPY - 1);
            atomicAdd(&sum0[cp * 64 + t], s);
            atomicAdd(&ssq0[cp * 64 + t], q);
        }
    }
}

// ---------------- layer2: BN1+ReLU on load + GEMM(64->64) + stats ----------------
__global__ __launch_bounds__(256) void k_layer2(const float* __restrict__ h1,
                                                const float* __restrict__ Wt1,
                                                const float* __restrict__ bias1,
                                                const float* __restrict__ ss1,
                                                float* __restrict__ h2,
                                                float* __restrict__ sum1,
                                                float* __restrict__ ssq1)
{
    __shared__ __align__(16) float Ft[64 * 128];
    __shared__ __align__(16) float Ws[64 * 64];
    __shared__ float s_sc[64], s_sh[64];
    const int t = threadIdx.x;
    const int m0 = blockIdx.x * 128;
    for (int i = t; i < 64 * 64; i += 256) Ws[i] = Wt1[i];
    if (t < 64) { s_sc[t] = ss1[t]; s_sh[t] = ss1[64 + t]; }
    __syncthreads();
    {
        const int tq = t >> 2, qq = t & 3;
#pragma unroll
        for (int rr = 0; rr < 2; ++rr) {
            const int r = rr * 64 + tq;
            const float* hrow = h1 + (size_t)(m0 + r) * 64;
#pragma unroll
            for (int rep = 0; rep < 4; ++rep) {
                const int c4 = qq * 4 + rep * 16;
                float4 v = *(const float4*)(hrow + c4);
                Ft[(c4 + 0) * 128 + r] = fmaxf(0.f, fmaf(v.x, s_sc[c4 + 0], s_sh[c4 + 0]));
                Ft[(c4 + 1) * 128 + r] = fmaxf(0.f, fmaf(v.y, s_sc[c4 + 1], s_sh[c4 + 1]));
                Ft[(c4 + 2) * 128 + r] = fmaxf(0.f, fmaf(v.z, s_sc[c4 + 2], s_sh[c4 + 2]));
                Ft[(c4 + 3) * 128 + r] = fmaxf(0.f, fmaf(v.w, s_sc[c4 + 3], s_sh[c4 + 3]));
            }
        }
    }
    __syncthreads();
    const int rg = t >> 3;
    const int cg = t & 7;
    float4 ba = *(const float4*)(bias1 + cg * 8);
    float4 bb = *(const float4*)(bias1 + cg * 8 + 4);
    float acc[4][8];
#pragma unroll
    for (int j = 0; j < 4; ++j) {
        acc[j][0] = ba.x; acc[j][1] = ba.y; acc[j][2] = ba.z; acc[j][3] = ba.w;
        acc[j][4] = bb.x; acc[j][5] = bb.y; acc[j][6] = bb.z; acc[j][7] = bb.w;
    }
    for (int kk = 0; kk < 64; ++kk) {
        float4 f = *(const float4*)(Ft + kk * 128 + rg * 4);
        float4 wa = *(const float4*)(Ws + kk * 64 + cg * 8);
        float4 wb = *(const float4*)(Ws + kk * 64 + cg * 8 + 4);
        float fv[4] = {f.x, f.y, f.z, f.w};
        float wv[8] = {wa.x, wa.y, wa.z, wa.w, wb.x, wb.y, wb.z, wb.w};
#pragma unroll
        for (int j = 0; j < 4; ++j)
#pragma unroll
            for (int i = 0; i < 8; ++i) acc[j][i] = fmaf(fv[j], wv[i], acc[j][i]);
    }
    float ls[8] = {0,0,0,0,0,0,0,0}, lq[8] = {0,0,0,0,0,0,0,0};
#pragma unroll
    for (int j = 0; j < 4; ++j) {
        int m = m0 + rg * 4 + j;
        float4 oa = {acc[j][0], acc[j][1], acc[j][2], acc[j][3]};
        float4 ob = {acc[j][4], acc[j][5], acc[j][6], acc[j][7]};
        *(float4*)(h2 + (size_t)m * 64 + cg * 8) = oa;
        *(float4*)(h2 + (size_t)m * 64 + cg * 8 + 4) = ob;
#pragma unroll
        for (int i = 0; i < 8; ++i) { float v = acc[j][i]; ls[i] += v; lq[i] += v * v; }
    }
    __syncthreads();
    float* part_s = Ft;
    float* part_q = Ft + 2048;
#pragma unroll
    for (int i = 0; i < 8; ++i) { part_s[rg * 64 + cg * 8 + i] = ls[i]; part_q[rg * 64 + cg * 8 + i] = lq[i]; }
    __syncthreads();
    if (t < 64) {
        float s = 0.f, q = 0.f;
#pragma unroll
        for (int rgi = 0; rgi < 32; ++rgi) { s += part_s[rgi * 64 + t]; q += part_q[rgi * 64 + t]; }
        int cp = blockIdx.x & (NCOPY - 1);
        atomicAdd(&sum1[cp * 64 + t], s);
        atomicAdd(&ssq1[cp * 64 + t], q);
    }
}

// ---------------- layer3: BN2+ReLU + GEMM(64->128) + stats + per-group max/min ----------------
// Pooling trick: max_k relu(a*h+b) == relu(a*max_k h + b) for a>=0 (min_k for a<0),
// exact in fp32 by monotonicity of fmaf/relu. So h3 is never materialized.
__global__ __launch_bounds__(256) void k_layer3(const float* __restrict__ h2,
                                                const float* __restrict__ Wt2,
                                                const float* __restrict__ bias2,
                                                const float* __restrict__ ss2,
                                                float* __restrict__ sum2,
                                                float* __restrict__ ssq2,
                                                float* __restrict__ gmax,
                                                float* __restrict__ gmin)
{
    __shared__ __align__(16) float Ft[64 * 128];
    __shared__ __align__(16) float Ws[64 * 128];
    __shared__ float s_sc[64], s_sh[64];
    const int t = threadIdx.x;
    const int m0 = blockIdx.x * 128;
    for (int i = t; i < 64 * 128; i += 256) Ws[i] = Wt2[i];
    if (t < 64) { s_sc[t] = ss2[t]; s_sh[t] = ss2[64 + t]; }
    __syncthreads();
    {
        const int tq = t >> 2, qq = t & 3;
#pragma unroll
        for (int rr = 0; rr < 2; ++rr) {
            const int r = rr * 64 + tq;
            const float* hrow = h2 + (size_t)(m0 + r) * 64;
#pragma unroll
            for (int rep = 0; rep < 4; ++rep) {
                const int c4 = qq * 4 + rep * 16;
                float4 v = *(const float4*)(hrow + c4);
                Ft[(c4 + 0) * 128 + r] = fmaxf(0.f, fmaf(v.x, s_sc[c4 + 0], s_sh[c4 + 0]));
                Ft[(c4 + 1) * 128 + r] = fmaxf(0.f, fmaf(v.y, s_sc[c4 + 1], s_sh[c4 + 1]));
                Ft[(c4 + 2) * 128 + r] = fmaxf(0.f, fmaf(v.z, s_sc[c4 + 2], s_sh[c4 + 2]));
                Ft[(c4 + 3) * 128 + r] = fmaxf(0.f, fmaf(v.w, s_sc[c4 + 3], s_sh[c4 + 3]));
            }
        }
    }
    __syncthreads();
    const int rg = t >> 4;  // 0..15 -> rows rg*8..+7
    const int cg = t & 15;  // 0..15 -> cols cg*8..+7
    float4 ba = *(const float4*)(bias2 + cg * 8);
    float4 bb = *(const float4*)(bias2 + cg * 8 + 4);
    float acc[8][8];
#pragma unroll
    for (int j = 0; j < 8; ++j) {
        acc[j][0] = ba.x; acc[j][1] = ba.y; acc[j][2] = ba.z; acc[j][3] = ba.w;
        acc[j][4] = bb.x; acc[j][5] = bb.y; acc[j][6] = bb.z; acc[j][7] = bb.w;
    }
    for (int kk = 0; kk < 64; ++kk) {
        float4 fa = *(const float4*)(Ft + kk * 128 + rg * 8);
        float4 fb = *(const float4*)(Ft + kk * 128 + rg * 8 + 4);
        float4 wa = *(const float4*)(Ws + kk * 128 + cg * 8);
        float4 wb = *(const float4*)(Ws + kk * 128 + cg * 8 + 4);
        float fv[8] = {fa.x, fa.y, fa.z, fa.w, fb.x, fb.y, fb.z, fb.w};
        float wv[8] = {wa.x, wa.y, wa.z, wa.w, wb.x, wb.y, wb.z, wb.w};
#pragma unroll
        for (int j = 0; j < 8; ++j)
#pragma unroll
            for (int i = 0; i < 8; ++i) acc[j][i] = fmaf(fv[j], wv[i], acc[j][i]);
    }
    float ls[8] = {0,0,0,0,0,0,0,0}, lq[8] = {0,0,0,0,0,0,0,0};
    float pm[8], pn[8];
#pragma unroll
    for (int i = 0; i < 8; ++i) { pm[i] = acc[0][i]; pn[i] = acc[0][i]; }
#pragma unroll
    for (int j = 0; j < 8; ++j)
#pragma unroll
        for (int i = 0; i < 8; ++i) {
            float v = acc[j][i];
            ls[i] += v; lq[i] += v * v;
            pm[i] = fmaxf(pm[i], v); pn[i] = fminf(pn[i], v);
        }
    __syncthreads();
    float* part_s = Ft;        // [16][128]
    float* part_q = Ft + 2048; // [16][128]
    float* part_m = Ft + 4096; // [16][128]
    float* part_n = Ft + 6144; // [16][128]
#pragma unroll
    for (int i = 0; i < 8; ++i) {
        part_s[rg * 128 + cg * 8 + i] = ls[i];
        part_q[rg * 128 + cg * 8 + i] = lq[i];
        part_m[rg * 128 + cg * 8 + i] = pm[i];
        part_n[rg * 128 + cg * 8 + i] = pn[i];
    }
    __syncthreads();
    if (t < 128) {
        float s = 0.f, q = 0.f;
#pragma unroll
        for (int rgi = 0; rgi < 16; ++rgi) { s += part_s[rgi * 128 + t]; q += part_q[rgi * 128 + t]; }
        int cp = blockIdx.x & (NCOPY - 1);
        atomicAdd(&sum2[cp * 128 + t], s);
        atomicAdd(&ssq2[cp * 128 + t], q);
    }
    for (int e = t; e < 512; e += 256) {
        int g = e >> 7, c = e & 127;
        float M = part_m[(g * 4 + 0) * 128 + c];
        M = fmaxf(M, part_m[(g * 4 + 1) * 128 + c]);
        M = fmaxf(M, part_m[(g * 4 + 2) * 128 + c]);
        M = fmaxf(M, part_m[(g * 4 + 3) * 128 + c]);
        float N = part_n[(g * 4 + 0) * 128 + c];
        N = fminf(N, part_n[(g * 4 + 1) * 128 + c]);
        N = fminf(N, part_n[(g * 4 + 2) * 128 + c]);
        N = fminf(N, part_n[(g * 4 + 3) * 128 + c]);
        int grp = blockIdx.x * 4 + g;              // == b*1024 + s
        gmax[(size_t)grp * 128 + c] = M;
        gmin[(size_t)grp * 128 + c] = N;
    }
}

// ---------------- pool2: apply BN3+ReLU to pooled max/min, transposed store ----------------
__global__ __launch_bounds__(256) void k_pool2(const float* __restrict__ gmax,
                                               const float* __restrict__ gmin,
                                               const float* __restrict__ ss3,
                                               float* __restrict__ outp)
{
    int idx = blockIdx.x * 256 + threadIdx.x;      // 1,048,576 = 8*128*1024
    int b = idx >> 17;
    int c = (idx >> 10) & 127;
    int s = idx & 1023;
    int grp = (b << 10) + s;
    float a = ss3[c], sh = ss3[128 + c];
    float m = (a >= 0.f) ? gmax[(size_t)grp * 128 + c] : gmin[(size_t)grp * 128 + c];
    outp[idx] = fmaxf(0.f, fmaf(m, a, sh));
}

// ---------------- finalize BN stats -> scale/shift ----------------
__global__ void k_finalize(const float* __restrict__ sum, const float* __restrict__ ssq,
                           const float* __restrict__ g, const float* __restrict__ beta,
                           float* __restrict__ ss, int nc)
{
    int c = threadIdx.x;
    if (c >= nc) return;
    float s = 0.f, q = 0.f;
    for (int k = 0; k < NCOPY; ++k) { s += sum[k * nc + c]; q += ssq[k * nc + c]; }
    const float inv = 1.0f / 262144.0f;
    float mean = s * inv;
    float var = q * inv - mean * mean;
    float rstd = 1.0f / sqrtf(var + 1e-5f);
    float scale = g[c] * rstd;
    ss[c] = scale;
    ss[nc + c] = beta[c] - mean * scale;
}

extern "C" void kernel_launch(void* const* d_in, const int* in_sizes, int n_in,
                              void* d_out, int out_size, void* d_ws, size_t ws_size,
                              hipStream_t stream)
{
    const float* xyz    = (const float*)d_in[0];
    const float* points = (const float*)d_in[1];
    const float* w0 = (const float*)d_in[2];
    const float* b0 = (const float*)d_in[3];
    const float* gm0 = (const float*)d_in[4];
    const float* bt0 = (const float*)d_in[5];
    const float* w1 = (const float*)d_in[6];
    const float* b1 = (const float*)d_in[7];
    const float* gm1 = (const float*)d_in[8];
    const float* bt1 = (const float*)d_in[9];
    const float* w2 = (const float*)d_in[10];
    const float* b2 = (const float*)d_in[11];
    const float* gm2 = (const float*)d_in[12];
    const float* bt2 = (const float*)d_in[13];
    float* out = (float*)d_out;

    char* p = (char*)d_ws;
    auto alloc = [&](size_t nbytes) -> void* {
        void* r = (void*)p;
        p += (nbytes + 255) & ~(size_t)255;
        return r;
    };
    float* fps_pts = (float*)alloc((size_t)NB * SP * 3 * 4);
    float* pts_t = (float*)alloc((size_t)NB * NP * CD * 4);
    float* h1 = (float*)alloc((size_t)MROWS * 64 * 4);
    float* h2 = (float*)alloc((size_t)MROWS * 64 * 4);
    float* gmax = (float*)alloc((size_t)NB * SP * 128 * 4);
    float* gmin = (float*)alloc((size_t)NB * SP * 128 * 4);
    float* Wt0 = (float*)alloc(67 * 64 * 4);
    float* Wt1 = (float*)alloc(64 * 64 * 4);
    float* Wt2 = (float*)alloc(64 * 128 * 4);
    float* stats = (float*)alloc(8192 * 4);
    float* ss1 = (float*)alloc(128 * 4);
    float* ss2 = (float*)alloc(128 * 4);
    float* ss3 = (float*)alloc(256 * 4);
    int*   ctl = (int*)alloc(256);

    float* sum0 = stats;
    float* ssq0 = stats + 16 * 64;
    float* sum1 = stats + 2 * 16 * 64;
    float* ssq1 = stats + 3 * 16 * 64;
    float* sum2 = stats + 4 * 16 * 64;
    float* ssq2 = sum2 + 16 * 128;

    k_pre<<<NB * (NP / 64) + 1, 512, 0, stream>>>(points, pts_t, w0, w1, w2, Wt0, Wt1, Wt2, stats, ctl);
    k_mega<<<256, 512, 0, stream>>>(xyz, fps_pts, out, pts_t, Wt0, b0, h1, sum0, ssq0, ctl);
    k_finalize<<<1, 128, 0, stream>>>(sum0, ssq0, gm0, bt0, ss1, 64);
    k_layer2<<<MROWS / 128, 256, 0, stream>>>(h1, Wt1, b1, ss1, h2, sum1, ssq1);
    k_finalize<<<1, 128, 0, stream>>>(sum1, ssq1, gm1, bt1, ss2, 64);
    k_layer3<<<MROWS / 128, 256, 0, stream>>>(h2, Wt2, b2, ss2, sum2, ssq2, gmax, gmin);
    k_finalize<<<1, 128, 0, stream>>>(sum2, ssq2, gm2, bt2, ss3, 128);
    k_pool2<<<(NB * SP * 128) / 256, 256, 0, stream>>>(gmax, gmin, ss3, out + 24576);
}

// Round 6
// 1277.829 us; speedup vs baseline: 1.0139x; 1.0139x over previous
//
#include <hip/hip_runtime.h>

#define NB 8
#define NP 8192
#define SP 1024
#define KS 32
#define CD 64
#define MROWS (NB*SP*KS)
#define NCOPY 16

typedef float v2f __attribute__((ext_vector_type(2)));
typedef unsigned long long u64;

// one DPP max step on a u64 key: pure VALU, no LDS. ctrl is a template param because
// __builtin_amdgcn_update_dpp requires an immediate. old=src + bound_ctrl=false ->
// lanes with no valid source keep their own value (identity for max).
template <int CTRL>
__device__ __forceinline__ u64 dpp_max_step(u64 x) {
    int lo = (int)(unsigned)(x & 0xffffffffull);
    int hi = (int)(unsigned)(x >> 32);
    int slo = __builtin_amdgcn_update_dpp(lo, lo, CTRL, 0xf, 0xf, false);
    int shi = __builtin_amdgcn_update_dpp(hi, hi, CTRL, 0xf, 0xf, false);
    u64 y = ((u64)(unsigned)shi << 32) | (unsigned)slo;
    return x > y ? x : y;
}

// ---------------- pre-kernel: points transpose + weight prep + zero stats/ctl ----------------
// All of this is consumed by LATER kernels only -> kernel-boundary coherence (validated r0-r3).
__global__ __launch_bounds__(512) void k_pre(const float* __restrict__ points,
                                             float* __restrict__ pts_t,
                                             const float* __restrict__ w0,
                                             const float* __restrict__ w1,
                                             const float* __restrict__ w2,
                                             float* __restrict__ Wt0,
                                             float* __restrict__ Wt1,
                                             float* __restrict__ Wt2,
                                             float* __restrict__ stats,
                                             int* __restrict__ ctl)
{
    __shared__ float tile[64][65];
    const int blk = blockIdx.x;
    const int t = threadIdx.x;
    if (blk >= NB * (NP / 64)) {
        // weight prep: zero stats + ctl (padded: 1024 ints), transpose weights to [kk][c]
        for (int i = t; i < 8192; i += 512) stats[i] = 0.f;
        for (int i = t; i < 1024; i += 512) ctl[i] = 0;
        for (int i = t; i < 64 * 67; i += 512) { int c = i / 67, kk = i % 67; Wt0[kk * 64 + c] = w0[i]; }
        for (int i = t; i < 64 * 64; i += 512) { int c = i >> 6, kk = i & 63; Wt1[kk * 64 + c] = w1[i]; }
        for (int i = t; i < 128 * 64; i += 512) { int c = i >> 6, kk = i & 63; Wt2[kk * 128 + c] = w2[i]; }
        return;
    }
    // points transpose (B,64,N) -> (B,N,64), 64x64 tile, 512 threads (r0-verbatim)
    const int b = blk >> 7;
    const int n0 = (blk & 127) << 6;
    const float* pb = points + (size_t)b * CD * NP;
    const int c = t & 63;
    const int dr = t >> 6;                 // 0..7
#pragma unroll
    for (int it = 0; it < 8; ++it) {
        int d = dr + it * 8;
        tile[d][c] = pb[(size_t)d * NP + n0 + c];
    }
    __syncthreads();
#pragma unroll
    for (int it = 0; it < 8; ++it) {
        int nn = dr + it * 8;
        pts_t[((size_t)b * NP + n0 + nn) * CD + c] = tile[c][nn];
    }
}

// ---------------- mega kernel: FPS producers (blocks 0..7) + ballquery/layer1 consumers ----------
// 256 blocks x 512 thr, 128.25KB static LDS -> 1 block/CU, all co-resident (validated r4/r5).
// Coherence: device-scope RMW atomics ONLY for cross-block data (validated r5, bit-exact).
// r5 lesson (passed but +160us producer slowdown): ALL control words shared one 128B L2 line,
// and 248 spinners at 0.85us period saturated its atomic point; producer bursts queued behind.
// This round: (1) each control word on its own 256B line (prog[b]=ctl[b*64], ticket=ctl[512]);
// (2) spin backoff s_sleep(127) (~3.4us) -> ~30x fewer RMWs/line; (3) fps_pts in float4 stride,
// publish = 1 u64 + 1 u32 atomicExch per thread (was 3 u32).
__global__ __launch_bounds__(512, 1) void k_mega(const float* __restrict__ xyz,
                                                 float4* __restrict__ fps_q,
                                                 float* __restrict__ out_nx,
                                                 const float* __restrict__ pts_t,
                                                 const float* __restrict__ Wt0,
                                                 const float* __restrict__ bias0,
                                                 float* __restrict__ h1,
                                                 float* __restrict__ sum0,
                                                 float* __restrict__ ssq0,
                                                 int* __restrict__ ctl)
{
#pragma clang fp contract(off)
    __shared__ __align__(16) unsigned char smem[131344];
    const int blk = blockIdx.x;
    const int t = threadIdx.x;
    const int lane = t & 63, wid = t >> 6;

    if (blk < NB) {
        // ---- FPS producer (r0-verbatim loop + RMW burst publish) ----
        float4* s_p = (float4*)smem;               // 128 KB xyz mirror
        u64 (*s_wk)[8] = (u64(*)[8])(smem + 131072);
        const int b = blk;
        const float* xb = xyz + (size_t)b * 3 * NP;
        v2f px[8], py[8], pz[8], dv[8];
#pragma unroll
        for (int j = 0; j < 8; ++j) {
            const int n0 = t + (2 * j) * 512, n1 = n0 + 512;
            px[j] = (v2f){xb[n0], xb[n1]};
            py[j] = (v2f){xb[NP + n0], xb[NP + n1]};
            pz[j] = (v2f){xb[2 * NP + n0], xb[2 * NP + n1]};
            dv[j] = (v2f){1e10f, 1e10f};
            s_p[n0] = make_float4(px[j].x, py[j].x, pz[j].x, 0.f);
            s_p[n1] = make_float4(px[j].y, py[j].y, pz[j].y, 0.f);
        }
        float cx = xb[0], cy = xb[NP], cz = xb[2 * NP];
        float hx0 = 0.f, hy0 = 0.f, hz0 = 0.f;     // captured centroid of iteration i == t
        float hx1 = 0.f, hy1 = 0.f, hz1 = 0.f;     // captured centroid of iteration i == t + 512
        __syncthreads();
        for (int i = 0; i < SP; ++i) {
            if (i == t)       { hx0 = cx; hy0 = cy; hz0 = cz; }
            if (i == t + 512) { hx1 = cx; hy1 = cy; hz1 = cz; }
            // RMW burst publish at iteration top: drain lands at THIS iteration's barrier,
            // overlapped with the distance phase. One burst per 32 iterations, 64 atomics,
            // to lines nothing spins on.
            if ((i & 31) == 31) {
                if (i < 512) {
                    if (t >= i - 31 && t <= i) {
                        float4* dst = fps_q + (size_t)b * SP + t;
                        u64 pk = ((u64)__float_as_uint(hy0) << 32) | __float_as_uint(hx0);
                        atomicExch((u64*)dst, pk);
                        atomicExch((unsigned int*)dst + 2, __float_as_uint(hz0));
                    }
                } else {
                    const int s = t + 512;
                    if (s >= i - 31 && s <= i) {
                        float4* dst = fps_q + (size_t)b * SP + s;
                        u64 pk = ((u64)__float_as_uint(hy1) << 32) | __float_as_uint(hx1);
                        atomicExch((u64*)dst, pk);
                        atomicExch((unsigned int*)dst + 2, __float_as_uint(hz1));
                    }
                }
            }
            // progress one iteration AFTER the burst (its stores drained at the prior barrier)
            if ((i & 31) == 0 && i != 0 && t == 2) atomicExch(&ctl[b << 6], i);
            // distance update + in-thread argmax (EXACT fp32: sub, mul, (x2+y2)+z2, min;
            // contract(off) forbids fma; ascending gid + strict > == first-index tie-break)
            float bv = -1.f; int bg = 0;
#pragma unroll
            for (int j = 0; j < 8; ++j) {
                v2f dx = px[j] - cx;
                v2f dy = py[j] - cy;
                v2f dz = pz[j] - cz;
                v2f d  = dx * dx + dy * dy;
                d = d + dz * dz;
                v2f dm = dv[j];
                dm.x = fminf(dm.x, d.x);
                dm.y = fminf(dm.y, d.y);
                dv[j] = dm;
                if (dm.x > bv) { bv = dm.x; bg = t + (2 * j) * 512; }
                if (dm.y > bv) { bv = dm.y; bg = t + (2 * j + 1) * 512; }
            }
            u64 bk = ((u64)__float_as_uint(bv) << 32) | (unsigned int)~bg;
            // per-wave DPP max ladder (VALU only); lane 63 ends with the wave max
            bk = dpp_max_step<0x111>(bk);          // row_shr:1
            bk = dpp_max_step<0x112>(bk);          // row_shr:2
            bk = dpp_max_step<0x114>(bk);          // row_shr:4
            bk = dpp_max_step<0x118>(bk);          // row_shr:8
            bk = dpp_max_step<0x142>(bk);          // row_bcast:15
            bk = dpp_max_step<0x143>(bk);          // row_bcast:31
            const int par = i & 1;
            if (lane == 63) s_wk[par][wid] = bk;   // plain overwrite, parity-dbuf'd
            __syncthreads();
            // every wave DPP-reduces the 8 leader keys (replicated twice per 16-lane row)
            u64 rk = s_wk[par][lane & 7];
            rk = dpp_max_step<0x111>(rk);
            rk = dpp_max_step<0x112>(rk);
            rk = dpp_max_step<0x114>(rk);
            rk = dpp_max_step<0x118>(rk);
            const int wg = ~__builtin_amdgcn_readlane((int)(unsigned)(rk & 0xffffffffull), 15);
            const float4 c = s_p[wg];              // uniform broadcast ds_read_b128
            cx = c.x; cy = c.y; cz = c.z;
            // safe without 2nd barrier: next write to s_wk[par] is 2 iters away, past the next barrier
        }
        // all published (last burst drained at i=1023's barrier)
        if (t == 2) atomicExch(&ctl[b << 6], SP);
        // deferred out_nx (output 0) stores — kernel-boundary coherence
        out_nx[(size_t)b * 3 * SP + 0 * SP + t] = hx0;
        out_nx[(size_t)b * 3 * SP + 1 * SP + t] = hy0;
        out_nx[(size_t)b * 3 * SP + 2 * SP + t] = hz0;
        out_nx[(size_t)b * 3 * SP + 0 * SP + t + 512] = hx1;
        out_nx[(size_t)b * 3 * SP + 1 * SP + t + 512] = hy1;
        out_nx[(size_t)b * 3 * SP + 2 * SP + t + 512] = hz1;
        return;
    }

    // ---- consumer blocks: units of (batch b, 4 centroids): ballquery + layer1 ----
    float* Ft    = (float*)smem;                   // [67*128] floats (34304 B)
    float* Ws    = (float*)(smem + 34304);         // [67*64]  floats (17152 B)
    int*   s_idx = (int*)(smem + 51456);           // [128]
    float* s_q   = (float*)(smem + 51968);         // [12]
    int*   s_tk  = (int*)(smem + 131328);
    int*   s_rdy = (int*)(smem + 131332);

    // stage Ws once (Wt0 from k_pre across the kernel boundary; Ws region never clobbered)
    for (int i = t; i < 67 * 64; i += 512) Ws[i] = Wt0[i];

    for (;;) {
        __syncthreads();
        if (t == 0) *s_tk = atomicAdd(&ctl[512], 1);
        __syncthreads();
        const int u = *s_tk;
        if (u >= 2048) break;
        const int b = u & 7, kq = u >> 3;
        const int need = 4 * kq + 4;
        const int g0 = b * SP + kq * 4;            // global group index base
        // spin on producer progress (RMW read on a private 256B line; heavy backoff)
        for (;;) {
            if (t == 0) *s_rdy = (atomicAdd(&ctl[b << 6], 0) >= need);
            __syncthreads();
            const int ok = *s_rdy;
            __syncthreads();
            if (ok) break;
            __builtin_amdgcn_s_sleep(127);
        }
        // RMW-read the 4 query centroids (float4 stride) into LDS
        if (t < 4) {
            float4* src = fps_q + g0 + t;
            u64 pk = atomicAdd((u64*)src, 0ull);
            unsigned int uz = atomicAdd((unsigned int*)src + 2, 0u);
            s_q[t * 3 + 0] = __uint_as_float((unsigned int)(pk & 0xffffffffull));
            s_q[t * 3 + 1] = __uint_as_float((unsigned int)(pk >> 32));
            s_q[t * 3 + 2] = __uint_as_float(uz);
        }
        __syncthreads();
        // ballquery: waves 0..3 handle one query each (verbatim k_ballquery math)
        if (wid < 4) {
            const float qx = s_q[wid * 3 + 0];
            const float qy = s_q[wid * 3 + 1];
            const float qz = s_q[wid * 3 + 2];
            const float* xbq = xyz + (size_t)b * 3 * NP;
            int* list = s_idx + wid * KS;
            const float r2 = (float)(0.2 * 0.2);   // 0.039999999f — matches python double->f32
            int found = 0;
            for (int base2 = 0; base2 < NP && found < KS; base2 += 64) {
                int n = base2 + lane;
                float dx = __fsub_rn(qx, xbq[n]);
                float dy = __fsub_rn(qy, xbq[NP + n]);
                float dz = __fsub_rn(qz, xbq[2 * NP + n]);
                float d = __fadd_rn(__fadd_rn(__fmul_rn(dx, dx), __fmul_rn(dy, dy)), __fmul_rn(dz, dz));
                bool in = !(d > r2);
                unsigned long long m = __ballot(in);
                int before = __popcll(m & ((1ull << lane) - 1ull));
                int pos = found + before;
                if (in && pos < KS) list[pos] = n;
                found += __popcll(m);
            }
            int first = list[0];
            if (lane < KS) { int v = (lane < found) ? list[lane] : first; list[lane] = v; }
        }
        __syncthreads();
        // layer1 gather (verbatim k_layer1, threads 0..255 active)
        const size_t m0 = (size_t)g0 * KS;
        if (t < 256) {
            const int r = t >> 1, half = t & 1;
            const int n = s_idx[r];
            const float* prow = pts_t + ((size_t)b * NP + n) * CD;
#pragma unroll
            for (int rep = 0; rep < 8; ++rep) {
                const int c4 = half * 4 + rep * 8;
                float4 v = *(const float4*)(prow + c4);
                Ft[(3 + c4 + 0) * 128 + r] = v.x;
                Ft[(3 + c4 + 1) * 128 + r] = v.y;
                Ft[(3 + c4 + 2) * 128 + r] = v.z;
                Ft[(3 + c4 + 3) * 128 + r] = v.w;
            }
            if (t < 128) {
                const int n2 = s_idx[t];
                const int g = t >> 5;
                const float* xbg = xyz + (size_t)b * 3 * NP;
                Ft[0 * 128 + t] = __fsub_rn(xbg[n2],          s_q[g * 3 + 0]);
                Ft[1 * 128 + t] = __fsub_rn(xbg[NP + n2],     s_q[g * 3 + 1]);
                Ft[2 * 128 + t] = __fsub_rn(xbg[2 * NP + n2], s_q[g * 3 + 2]);
            }
        }
        __syncthreads();
        const int rg = t >> 3;   // 0..31 -> rows rg*4..+3 (t<256)
        const int cg = t & 7;    // 0..7  -> cols cg*8..+7
        float ls[8] = {0,0,0,0,0,0,0,0}, lq[8] = {0,0,0,0,0,0,0,0};
        if (t < 256) {
            float4 ba = *(const float4*)(bias0 + cg * 8);
            float4 bb = *(const float4*)(bias0 + cg * 8 + 4);
            float acc[4][8];
#pragma unroll
            for (int j = 0; j < 4; ++j) {
                acc[j][0] = ba.x; acc[j][1] = ba.y; acc[j][2] = ba.z; acc[j][3] = ba.w;
                acc[j][4] = bb.x; acc[j][5] = bb.y; acc[j][6] = bb.z; acc[j][7] = bb.w;
            }
            for (int kk = 0; kk < 67; ++kk) {
                float4 f = *(const float4*)(Ft + kk * 128 + rg * 4);
                float4 wa = *(const float4*)(Ws + kk * 64 + cg * 8);
                float4 wb = *(const float4*)(Ws + kk * 64 + cg * 8 + 4);
                float fv[4] = {f.x, f.y, f.z, f.w};
                float wv[8] = {wa.x, wa.y, wa.z, wa.w, wb.x, wb.y, wb.z, wb.w};
#pragma unroll
                for (int j = 0; j < 4; ++j)
#pragma unroll
                    for (int i = 0; i < 8; ++i) acc[j][i] = fmaf(fv[j], wv[i], acc[j][i]);
            }
#pragma unroll
            for (int j = 0; j < 4; ++j) {
                size_t m = m0 + rg * 4 + j;
                float4 oa = {acc[j][0], acc[j][1], acc[j][2], acc[j][3]};
                float4 ob = {acc[j][4], acc[j][5], acc[j][6], acc[j][7]};
                *(float4*)(h1 + m * 64 + cg * 8) = oa;
                *(float4*)(h1 + m * 64 + cg * 8 + 4) = ob;
#pragma unroll
                for (int i = 0; i < 8; ++i) { float v = acc[j][i]; ls[i] += v; lq[i] += v * v; }
            }
        }
        __syncthreads();           // Ft reuse for stats partials
        float* part_s = Ft;        // [32][64]
        float* part_q = Ft + 2048; // [32][64]
        if (t < 256) {
#pragma unroll
            for (int i = 0; i < 8; ++i) { part_s[rg * 64 + cg * 8 + i] = ls[i]; part_q[rg * 64 + cg * 8 + i] = lq[i]; }
        }
        __syncthreads();
        if (t < 64) {
            float s = 0.f, q = 0.f;
#pragma unroll
            for (int rgi = 0; rgi < 32; ++rgi) { s += part_s[rgi * 64 + t]; q += part_q[rgi * 64 + t]; }
            int cp = kq & (NCOPY - 1);
            atomicAdd(&sum0[cp * 64 + t], s);
            atomicAdd(&ssq0[cp * 64 + t], q);
        }
    }
}

// ---------------- layer2: BN1+ReLU on load + GEMM(64->64) + stats ----------------
__global__ __launch_bounds__(256) void k_layer2(const float* __restrict__ h1,
                                                const float* __restrict__ Wt1,
                                                const float* __restrict__ bias1,
                                                const float* __restrict__ ss1,
                                                float* __restrict__ h2,
                                                float* __restrict__ sum1,
                                                float* __restrict__ ssq1)
{
    __shared__ __align__(16) float Ft[64 * 128];
    __shared__ __align__(16) float Ws[64 * 64];
    __shared__ float s_sc[64], s_sh[64];
    const int t = threadIdx.x;
    const int m0 = blockIdx.x * 128;
    for (int i = t; i < 64 * 64; i += 256) Ws[i] = Wt1[i];
    if (t < 64) { s_sc[t] = ss1[t]; s_sh[t] = ss1[64 + t]; }
    __syncthreads();
    {
        const int tq = t >> 2, qq = t & 3;
#pragma unroll
        for (int rr = 0; rr < 2; ++rr) {
            const int r = rr * 64 + tq;
            const float* hrow = h1 + (size_t)(m0 + r) * 64;
#pragma unroll
            for (int rep = 0; rep < 4; ++rep) {
                const int c4 = qq * 4 + rep * 16;
                float4 v = *(const float4*)(hrow + c4);
                Ft[(c4 + 0) * 128 + r] = fmaxf(0.f, fmaf(v.x, s_sc[c4 + 0], s_sh[c4 + 0]));
                Ft[(c4 + 1) * 128 + r] = fmaxf(0.f, fmaf(v.y, s_sc[c4 + 1], s_sh[c4 + 1]));
                Ft[(c4 + 2) * 128 + r] = fmaxf(0.f, fmaf(v.z, s_sc[c4 + 2], s_sh[c4 + 2]));
                Ft[(c4 + 3) * 128 + r] = fmaxf(0.f, fmaf(v.w, s_sc[c4 + 3], s_sh[c4 + 3]));
            }
        }
    }
    __syncthreads();
    const int rg = t >> 3;
    const int cg = t & 7;
    float4 ba = *(const float4*)(bias1 + cg * 8);
    float4 bb = *(const float4*)(bias1 + cg * 8 + 4);
    float acc[4][8];
#pragma unroll
    for (int j = 0; j < 4; ++j) {
        acc[j][0] = ba.x; acc[j][1] = ba.y; acc[j][2] = ba.z; acc[j][3] = ba.w;
        acc[j][4] = bb.x; acc[j][5] = bb.y; acc[j][6] = bb.z; acc[j][7] = bb.w;
    }
    for (int kk = 0; kk < 64; ++kk) {
        float4 f = *(const float4*)(Ft + kk * 128 + rg * 4);
        float4 wa = *(const float4*)(Ws + kk * 64 + cg * 8);
        float4 wb = *(const float4*)(Ws + kk * 64 + cg * 8 + 4);
        float fv[4] = {f.x, f.y, f.z, f.w};
        float wv[8] = {wa.x, wa.y, wa.z, wa.w, wb.x, wb.y, wb.z, wb.w};
#pragma unroll
        for (int j = 0; j < 4; ++j)
#pragma unroll
            for (int i = 0; i < 8; ++i) acc[j][i] = fmaf(fv[j], wv[i], acc[j][i]);
    }
    float ls[8] = {0,0,0,0,0,0,0,0}, lq[8] = {0,0,0,0,0,0,0,0};
#pragma unroll
    for (int j = 0; j < 4; ++j) {
        int m = m0 + rg * 4 + j;
        float4 oa = {acc[j][0], acc[j][1], acc[j][2], acc[j][3]};
        float4 ob = {acc[j][4], acc[j][5], acc[j][6], acc[j][7]};
        *(float4*)(h2 + (size_t)m * 64 + cg * 8) = oa;
        *(float4*)(h2 + (size_t)m * 64 + cg * 8 + 4) = ob;
#pragma unroll
        for (int i = 0; i < 8; ++i) { float v = acc[j][i]; ls[i] += v; lq[i] += v * v; }
    }
    __syncthreads();
    float* part_s = Ft;
    float* part_q = Ft + 2048;
#pragma unroll
    for (int i = 0; i < 8; ++i) { part_s[rg * 64 + cg * 8 + i] = ls[i]; part_q[rg * 64 + cg * 8 + i] = lq[i]; }
    __syncthreads();
    if (t < 64) {
        float s = 0.f, q = 0.f;
#pragma unroll
        for (int rgi = 0; rgi < 32; ++rgi) { s += part_s[rgi * 64 + t]; q += part_q[rgi * 64 + t]; }
        int cp = blockIdx.x & (NCOPY - 1);
        atomicAdd(&sum1[cp * 64 + t], s);
        atomicAdd(&ssq1[cp * 64 + t], q);
    }
}

// ---------------- layer3: BN2+ReLU + GEMM(64->128) + stats + per-group max/min ----------------
// Pooling trick: max_k relu(a*h+b) == relu(a*max_k h + b) for a>=0 (min_k for a<0),
// exact in fp32 by monotonicity of fmaf/relu. So h3 is never materialized.
__global__ __launch_bounds__(256) void k_layer3(const float* __restrict__ h2,
                                                const float* __restrict__ Wt2,
                                                const float* __restrict__ bias2,
                                                const float* __restrict__ ss2,
                                                float* __restrict__ sum2,
                                                float* __restrict__ ssq2,
                                                float* __restrict__ gmax,
                                                float* __restrict__ gmin)
{
    __shared__ __align__(16) float Ft[64 * 128];
    __shared__ __align__(16) float Ws[64 * 128];
    __shared__ float s_sc[64], s_sh[64];
    const int t = threadIdx.x;
    const int m0 = blockIdx.x * 128;
    for (int i = t; i < 64 * 128; i += 256) Ws[i] = Wt2[i];
    if (t < 64) { s_sc[t] = ss2[t]; s_sh[t] = ss2[64 + t]; }
    __syncthreads();
    {
        const int tq = t >> 2, qq = t & 3;
#pragma unroll
        for (int rr = 0; rr < 2; ++rr) {
            const int r = rr * 64 + tq;
            const float* hrow = h2 + (size_t)(m0 + r) * 64;
#pragma unroll
            for (int rep = 0; rep < 4; ++rep) {
                const int c4 = qq * 4 + rep * 16;
                float4 v = *(const float4*)(hrow + c4);
                Ft[(c4 + 0) * 128 + r] = fmaxf(0.f, fmaf(v.x, s_sc[c4 + 0], s_sh[c4 + 0]));
                Ft[(c4 + 1) * 128 + r] = fmaxf(0.f, fmaf(v.y, s_sc[c4 + 1], s_sh[c4 + 1]));
                Ft[(c4 + 2) * 128 + r] = fmaxf(0.f, fmaf(v.z, s_sc[c4 + 2], s_sh[c4 + 2]));
                Ft[(c4 + 3) * 128 + r] = fmaxf(0.f, fmaf(v.w, s_sc[c4 + 3], s_sh[c4 + 3]));
            }
        }
    }
    __syncthreads();
    const int rg = t >> 4;  // 0..15 -> rows rg*8..+7
    const int cg = t & 15;  // 0..15 -> cols cg*8..+7
    float4 ba = *(const float4*)(bias2 + cg * 8);
    float4 bb = *(const float4*)(bias2 + cg * 8 + 4);
    float acc[8][8];
#pragma unroll
    for (int j = 0; j < 8; ++j) {
        acc[j][0] = ba.x; acc[j][1] = ba.y; acc[j][2] = ba.z; acc[j][3] = ba.w;
        acc[j][4] = bb.x; acc[j][5] = bb.y; acc[j][6] = bb.z; acc[j][7] = bb.w;
    }
    for (int kk = 0; kk < 64; ++kk) {
        float4 fa = *(const float4*)(Ft + kk * 128 + rg * 8);
        float4 fb = *(const float4*)(Ft + kk * 128 + rg * 8 + 4);
        float4 wa = *(const float4*)(Ws + kk * 128 + cg * 8);
        float4 wb = *(const float4*)(Ws + kk * 128 + cg * 8 + 4);
        float fv[8] = {fa.x, fa.y, fa.z, fa.w, fb.x, fb.y, fb.z, fb.w};
        float wv[8] = {wa.x, wa.y, wa.z, wa.w, wb.x, wb.y, wb.z, wb.w};
#pragma unroll
        for (int j = 0; j < 8; ++j)
#pragma unroll
            for (int i = 0; i < 8; ++i) acc[j][i] = fmaf(fv[j], wv[i], acc[j][i]);
    }
    float ls[8] = {0,0,0,0,0,0,0,0}, lq[8] = {0,0,0,0,0,0,0,0};
    float pm[8], pn[8];
#pragma unroll
    for (int i = 0; i < 8; ++i) { pm[i] = acc[0][i]; pn[i] = acc[0][i]; }
#pragma unroll
    for (int j = 0; j < 8; ++j)
#pragma unroll
        for (int i = 0; i < 8; ++i) {
            float v = acc[j][i];
            ls[i] += v; lq[i] += v * v;
            pm[i] = fmaxf(pm[i], v); pn[i] = fminf(pn[i], v);
        }
    __syncthreads();
    float* part_s = Ft;        // [16][128]
    float* part_q = Ft + 2048; // [16][128]
    float* part_m = Ft + 4096; // [16][128]
    float* part_n = Ft + 6144; // [16][128]
#pragma unroll
    for (int i = 0; i < 8; ++i) {
        part_s[rg * 128 + cg * 8 + i] = ls[i];
        part_q[rg * 128 + cg * 8 + i] = lq[i];
        part_m[rg * 128 + cg * 8 + i] = pm[i];
        part_n[rg * 128 + cg * 8 + i] = pn[i];
    }
    __syncthreads();
    if (t < 128) {
        float s = 0.f, q = 0.f;
#pragma unroll
        for (int rgi = 0; rgi < 16; ++rgi) { s += part_s[rgi * 128 + t]; q += part_q[rgi * 128 + t]; }
        int cp = blockIdx.x & (NCOPY - 1);
        atomicAdd(&sum2[cp * 128 + t], s);
        atomicAdd(&ssq2[cp * 128 + t], q);
    }
    for (int e = t; e < 512; e += 256) {
        int g = e >> 7, c = e & 127;
        float M = part_m[(g * 4 + 0) * 128 + c];
        M = fmaxf(M, part_m[(g * 4 + 1) * 128 + c]);
        M = fmaxf(M, part_m[(g * 4 + 2) * 128 + c]);
        M = fmaxf(M, part_m[(g * 4 + 3) * 128 + c]);
        float N = part_n[(g * 4 + 0) * 128 + c];
        N = fminf(N, part_n[(g * 4 + 1) * 128 + c]);
        N = fminf(N, part_n[(g * 4 + 2) * 128 + c]);
        N = fminf(N, part_n[(g * 4 + 3) * 128 + c]);
        int grp = blockIdx.x * 4 + g;              // == b*1024 + s
        gmax[(size_t)grp * 128 + c] = M;
        gmin[(size_t)grp * 128 + c] = N;
    }
}

// ---------------- pool2: apply BN3+ReLU to pooled max/min, transposed store ----------------
__global__ __launch_bounds__(256) void k_pool2(const float* __restrict__ gmax,
                                               const float* __restrict__ gmin,
                                               const float* __restrict__ ss3,
                                               float* __restrict__ outp)
{
    int idx = blockIdx.x * 256 + threadIdx.x;      // 1,048,576 = 8*128*1024
    int b = idx >> 17;
    int c = (idx >> 10) & 127;
    int s = idx & 1023;
    int grp = (b << 10) + s;
    float a = ss3[c], sh = ss3[128 + c];
    float m = (a >= 0.f) ? gmax[(size_t)grp * 128 + c] : gmin[(size_t)grp * 128 + c];
    outp[idx] = fmaxf(0.f, fmaf(m, a, sh));
}

// ---------------- finalize BN stats -> scale/shift ----------------
__global__ void k_finalize(const float* __restrict__ sum, const float* __restrict__ ssq,
                           const float* __restrict__ g, const float* __restrict__ beta,
                           float* __restrict__ ss, int nc)
{
    int c = threadIdx.x;
    if (c >= nc) return;
    float s = 0.f, q = 0.f;
    for (int k = 0; k < NCOPY; ++k) { s += sum[k * nc + c]; q += ssq[k * nc + c]; }
    const float inv = 1.0f / 262144.0f;
    float mean = s * inv;
    float var = q * inv - mean * mean;
    float rstd = 1.0f / sqrtf(var + 1e-5f);
    float scale = g[c] * rstd;
    ss[c] = scale;
    ss[nc + c] = beta[c] - mean * scale;
}

extern "C" void kernel_launch(void* const* d_in, const int* in_sizes, int n_in,
                              void* d_out, int out_size, void* d_ws, size_t ws_size,
                              hipStream_t stream)
{
    const float* xyz    = (const float*)d_in[0];
    const float* points = (const float*)d_in[1];
    const float* w0 = (const float*)d_in[2];
    const float* b0 = (const float*)d_in[3];
    const float* gm0 = (const float*)d_in[4];
    const float* bt0 = (const float*)d_in[5];
    const float* w1 = (const float*)d_in[6];
    const float* b1 = (const float*)d_in[7];
    const float* gm1 = (const float*)d_in[8];
    const float* bt1 = (const float*)d_in[9];
    const float* w2 = (const float*)d_in[10];
    const float* b2 = (const float*)d_in[11];
    const float* gm2 = (const float*)d_in[12];
    const float* bt2 = (const float*)d_in[13];
    float* out = (float*)d_out;

    char* p = (char*)d_ws;
    auto alloc = [&](size_t nbytes) -> void* {
        void* r = (void*)p;
        p += (nbytes + 255) & ~(size_t)255;
        return r;
    };
    float4* fps_q = (float4*)alloc((size_t)NB * SP * 16);
    float* pts_t = (float*)alloc((size_t)NB * NP * CD * 4);
    float* h1 = (float*)alloc((size_t)MROWS * 64 * 4);
    float* h2 = (float*)alloc((size_t)MROWS * 64 * 4);
    float* gmax = (float*)alloc((size_t)NB * SP * 128 * 4);
    float* gmin = (float*)alloc((size_t)NB * SP * 128 * 4);
    float* Wt0 = (float*)alloc(67 * 64 * 4);
    float* Wt1 = (float*)alloc(64 * 64 * 4);
    float* Wt2 = (float*)alloc(64 * 128 * 4);
    float* stats = (float*)alloc(8192 * 4);
    float* ss1 = (float*)alloc(128 * 4);
    float* ss2 = (float*)alloc(128 * 4);
    float* ss3 = (float*)alloc(256 * 4);
    int*   ctl = (int*)alloc(4096);

    float* sum0 = stats;
    float* ssq0 = stats + 16 * 64;
    float* sum1 = stats + 2 * 16 * 64;
    float* ssq1 = stats + 3 * 16 * 64;
    float* sum2 = stats + 4 * 16 * 64;
    float* ssq2 = sum2 + 16 * 128;

    k_pre<<<NB * (NP / 64) + 1, 512, 0, stream>>>(points, pts_t, w0, w1, w2, Wt0, Wt1, Wt2, stats, ctl);
    k_mega<<<256, 512, 0, stream>>>(xyz, fps_q, out, pts_t, Wt0, b0, h1, sum0, ssq0, ctl);
    k_finalize<<<1, 128, 0, stream>>>(sum0, ssq0, gm0, bt0, ss1, 64);
    k_layer2<<<MROWS / 128, 256, 0, stream>>>(h1, Wt1, b1, ss1, h2, sum1, ssq1);
    k_finalize<<<1, 128, 0, stream>>>(sum1, ssq1, gm1, bt1, ss2, 64);
    k_layer3<<<MROWS / 128, 256, 0, stream>>>(h2, Wt2, b2, ss2, sum2, ssq2, gmax, gmin);
    k_finalize<<<1, 128, 0, stream>>>(sum2, ssq2, gm2, bt2, ss3, 128);
    k_pool2<<<(NB * SP * 128) / 256, 256, 0, stream>>>(gmax, gmin, ss3, out + 24576);
}

// Round 7
// 1234.936 us; speedup vs baseline: 1.0491x; 1.0347x over previous
//
#include <hip/hip_runtime.h>

#define NB 8
#define NP 8192
#define SP 1024
#define KS 32
#define CD 64
#define MROWS (NB*SP*KS)
#define NCOPY 16

typedef float v2f __attribute__((ext_vector_type(2)));
typedef unsigned long long u64;

// one DPP max step on a u64 key: pure VALU, no LDS. ctrl is a template param because
// __builtin_amdgcn_update_dpp requires an immediate. old=src + bound_ctrl=false ->
// lanes with no valid source keep their own value (identity for max).
template <int CTRL>
__device__ __forceinline__ u64 dpp_max_step(u64 x) {
    int lo = (int)(unsigned)(x & 0xffffffffull);
    int hi = (int)(unsigned)(x >> 32);
    int slo = __builtin_amdgcn_update_dpp(lo, lo, CTRL, 0xf, 0xf, false);
    int shi = __builtin_amdgcn_update_dpp(hi, hi, CTRL, 0xf, 0xf, false);
    u64 y = ((u64)(unsigned)shi << 32) | (unsigned)slo;
    return x > y ? x : y;
}

// ---------------- fused FPS (blocks 0..7) + points-transpose (8..1031) + weight-prep (1032) ----------
// r0-VERBATIM (941us certified, bit-exact). Rounds 1-6 post-mortems: the FPS loop is at a
// structural lockstep-serial floor — longer chain (r1), more waves (r2), fewer instructions (r3)
// all neutral-to-worse; in-kernel producer->consumer overlap (r4-r6) costs the producer ~145us
// via an unidentified mechanism and is net-negative. Do not touch this kernel.
__global__ __launch_bounds__(512, 1) void k_fps_pre(const float* __restrict__ xyz,
                                                    float* __restrict__ fps_pts,
                                                    float* __restrict__ out_nx,
                                                    const float* __restrict__ points,
                                                    float* __restrict__ pts_t,
                                                    const float* __restrict__ w0,
                                                    const float* __restrict__ w1,
                                                    const float* __restrict__ w2,
                                                    float* __restrict__ Wt0,
                                                    float* __restrict__ Wt1,
                                                    float* __restrict__ Wt2,
                                                    float* __restrict__ stats)
{
#pragma clang fp contract(off)
    __shared__ __align__(16) unsigned char smem[131072 + 256];
    const int blk = blockIdx.x;
    const int t = threadIdx.x;

    if (blk >= NB) {
        if (blk >= NB + NB * (NP / 64)) {
            // weight prep: zero stats, transpose weights to [kk][c]
            for (int i = t; i < 8192; i += 512) stats[i] = 0.f;
            for (int i = t; i < 64 * 67; i += 512) { int c = i / 67, kk = i % 67; Wt0[kk * 64 + c] = w0[i]; }
            for (int i = t; i < 64 * 64; i += 512) { int c = i >> 6, kk = i & 63; Wt1[kk * 64 + c] = w1[i]; }
            for (int i = t; i < 128 * 64; i += 512) { int c = i >> 6, kk = i & 63; Wt2[kk * 128 + c] = w2[i]; }
            return;
        }
        // points transpose (B,64,N) -> (B,N,64), 64x64 tile, 512 threads
        float (*tile)[65] = (float(*)[65])smem;
        const int tblk = blk - NB;
        const int b = tblk >> 7;
        const int n0 = (tblk & 127) << 6;
        const float* pb = points + (size_t)b * CD * NP;
        const int c = t & 63;
        const int dr = t >> 6;                 // 0..7
#pragma unroll
        for (int it = 0; it < 8; ++it) {
            int d = dr + it * 8;
            tile[d][c] = pb[(size_t)d * NP + n0 + c];
        }
        __syncthreads();
#pragma unroll
        for (int it = 0; it < 8; ++it) {
            int nn = dr + it * 8;
            pts_t[((size_t)b * NP + n0 + nn) * CD + c] = tile[c][nn];
        }
        return;
    }

    // ---- FPS path ----
    float4* s_p = (float4*)smem;               // 128 KB xyz mirror
    u64 (*s_wk)[8] = (u64(*)[8])(smem + 131072);
    const int b = blk;
    const int lane = t & 63, wid = t >> 6;     // 8 waves
    const float* xb = xyz + (size_t)b * 3 * NP;
    v2f px[8], py[8], pz[8], dv[8];
#pragma unroll
    for (int j = 0; j < 8; ++j) {
        const int n0 = t + (2 * j) * 512, n1 = n0 + 512;
        px[j] = (v2f){xb[n0], xb[n1]};
        py[j] = (v2f){xb[NP + n0], xb[NP + n1]};
        pz[j] = (v2f){xb[2 * NP + n0], xb[2 * NP + n1]};
        dv[j] = (v2f){1e10f, 1e10f};
        s_p[n0] = make_float4(px[j].x, py[j].x, pz[j].x, 0.f);
        s_p[n1] = make_float4(px[j].y, py[j].y, pz[j].y, 0.f);
    }
    float cx = xb[0], cy = xb[NP], cz = xb[2 * NP];
    float hx0 = 0.f, hy0 = 0.f, hz0 = 0.f;     // captured centroid of iteration i == t
    float hx1 = 0.f, hy1 = 0.f, hz1 = 0.f;     // captured centroid of iteration i == t + 512
    __syncthreads();
    for (int i = 0; i < SP; ++i) {
        if (i == t)       { hx0 = cx; hy0 = cy; hz0 = cz; }
        if (i == t + 512) { hx1 = cx; hy1 = cy; hz1 = cz; }
        // distance update + in-thread argmax (EXACT fp32: sub, mul, (x2+y2)+z2, min;
        // contract(off) forbids fma; ascending gid + strict > == first-index tie-break)
        float bv = -1.f; int bg = 0;
#pragma unroll
        for (int j = 0; j < 8; ++j) {
            v2f dx = px[j] - cx;
            v2f dy = py[j] - cy;
            v2f dz = pz[j] - cz;
            v2f d  = dx * dx + dy * dy;
            d = d + dz * dz;
            v2f dm = dv[j];
            dm.x = fminf(dm.x, d.x);
            dm.y = fminf(dm.y, d.y);
            dv[j] = dm;
            if (dm.x > bv) { bv = dm.x; bg = t + (2 * j) * 512; }
            if (dm.y > bv) { bv = dm.y; bg = t + (2 * j + 1) * 512; }
        }
        u64 bk = ((u64)__float_as_uint(bv) << 32) | (unsigned int)~bg;
        // per-wave DPP max ladder (VALU only); lane 63 ends with the wave max
        bk = dpp_max_step<0x111>(bk);          // row_shr:1
        bk = dpp_max_step<0x112>(bk);          // row_shr:2
        bk = dpp_max_step<0x114>(bk);          // row_shr:4
        bk = dpp_max_step<0x118>(bk);          // row_shr:8
        bk = dpp_max_step<0x142>(bk);          // row_bcast:15
        bk = dpp_max_step<0x143>(bk);          // row_bcast:31
        const int par = i & 1;
        if (lane == 63) s_wk[par][wid] = bk;   // plain overwrite, parity-dbuf'd
        __syncthreads();
        // every wave DPP-reduces the 8 leader keys (replicated twice per 16-lane row;
        // row ladder shr 1,2,4,8 -> lane 15 of each row = max over all 8 entries)
        u64 rk = s_wk[par][lane & 7];
        rk = dpp_max_step<0x111>(rk);
        rk = dpp_max_step<0x112>(rk);
        rk = dpp_max_step<0x114>(rk);
        rk = dpp_max_step<0x118>(rk);
        const int wg = ~__builtin_amdgcn_readlane((int)(unsigned)(rk & 0xffffffffull), 15);
        const float4 c = s_p[wg];              // uniform broadcast ds_read_b128
        cx = c.x; cy = c.y; cz = c.z;
        // safe without 2nd barrier: next write to s_wk[par] is 2 iters away, past the next barrier
    }
    // deferred outputs: thread t owns fps points t and t+512
    fps_pts[(b * SP + t) * 3 + 0] = hx0;
    fps_pts[(b * SP + t) * 3 + 1] = hy0;
    fps_pts[(b * SP + t) * 3 + 2] = hz0;
    fps_pts[(b * SP + t + 512) * 3 + 0] = hx1;
    fps_pts[(b * SP + t + 512) * 3 + 1] = hy1;
    fps_pts[(b * SP + t + 512) * 3 + 2] = hz1;
    out_nx[(size_t)b * 3 * SP + 0 * SP + t] = hx0;
    out_nx[(size_t)b * 3 * SP + 1 * SP + t] = hy0;
    out_nx[(size_t)b * 3 * SP + 2 * SP + t] = hz0;
    out_nx[(size_t)b * 3 * SP + 0 * SP + t + 512] = hx1;
    out_nx[(size_t)b * 3 * SP + 1 * SP + t + 512] = hy1;
    out_nx[(size_t)b * 3 * SP + 2 * SP + t + 512] = hz1;
}

// ---------------- layer1 (merged): ballquery scan + gather(feat 67) + GEMM(67->64) + stats ------
// Structure lifted from r5's consumer phase B, which passed bit-exact: 512 thr; waves 0-3 run the
// verbatim k_ballquery scan for this block's 4 groups (lists in LDS, no ball_idx round-trip)
// while waves 4-7 stage Ws; then threads 0-255 run the r0-verbatim gather/GEMM/stats.
// Data sourcing is plain loads across the kernel boundary (r0-validated coherence).
// Occupancy: 52KB LDS -> 3 blocks/CU; GEMM-active waves/CU = 12, same as the unmerged r0 pair.
__global__ __launch_bounds__(512) void k_layer1(const float* __restrict__ xyz,
                                                const float* __restrict__ pts_t,
                                                const float* __restrict__ fps_pts,
                                                const float* __restrict__ Wt0,
                                                const float* __restrict__ bias0,
                                                float* __restrict__ h1,
                                                float* __restrict__ sum0,
                                                float* __restrict__ ssq0)
{
    __shared__ __align__(16) float Ft[67 * 128];
    __shared__ __align__(16) float Ws[67 * 64];
    __shared__ int   s_idx[128];
    __shared__ float s_q[12];
    const int t = threadIdx.x;
    const int lane = t & 63, wid = t >> 6;
    const int m0 = blockIdx.x * 128;
    const int g0 = m0 >> 5;                    // == blockIdx.x * 4
    const int b = g0 >> 10;
    if (t < 12) s_q[t] = fps_pts[g0 * 3 + t];
    __syncthreads();
    // ballquery (waves 0-3, verbatim k_ballquery math) || Ws staging (waves 4-7)
    if (wid < 4) {
        const float qx = s_q[wid * 3 + 0];
        const float qy = s_q[wid * 3 + 1];
        const float qz = s_q[wid * 3 + 2];
        const float* xbq = xyz + (size_t)b * 3 * NP;
        int* list = s_idx + wid * KS;
        const float r2 = (float)(0.2 * 0.2);   // 0.039999999f — matches python double->f32
        int found = 0;
        for (int base2 = 0; base2 < NP && found < KS; base2 += 64) {
            int n = base2 + lane;
            float dx = __fsub_rn(qx, xbq[n]);
            float dy = __fsub_rn(qy, xbq[NP + n]);
            float dz = __fsub_rn(qz, xbq[2 * NP + n]);
            float d = __fadd_rn(__fadd_rn(__fmul_rn(dx, dx), __fmul_rn(dy, dy)), __fmul_rn(dz, dz));
            bool in = !(d > r2);
            unsigned long long m = __ballot(in);
            int before = __popcll(m & ((1ull << lane) - 1ull));
            int pos = found + before;
            if (in && pos < KS) list[pos] = n;
            found += __popcll(m);
        }
        int first = list[0];
        if (lane < KS) { int v = (lane < found) ? list[lane] : first; list[lane] = v; }
    } else {
        for (int i = t - 256; i < 67 * 64; i += 256) Ws[i] = Wt0[i];
    }
    __syncthreads();
    // gather (r0-verbatim, threads 0..255 active)
    if (t < 256) {
        const int r = t >> 1, half = t & 1;
        const int n = s_idx[r];
        const float* prow = pts_t + ((size_t)b * NP + n) * CD;
#pragma unroll
        for (int rep = 0; rep < 8; ++rep) {
            const int c4 = half * 4 + rep * 8;
            float4 v = *(const float4*)(prow + c4);
            Ft[(3 + c4 + 0) * 128 + r] = v.x;
            Ft[(3 + c4 + 1) * 128 + r] = v.y;
            Ft[(3 + c4 + 2) * 128 + r] = v.z;
            Ft[(3 + c4 + 3) * 128 + r] = v.w;
        }
        if (t < 128) {
            const int n2 = s_idx[t];
            const int g = t >> 5;
            const float* xbg = xyz + (size_t)b * 3 * NP;
            Ft[0 * 128 + t] = __fsub_rn(xbg[n2],          s_q[g * 3 + 0]);
            Ft[1 * 128 + t] = __fsub_rn(xbg[NP + n2],     s_q[g * 3 + 1]);
            Ft[2 * 128 + t] = __fsub_rn(xbg[2 * NP + n2], s_q[g * 3 + 2]);
        }
    }
    __syncthreads();
    const int rg = t >> 3;   // 0..31 -> rows rg*4..+3 (t<256)
    const int cg = t & 7;    // 0..7  -> cols cg*8..+7
    float ls[8] = {0,0,0,0,0,0,0,0}, lq[8] = {0,0,0,0,0,0,0,0};
    if (t < 256) {
        float4 ba = *(const float4*)(bias0 + cg * 8);
        float4 bb = *(const float4*)(bias0 + cg * 8 + 4);
        float acc[4][8];
#pragma unroll
        for (int j = 0; j < 4; ++j) {
            acc[j][0] = ba.x; acc[j][1] = ba.y; acc[j][2] = ba.z; acc[j][3] = ba.w;
            acc[j][4] = bb.x; acc[j][5] = bb.y; acc[j][6] = bb.z; acc[j][7] = bb.w;
        }
        for (int kk = 0; kk < 67; ++kk) {
            float4 f = *(const float4*)(Ft + kk * 128 + rg * 4);
            float4 wa = *(const float4*)(Ws + kk * 64 + cg * 8);
            float4 wb = *(const float4*)(Ws + kk * 64 + cg * 8 + 4);
            float fv[4] = {f.x, f.y, f.z, f.w};
            float wv[8] = {wa.x, wa.y, wa.z, wa.w, wb.x, wb.y, wb.z, wb.w};
#pragma unroll
            for (int j = 0; j < 4; ++j)
#pragma unroll
                for (int i = 0; i < 8; ++i) acc[j][i] = fmaf(fv[j], wv[i], acc[j][i]);
        }
#pragma unroll
        for (int j = 0; j < 4; ++j) {
            int m = m0 + rg * 4 + j;
            float4 oa = {acc[j][0], acc[j][1], acc[j][2], acc[j][3]};
            float4 ob = {acc[j][4], acc[j][5], acc[j][6], acc[j][7]};
            *(float4*)(h1 + (size_t)m * 64 + cg * 8) = oa;
            *(float4*)(h1 + (size_t)m * 64 + cg * 8 + 4) = ob;
#pragma unroll
            for (int i = 0; i < 8; ++i) { float v = acc[j][i]; ls[i] += v; lq[i] += v * v; }
        }
    }
    __syncthreads();           // Ft reuse for stats partials
    float* part_s = Ft;        // [32][64]
    float* part_q = Ft + 2048; // [32][64]
    if (t < 256) {
#pragma unroll
        for (int i = 0; i < 8; ++i) { part_s[rg * 64 + cg * 8 + i] = ls[i]; part_q[rg * 64 + cg * 8 + i] = lq[i]; }
    }
    __syncthreads();
    if (t < 64) {
        float s = 0.f, q = 0.f;
#pragma unroll
        for (int rgi = 0; rgi < 32; ++rgi) { s += part_s[rgi * 64 + t]; q += part_q[rgi * 64 + t]; }
        int cp = blockIdx.x & (NCOPY - 1);
        atomicAdd(&sum0[cp * 64 + t], s);
        atomicAdd(&ssq0[cp * 64 + t], q);
    }
}

// ---------------- layer2: BN1+ReLU on load + GEMM(64->64) + stats ----------------
__global__ __launch_bounds__(256) void k_layer2(const float* __restrict__ h1,
                                                const float* __restrict__ Wt1,
                                                const float* __restrict__ bias1,
                                                const float* __restrict__ ss1,
                                                float* __restrict__ h2,
                                                float* __restrict__ sum1,
                                                float* __restrict__ ssq1)
{
    __shared__ __align__(16) float Ft[64 * 128];
    __shared__ __align__(16) float Ws[64 * 64];
    __shared__ float s_sc[64], s_sh[64];
    const int t = threadIdx.x;
    const int m0 = blockIdx.x * 128;
    for (int i = t; i < 64 * 64; i += 256) Ws[i] = Wt1[i];
    if (t < 64) { s_sc[t] = ss1[t]; s_sh[t] = ss1[64 + t]; }
    __syncthreads();
    {
        const int tq = t >> 2, qq = t & 3;
#pragma unroll
        for (int rr = 0; rr < 2; ++rr) {
            const int r = rr * 64 + tq;
            const float* hrow = h1 + (size_t)(m0 + r) * 64;
#pragma unroll
            for (int rep = 0; rep < 4; ++rep) {
                const int c4 = qq * 4 + rep * 16;
                float4 v = *(const float4*)(hrow + c4);
                Ft[(c4 + 0) * 128 + r] = fmaxf(0.f, fmaf(v.x, s_sc[c4 + 0], s_sh[c4 + 0]));
                Ft[(c4 + 1) * 128 + r] = fmaxf(0.f, fmaf(v.y, s_sc[c4 + 1], s_sh[c4 + 1]));
                Ft[(c4 + 2) * 128 + r] = fmaxf(0.f, fmaf(v.z, s_sc[c4 + 2], s_sh[c4 + 2]));
                Ft[(c4 + 3) * 128 + r] = fmaxf(0.f, fmaf(v.w, s_sc[c4 + 3], s_sh[c4 + 3]));
            }
        }
    }
    __syncthreads();
    const int rg = t >> 3;
    const int cg = t & 7;
    float4 ba = *(const float4*)(bias1 + cg * 8);
    float4 bb = *(const float4*)(bias1 + cg * 8 + 4);
    float acc[4][8];
#pragma unroll
    for (int j = 0; j < 4; ++j) {
        acc[j][0] = ba.x; acc[j][1] = ba.y; acc[j][2] = ba.z; acc[j][3] = ba.w;
        acc[j][4] = bb.x; acc[j][5] = bb.y; acc[j][6] = bb.z; acc[j][7] = bb.w;
    }
    for (int kk = 0; kk < 64; ++kk) {
        float4 f = *(const float4*)(Ft + kk * 128 + rg * 4);
        float4 wa = *(const float4*)(Ws + kk * 64 + cg * 8);
        float4 wb = *(const float4*)(Ws + kk * 64 + cg * 8 + 4);
        float fv[4] = {f.x, f.y, f.z, f.w};
        float wv[8] = {wa.x, wa.y, wa.z, wa.w, wb.x, wb.y, wb.z, wb.w};
#pragma unroll
        for (int j = 0; j < 4; ++j)
#pragma unroll
            for (int i = 0; i < 8; ++i) acc[j][i] = fmaf(fv[j], wv[i], acc[j][i]);
    }
    float ls[8] = {0,0,0,0,0,0,0,0}, lq[8] = {0,0,0,0,0,0,0,0};
#pragma unroll
    for (int j = 0; j < 4; ++j) {
        int m = m0 + rg * 4 + j;
        float4 oa = {acc[j][0], acc[j][1], acc[j][2], acc[j][3]};
        float4 ob = {acc[j][4], acc[j][5], acc[j][6], acc[j][7]};
        *(float4*)(h2 + (size_t)m * 64 + cg * 8) = oa;
        *(float4*)(h2 + (size_t)m * 64 + cg * 8 + 4) = ob;
#pragma unroll
        for (int i = 0; i < 8; ++i) { float v = acc[j][i]; ls[i] += v; lq[i] += v * v; }
    }
    __syncthreads();
    float* part_s = Ft;
    float* part_q = Ft + 2048;
#pragma unroll
    for (int i = 0; i < 8; ++i) { part_s[rg * 64 + cg * 8 + i] = ls[i]; part_q[rg * 64 + cg * 8 + i] = lq[i]; }
    __syncthreads();
    if (t < 64) {
        float s = 0.f, q = 0.f;
#pragma unroll
        for (int rgi = 0; rgi < 32; ++rgi) { s += part_s[rgi * 64 + t]; q += part_q[rgi * 64 + t]; }
        int cp = blockIdx.x & (NCOPY - 1);
        atomicAdd(&sum1[cp * 64 + t], s);
        atomicAdd(&ssq1[cp * 64 + t], q);
    }
}

// ---------------- layer3: BN2+ReLU + GEMM(64->128) + stats + per-group max/min ----------------
// Pooling trick: max_k relu(a*h+b) == relu(a*max_k h + b) for a>=0 (min_k for a<0),
// exact in fp32 by monotonicity of fmaf/relu. So h3 is never materialized.
__global__ __launch_bounds__(256) void k_layer3(const float* __restrict__ h2,
                                                const float* __restrict__ Wt2,
                                                const float* __restrict__ bias2,
                                                const float* __restrict__ ss2,
                                                float* __restrict__ sum2,
                                                float* __restrict__ ssq2,
                                                float* __restrict__ gmax,
                                                float* __restrict__ gmin)
{
    __shared__ __align__(16) float Ft[64 * 128];
    __shared__ __align__(16) float Ws[64 * 128];
    __shared__ float s_sc[64], s_sh[64];
    const int t = threadIdx.x;
    const int m0 = blockIdx.x * 128;
    for (int i = t; i < 64 * 128; i += 256) Ws[i] = Wt2[i];
    if (t < 64) { s_sc[t] = ss2[t]; s_sh[t] = ss2[64 + t]; }
    __syncthreads();
    {
        const int tq = t >> 2, qq = t & 3;
#pragma unroll
        for (int rr = 0; rr < 2; ++rr) {
            const int r = rr * 64 + tq;
            const float* hrow = h2 + (size_t)(m0 + r) * 64;
#pragma unroll
            for (int rep = 0; rep < 4; ++rep) {
                const int c4 = qq * 4 + rep * 16;
                float4 v = *(const float4*)(hrow + c4);
                Ft[(c4 + 0) * 128 + r] = fmaxf(0.f, fmaf(v.x, s_sc[c4 + 0], s_sh[c4 + 0]));
                Ft[(c4 + 1) * 128 + r] = fmaxf(0.f, fmaf(v.y, s_sc[c4 + 1], s_sh[c4 + 1]));
                Ft[(c4 + 2) * 128 + r] = fmaxf(0.f, fmaf(v.z, s_sc[c4 + 2], s_sh[c4 + 2]));
                Ft[(c4 + 3) * 128 + r] = fmaxf(0.f, fmaf(v.w, s_sc[c4 + 3], s_sh[c4 + 3]));
            }
        }
    }
    __syncthreads();
    const int rg = t >> 4;  // 0..15 -> rows rg*8..+7  (all within group rg>>2)
    const int cg = t & 15;  // 0..15 -> cols cg*8..+7
    float4 ba = *(const float4*)(bias2 + cg * 8);
    float4 bb = *(const float4*)(bias2 + cg * 8 + 4);
    float acc[8][8];
#pragma unroll
    for (int j = 0; j < 8; ++j) {
        acc[j][0] = ba.x; acc[j][1] = ba.y; acc[j][2] = ba.z; acc[j][3] = ba.w;
        acc[j][4] = bb.x; acc[j][5] = bb.y; acc[j][6] = bb.z; acc[j][7] = bb.w;
    }
    for (int kk = 0; kk < 64; ++kk) {
        float4 fa = *(const float4*)(Ft + kk * 128 + rg * 8);
        float4 fb = *(const float4*)(Ft + kk * 128 + rg * 8 + 4);
        float4 wa = *(const float4*)(Ws + kk * 128 + cg * 8);
        float4 wb = *(const float4*)(Ws + kk * 128 + cg * 8 + 4);
        float fv[8] = {fa.x, fa.y, fa.z, fa.w, fb.x, fb.y, fb.z, fb.w};
        float wv[8] = {wa.x, wa.y, wa.z, wa.w, wb.x, wb.y, wb.z, wb.w};
#pragma unroll
        for (int j = 0; j < 8; ++j)
#pragma unroll
            for (int i = 0; i < 8; ++i) acc[j][i] = fmaf(fv[j], wv[i], acc[j][i]);
    }
    float ls[8] = {0,0,0,0,0,0,0,0}, lq[8] = {0,0,0,0,0,0,0,0};
    float pm[8], pn[8];
#pragma unroll
    for (int i = 0; i < 8; ++i) { pm[i] = acc[0][i]; pn[i] = acc[0][i]; }
#pragma unroll
    for (int j = 0; j < 8; ++j)
#pragma unroll
        for (int i = 0; i < 8; ++i) {
            float v = acc[j][i];
            ls[i] += v; lq[i] += v * v;
            pm[i] = fmaxf(pm[i], v); pn[i] = fminf(pn[i], v);
        }
    __syncthreads();
    float* part_s = Ft;        // [16][128]
    float* part_q = Ft + 2048; // [16][128]
    float* part_m = Ft + 4096; // [16][128]
    float* part_n = Ft + 6144; // [16][128]
#pragma unroll
    for (int i = 0; i < 8; ++i) {
        part_s[rg * 128 + cg * 8 + i] = ls[i];
        part_q[rg * 128 + cg * 8 + i] = lq[i];
        part_m[rg * 128 + cg * 8 + i] = pm[i];
        part_n[rg * 128 + cg * 8 + i] = pn[i];
    }
    __syncthreads();
    if (t < 128) {
        float s = 0.f, q = 0.f;
#pragma unroll
        for (int rgi = 0; rgi < 16; ++rgi) { s += part_s[rgi * 128 + t]; q += part_q[rgi * 128 + t]; }
        int cp = blockIdx.x & (NCOPY - 1);
        atomicAdd(&sum2[cp * 128 + t], s);
        atomicAdd(&ssq2[cp * 128 + t], q);
    }
    for (int e = t; e < 512; e += 256) {
        int g = e >> 7, c = e & 127;
        float M = part_m[(g * 4 + 0) * 128 + c];
        M = fmaxf(M, part_m[(g * 4 + 1) * 128 + c]);
        M = fmaxf(M, part_m[(g * 4 + 2) * 128 + c]);
        M = fmaxf(M, part_m[(g * 4 + 3) * 128 + c]);
        float N = part_n[(g * 4 + 0) * 128 + c];
        N = fminf(N, part_n[(g * 4 + 1) * 128 + c]);
        N = fminf(N, part_n[(g * 4 + 2) * 128 + c]);
        N = fminf(N, part_n[(g * 4 + 3) * 128 + c]);
        int grp = blockIdx.x * 4 + g;              // == b*1024 + s
        gmax[(size_t)grp * 128 + c] = M;
        gmin[(size_t)grp * 128 + c] = N;
    }
}

// ---------------- pool2: apply BN3+ReLU to pooled max/min, transposed store ----------------
__global__ __launch_bounds__(256) void k_pool2(const float* __restrict__ gmax,
                                               const float* __restrict__ gmin,
                                               const float* __restrict__ ss3,
                                               float* __restrict__ outp)
{
    int idx = blockIdx.x * 256 + threadIdx.x;      // 1,048,576 = 8*128*1024
    int b = idx >> 17;
    int c = (idx >> 10) & 127;
    int s = idx & 1023;
    int grp = (b << 10) + s;
    float a = ss3[c], sh = ss3[128 + c];
    float m = (a >= 0.f) ? gmax[(size_t)grp * 128 + c] : gmin[(size_t)grp * 128 + c];
    outp[idx] = fmaxf(0.f, fmaf(m, a, sh));
}

// ---------------- finalize BN stats -> scale/shift ----------------
__global__ void k_finalize(const float* __restrict__ sum, const float* __restrict__ ssq,
                           const float* __restrict__ g, const float* __restrict__ beta,
                           float* __restrict__ ss, int nc)
{
    int c = threadIdx.x;
    if (c >= nc) return;
    float s = 0.f, q = 0.f;
    for (int k = 0; k < NCOPY; ++k) { s += sum[k * nc + c]; q += ssq[k * nc + c]; }
    const float inv = 1.0f / 262144.0f;
    float mean = s * inv;
    float var = q * inv - mean * mean;
    float rstd = 1.0f / sqrtf(var + 1e-5f);
    float scale = g[c] * rstd;
    ss[c] = scale;
    ss[nc + c] = beta[c] - mean * scale;
}

extern "C" void kernel_launch(void* const* d_in, const int* in_sizes, int n_in,
                              void* d_out, int out_size, void* d_ws, size_t ws_size,
                              hipStream_t stream)
{
    const float* xyz    = (const float*)d_in[0];
    const float* points = (const float*)d_in[1];
    const float* w0 = (const float*)d_in[2];
    const float* b0 = (const float*)d_in[3];
    const float* gm0 = (const float*)d_in[4];
    const float* bt0 = (const float*)d_in[5];
    const float* w1 = (const float*)d_in[6];
    const float* b1 = (const float*)d_in[7];
    const float* gm1 = (const float*)d_in[8];
    const float* bt1 = (const float*)d_in[9];
    const float* w2 = (const float*)d_in[10];
    const float* b2 = (const float*)d_in[11];
    const float* gm2 = (const float*)d_in[12];
    const float* bt2 = (const float*)d_in[13];
    float* out = (float*)d_out;

    char* p = (char*)d_ws;
    auto alloc = [&](size_t nbytes) -> void* {
        void* r = (void*)p;
        p += (nbytes + 255) & ~(size_t)255;
        return r;
    };
    float* fps_pts = (float*)alloc((size_t)NB * SP * 3 * 4);
    float* pts_t = (float*)alloc((size_t)NB * NP * CD * 4);
    float* h1 = (float*)alloc((size_t)MROWS * 64 * 4);
    float* h2 = (float*)alloc((size_t)MROWS * 64 * 4);
    float* gmax = (float*)alloc((size_t)NB * SP * 128 * 4);
    float* gmin = (float*)alloc((size_t)NB * SP * 128 * 4);
    float* Wt0 = (float*)alloc(67 * 64 * 4);
    float* Wt1 = (float*)alloc(64 * 64 * 4);
    float* Wt2 = (float*)alloc(64 * 128 * 4);
    float* stats = (float*)alloc(8192 * 4);
    float* ss1 = (float*)alloc(128 * 4);
    float* ss2 = (float*)alloc(128 * 4);
    float* ss3 = (float*)alloc(256 * 4);

    float* sum0 = stats;
    float* ssq0 = stats + 16 * 64;
    float* sum1 = stats + 2 * 16 * 64;
    float* ssq1 = stats + 3 * 16 * 64;
    float* sum2 = stats + 4 * 16 * 64;
    float* ssq2 = sum2 + 16 * 128;

    k_fps_pre<<<NB + NB * (NP / 64) + 1, 512, 0, stream>>>(
        xyz, fps_pts, out, points, pts_t, w0, w1, w2, Wt0, Wt1, Wt2, stats);
    k_layer1<<<MROWS / 128, 512, 0, stream>>>(xyz, pts_t, fps_pts, Wt0, b0, h1, sum0, ssq0);
    k_finalize<<<1, 128, 0, stream>>>(sum0, ssq0, gm0, bt0, ss1, 64);
    k_layer2<<<MROWS / 128, 256, 0, stream>>>(h1, Wt1, b1, ss1, h2, sum1, ssq1);
    k_finalize<<<1, 128, 0, stream>>>(sum1, ssq1, gm1, bt1, ss2, 64);
    k_layer3<<<MROWS / 128, 256, 0, stream>>>(h2, Wt2, b2, ss2, sum2, ssq2, gmax, gmin);
    k_finalize<<<1, 128, 0, stream>>>(sum2, ssq2, gm2, bt2, ss3, 128);
    k_pool2<<<(NB * SP * 128) / 256, 256, 0, stream>>>(gmax, gmin, ss3, out + 24576);
}

// Round 8
// 1201.898 us; speedup vs baseline: 1.0779x; 1.0275x over previous
//
#include <hip/hip_runtime.h>

#define NB 8
#define NP 8192
#define SP 1024
#define KS 32
#define CD 64
#define MROWS (NB*SP*KS)
#define NCOPY 16

typedef float v2f __attribute__((ext_vector_type(2)));
typedef unsigned long long u64;

// one DPP max step on a u64 key: pure VALU, no LDS. ctrl is a template param because
// __builtin_amdgcn_update_dpp requires an immediate. old=src + bound_ctrl=false ->
// lanes with no valid source keep their own value (identity for max).
template <int CTRL>
__device__ __forceinline__ u64 dpp_max_step(u64 x) {
    int lo = (int)(unsigned)(x & 0xffffffffull);
    int hi = (int)(unsigned)(x >> 32);
    int slo = __builtin_amdgcn_update_dpp(lo, lo, CTRL, 0xf, 0xf, false);
    int shi = __builtin_amdgcn_update_dpp(hi, hi, CTRL, 0xf, 0xf, false);
    u64 y = ((u64)(unsigned)shi << 32) | (unsigned)slo;
    return x > y ? x : y;
}

// ---------------- fused FPS (blocks 0..7) + points-transpose (8..1031) + weight-prep (1032) ----------
// FPS r8: Morton-sorted, bound-pruned EXACT FPS.
//  - One-time LDS counting sort of the 8192 points by 8x8x8 Morton cell; each thread owns 16
//    CONSECUTIVE sorted points (spatially tight chunk) with a bbox and cellmax = max dv.
//  - Per iteration, a wave skips the whole distance phase iff ALL its chunks satisfy
//    dmin2(c,bbox)*0.999 >= cellmax  (conservative: 1e-3 slack >> 1e-6 fp32 rounding, so a
//    skipped chunk provably has d(p,c) >= dv(p) for every p -> no dv changes -> its cached
//    wave key is exactly what recomputation would give; keys are non-increasing).
//  - key = (dist_bits<<32) | (8191-orig_gid)<<13 | sorted_pos : u64 max == (max dist, tie ->
//    min ORIGINAL gid) — bit-identical tie-break to the reference argmax; pos field only
//    locates the winner in s_p and can never affect ordering (same dist+gid => same point).
//  - Distance dag identical to the certified r0 loop: sub, mul, (x2+y2)+z2, fminf,
//    contract(off). Sort order cannot affect results (max-key is partition-independent).
// The serial skeleton (one barrier/iter, parity-dbuf s_wk, 4-step cross-wave reduce,
// readlane(15), uniform s_p broadcast) is r0-verbatim.
__global__ __launch_bounds__(512, 1) void k_fps_pre(const float* __restrict__ xyz,
                                                    float* __restrict__ fps_pts,
                                                    float* __restrict__ out_nx,
                                                    const float* __restrict__ points,
                                                    float* __restrict__ pts_t,
                                                    const float* __restrict__ w0,
                                                    const float* __restrict__ w1,
                                                    const float* __restrict__ w2,
                                                    float* __restrict__ Wt0,
                                                    float* __restrict__ Wt1,
                                                    float* __restrict__ Wt2,
                                                    float* __restrict__ stats)
{
#pragma clang fp contract(off)
    __shared__ __align__(16) unsigned char smem[131072 + 2560];
    const int blk = blockIdx.x;
    const int t = threadIdx.x;

    if (blk >= NB) {
        if (blk >= NB + NB * (NP / 64)) {
            // weight prep: zero stats, transpose weights to [kk][c]
            for (int i = t; i < 8192; i += 512) stats[i] = 0.f;
            for (int i = t; i < 64 * 67; i += 512) { int c = i / 67, kk = i % 67; Wt0[kk * 64 + c] = w0[i]; }
            for (int i = t; i < 64 * 64; i += 512) { int c = i >> 6, kk = i & 63; Wt1[kk * 64 + c] = w1[i]; }
            for (int i = t; i < 128 * 64; i += 512) { int c = i >> 6, kk = i & 63; Wt2[kk * 128 + c] = w2[i]; }
            return;
        }
        // points transpose (B,64,N) -> (B,N,64), 64x64 tile, 512 threads
        float (*tile)[65] = (float(*)[65])smem;
        const int tblk = blk - NB;
        const int b = tblk >> 7;
        const int n0 = (tblk & 127) << 6;
        const float* pb = points + (size_t)b * CD * NP;
        const int c = t & 63;
        const int dr = t >> 6;                 // 0..7
#pragma unroll
        for (int it = 0; it < 8; ++it) {
            int d = dr + it * 8;
            tile[d][c] = pb[(size_t)d * NP + n0 + c];
        }
        __syncthreads();
#pragma unroll
        for (int it = 0; it < 8; ++it) {
            int nn = dr + it * 8;
            pts_t[((size_t)b * NP + n0 + nn) * CD + c] = tile[c][nn];
        }
        return;
    }

    // ---- FPS path ----
    float4* s_p  = (float4*)smem;                          // 128 KB sorted pts (xyz + gid bits)
    int*    s_cnt = (int*)(smem + 131072);                 // 512 cell counts/offsets
    u64 (*s_wk)[8] = (u64(*)[8])(smem + 131072 + 2048);    // parity-dbuf leader keys
    const int b = blk;
    const int lane = t & 63, wid = t >> 6;                 // 8 waves
    const float* xb = xyz + (size_t)b * 3 * NP;

    // -- one-time Morton counting sort --
    float lx[16], ly[16], lz[16];
    int   lcell[16];
    s_cnt[t < 512 ? t : 0] = 0;                            // t in [0,512): zero own slot
    __syncthreads();
#pragma unroll
    for (int j = 0; j < 16; ++j) {
        const int n = t + j * 512;                         // r0-coalesced load
        lx[j] = xb[n]; ly[j] = xb[NP + n]; lz[j] = xb[2 * NP + n];
        int ix = (int)(lx[j] * 8.f); ix = ix < 0 ? 0 : (ix > 7 ? 7 : ix);
        int iy = (int)(ly[j] * 8.f); iy = iy < 0 ? 0 : (iy > 7 ? 7 : iy);
        int iz = (int)(lz[j] * 8.f); iz = iz < 0 ? 0 : (iz > 7 ? 7 : iz);
        int sx = ((ix & 4) << 4) | ((ix & 2) << 2) | (ix & 1);
        int sy = ((iy & 4) << 4) | ((iy & 2) << 2) | (iy & 1);
        int sz = ((iz & 4) << 4) | ((iz & 2) << 2) | (iz & 1);
        lcell[j] = (sx << 2) | (sy << 1) | sz;             // Morton id, 0..511
        atomicAdd(&s_cnt[lcell[j]], 1);
    }
    __syncthreads();
    if (t == 0) {                                          // exclusive prefix (one-time ~2us)
        int run = 0;
        for (int c2 = 0; c2 < 512; ++c2) { int v = s_cnt[c2]; s_cnt[c2] = run; run += v; }
    }
    __syncthreads();
#pragma unroll
    for (int j = 0; j < 16; ++j) {
        int pos = atomicAdd(&s_cnt[lcell[j]], 1);
        s_p[pos] = make_float4(lx[j], ly[j], lz[j], __uint_as_float((unsigned)(t + j * 512)));
    }
    __syncthreads();
    // -- reload sorted chunk [16t, 16t+16): coords, key low-words, bbox --
    float px[16], py[16], pz[16], dv16[16];
    unsigned klo[16];
    float blx = 1e30f, bly = 1e30f, blz = 1e30f, bhx = -1e30f, bhy = -1e30f, bhz = -1e30f;
#pragma unroll
    for (int j = 0; j < 16; ++j) {
        float4 v = s_p[16 * t + j];
        px[j] = v.x; py[j] = v.y; pz[j] = v.z;
        unsigned g = __float_as_uint(v.w);                 // original gid (raw bits)
        klo[j] = ((8191u - g) << 13) | (unsigned)(16 * t + j);
        dv16[j] = 1e10f;
        blx = fminf(blx, v.x); bhx = fmaxf(bhx, v.x);
        bly = fminf(bly, v.y); bhy = fmaxf(bhy, v.y);
        blz = fminf(blz, v.z); bhz = fmaxf(bhz, v.z);
    }
    float cx = xb[0], cy = xb[NP], cz = xb[2 * NP];
    float cellmax = 1e10f;                                 // max dv over this thread's chunk
    u64 wkey = 0;                                          // lane63's cached wave key
    float hx0 = 0.f, hy0 = 0.f, hz0 = 0.f;                 // captured centroid of iteration i == t
    float hx1 = 0.f, hy1 = 0.f, hz1 = 0.f;                 // captured centroid of iteration i == t + 512
    __syncthreads();
    for (int i = 0; i < SP; ++i) {
        if (i == t)       { hx0 = cx; hy0 = cy; hz0 = cz; }
        if (i == t + 512) { hx1 = cx; hy1 = cy; hz1 = cz; }
        // conservative bound: skip iff dmin2(c,bbox)*0.999 >= cellmax (slack >> fp32 rounding)
        float ddx = fmaxf(fmaxf(blx - cx, cx - bhx), 0.f);
        float ddy = fmaxf(fmaxf(bly - cy, cy - bhy), 0.f);
        float ddz = fmaxf(fmaxf(blz - cz, cz - bhz), 0.f);
        float dmin = ddx * ddx + ddy * ddy;
        dmin = dmin + ddz * ddz;
        bool act = (dmin * 0.999f < cellmax);
        if (__ballot(act)) {
            // full update for this wave (EXACT fp32: same dag as r0 — sub, mul, (x2+y2)+z2, min)
            u64 bk = 0; float cm = 0.f;
#pragma unroll
            for (int j = 0; j < 16; ++j) {
                float dx = px[j] - cx;
                float dy = py[j] - cy;
                float dz = pz[j] - cz;
                float d = dx * dx + dy * dy;
                d = d + dz * dz;
                float nd = fminf(dv16[j], d);
                dv16[j] = nd;
                cm = fmaxf(cm, nd);
                u64 k = ((u64)__float_as_uint(nd) << 32) | klo[j];
                bk = bk > k ? bk : k;
            }
            cellmax = cm;
            // per-wave DPP max ladder (r0-verbatim); lane 63 ends with the wave max
            bk = dpp_max_step<0x111>(bk);      // row_shr:1
            bk = dpp_max_step<0x112>(bk);      // row_shr:2
            bk = dpp_max_step<0x114>(bk);      // row_shr:4
            bk = dpp_max_step<0x118>(bk);      // row_shr:8
            bk = dpp_max_step<0x142>(bk);      // row_bcast:15
            bk = dpp_max_step<0x143>(bk);      // row_bcast:31
            wkey = bk;
        }
        const int par = i & 1;
        if (lane == 63) s_wk[par][wid] = wkey; // cached key if wave skipped (exactly equal by invariance)
        __syncthreads();
        // cross-wave reduce (r0-verbatim): 8 leader keys replicated twice per 16-lane row
        u64 rk = s_wk[par][lane & 7];
        rk = dpp_max_step<0x111>(rk);
        rk = dpp_max_step<0x112>(rk);
        rk = dpp_max_step<0x114>(rk);
        rk = dpp_max_step<0x118>(rk);
        const int wlo = __builtin_amdgcn_readlane((int)(unsigned)(rk & 0xffffffffull), 15);
        const int wpos = wlo & 0x1FFF;         // sorted position of the winner
        const float4 c = s_p[wpos];            // uniform broadcast ds_read_b128
        cx = c.x; cy = c.y; cz = c.z;
        // safe without 2nd barrier: next write to s_wk[par] is 2 iters away, past the next barrier
    }
    // deferred outputs: thread t owns fps points t and t+512
    fps_pts[(b * SP + t) * 3 + 0] = hx0;
    fps_pts[(b * SP + t) * 3 + 1] = hy0;
    fps_pts[(b * SP + t) * 3 + 2] = hz0;
    fps_pts[(b * SP + t + 512) * 3 + 0] = hx1;
    fps_pts[(b * SP + t + 512) * 3 + 1] = hy1;
    fps_pts[(b * SP + t + 512) * 3 + 2] = hz1;
    out_nx[(size_t)b * 3 * SP + 0 * SP + t] = hx0;
    out_nx[(size_t)b * 3 * SP + 1 * SP + t] = hy0;
    out_nx[(size_t)b * 3 * SP + 2 * SP + t] = hz0;
    out_nx[(size_t)b * 3 * SP + 0 * SP + t + 512] = hx1;
    out_nx[(size_t)b * 3 * SP + 1 * SP + t + 512] = hy1;
    out_nx[(size_t)b * 3 * SP + 2 * SP + t + 512] = hz1;
}

// ---------------- ball query: one wave per query, ordered first-32 append (r0-verbatim) --------
__global__ __launch_bounds__(256) void k_ballquery(const float* __restrict__ xyz,
                                                   const float* __restrict__ fps_pts,
                                                   int* __restrict__ ball_idx)
{
    const int wib = threadIdx.x >> 6;
    const int lane = threadIdx.x & 63;
    const int wid = blockIdx.x * 4 + wib;          // b*SP + s
    const int b = wid >> 10;
    const float* xb = xyz + (size_t)b * 3 * NP;
    const float qx = fps_pts[wid * 3 + 0];
    const float qy = fps_pts[wid * 3 + 1];
    const float qz = fps_pts[wid * 3 + 2];
    __shared__ int s_list[4][KS];
    int* list = s_list[wib];
    const float r2 = (float)(0.2 * 0.2);           // 0.039999999f — matches python double->f32
    int found = 0;
    for (int base = 0; base < NP && found < KS; base += 64) {
        int n = base + lane;
        float dx = __fsub_rn(qx, xb[n]);
        float dy = __fsub_rn(qy, xb[NP + n]);
        float dz = __fsub_rn(qz, xb[2 * NP + n]);
        float d = __fadd_rn(__fadd_rn(__fmul_rn(dx, dx), __fmul_rn(dy, dy)), __fmul_rn(dz, dz));
        bool in = !(d > r2);
        unsigned long long m = __ballot(in);
        int before = __popcll(m & ((1ull << lane) - 1ull));
        int pos = found + before;
        if (in && pos < KS) list[pos] = n;
        found += __popcll(m);
    }
    int first = list[0];
    if (lane < KS) {
        int v = (lane < found) ? list[lane] : first;
        ball_idx[wid * KS + lane] = v;
    }
}

// ---------------- layer1: gather(feat 67) + GEMM(67->64) + stats (r0-verbatim) ----------------
__global__ __launch_bounds__(256) void k_layer1(const float* __restrict__ xyz,
                                                const float* __restrict__ pts_t,
                                                const float* __restrict__ fps_pts,
                                                const int* __restrict__ ball_idx,
                                                const float* __restrict__ Wt0,
                                                const float* __restrict__ bias0,
                                                float* __restrict__ h1,
                                                float* __restrict__ sum0,
                                                float* __restrict__ ssq0)
{
    __shared__ __align__(16) float Ft[67 * 128];
    __shared__ __align__(16) float Ws[67 * 64];
    __shared__ int   s_idx[128];
    __shared__ float s_q[4][3];
    const int t = threadIdx.x;
    const int m0 = blockIdx.x * 128;
    const int g0 = m0 >> 5;
    const int b = g0 >> 10;
    if (t < 128) s_idx[t] = ball_idx[g0 * KS + t];
    if (t < 12) ((float*)s_q)[t] = fps_pts[g0 * 3 + t];
    for (int i = t; i < 67 * 64; i += 256) Ws[i] = Wt0[i];
    __syncthreads();
    {
        const int r = t >> 1, half = t & 1;
        const int n = s_idx[r];
        const float* prow = pts_t + ((size_t)b * NP + n) * CD;
#pragma unroll
        for (int rep = 0; rep < 8; ++rep) {
            const int c4 = half * 4 + rep * 8;
            float4 v = *(const float4*)(prow + c4);
            Ft[(3 + c4 + 0) * 128 + r] = v.x;
            Ft[(3 + c4 + 1) * 128 + r] = v.y;
            Ft[(3 + c4 + 2) * 128 + r] = v.z;
            Ft[(3 + c4 + 3) * 128 + r] = v.w;
        }
        if (t < 128) {
            const int n2 = s_idx[t];
            const int g = t >> 5;
            const float* xb = xyz + (size_t)b * 3 * NP;
            Ft[0 * 128 + t] = __fsub_rn(xb[n2],          s_q[g][0]);
            Ft[1 * 128 + t] = __fsub_rn(xb[NP + n2],     s_q[g][1]);
            Ft[2 * 128 + t] = __fsub_rn(xb[2 * NP + n2], s_q[g][2]);
        }
    }
    __syncthreads();
    const int rg = t >> 3;   // 0..31 -> rows rg*4..+3
    const int cg = t & 7;    // 0..7  -> cols cg*8..+7
    float4 ba = *(const float4*)(bias0 + cg * 8);
    float4 bb = *(const float4*)(bias0 + cg * 8 + 4);
    float acc[4][8];
#pragma unroll
    for (int j = 0; j < 4; ++j) {
        acc[j][0] = ba.x; acc[j][1] = ba.y; acc[j][2] = ba.z; acc[j][3] = ba.w;
        acc[j][4] = bb.x; acc[j][5] = bb.y; acc[j][6] = bb.z; acc[j][7] = bb.w;
    }
    for (int kk = 0; kk < 67; ++kk) {
        float4 f = *(const float4*)(Ft + kk * 128 + rg * 4);
        float4 wa = *(const float4*)(Ws + kk * 64 + cg * 8);
        float4 wb = *(const float4*)(Ws + kk * 64 + cg * 8 + 4);
        float fv[4] = {f.x, f.y, f.z, f.w};
        float wv[8] = {wa.x, wa.y, wa.z, wa.w, wb.x, wb.y, wb.z, wb.w};
#pragma unroll
        for (int j = 0; j < 4; ++j)
#pragma unroll
            for (int i = 0; i < 8; ++i) acc[j][i] = fmaf(fv[j], wv[i], acc[j][i]);
    }
    float ls[8] = {0,0,0,0,0,0,0,0}, lq[8] = {0,0,0,0,0,0,0,0};
#pragma unroll
    for (int j = 0; j < 4; ++j) {
        int m = m0 + rg * 4 + j;
        float4 oa = {acc[j][0], acc[j][1], acc[j][2], acc[j][3]};
        float4 ob = {acc[j][4], acc[j][5], acc[j][6], acc[j][7]};
        *(float4*)(h1 + (size_t)m * 64 + cg * 8) = oa;
        *(float4*)(h1 + (size_t)m * 64 + cg * 8 + 4) = ob;
#pragma unroll
        for (int i = 0; i < 8; ++i) { float v = acc[j][i]; ls[i] += v; lq[i] += v * v; }
    }
    __syncthreads();           // Ft reuse for stats partials
    float* part_s = Ft;        // [32][64]
    float* part_q = Ft + 2048; // [32][64]
#pragma unroll
    for (int i = 0; i < 8; ++i) { part_s[rg * 64 + cg * 8 + i] = ls[i]; part_q[rg * 64 + cg * 8 + i] = lq[i]; }
    __syncthreads();
    if (t < 64) {
        float s = 0.f, q = 0.f;
#pragma unroll
        for (int rgi = 0; rgi < 32; ++rgi) { s += part_s[rgi * 64 + t]; q += part_q[rgi * 64 + t]; }
        int cp = blockIdx.x & (NCOPY - 1);
        atomicAdd(&sum0[cp * 64 + t], s);
        atomicAdd(&ssq0[cp * 64 + t], q);
    }
}

// ---------------- layer2: BN1+ReLU on load + GEMM(64->64) + stats ----------------
__global__ __launch_bounds__(256) void k_layer2(const float* __restrict__ h1,
                                                const float* __restrict__ Wt1,
                                                const float* __restrict__ bias1,
                                                const float* __restrict__ ss1,
                                                float* __restrict__ h2,
                                                float* __restrict__ sum1,
                                                float* __restrict__ ssq1)
{
    __shared__ __align__(16) float Ft[64 * 128];
    __shared__ __align__(16) float Ws[64 * 64];
    __shared__ float s_sc[64], s_sh[64];
    const int t = threadIdx.x;
    const int m0 = blockIdx.x * 128;
    for (int i = t; i < 64 * 64; i += 256) Ws[i] = Wt1[i];
    if (t < 64) { s_sc[t] = ss1[t]; s_sh[t] = ss1[64 + t]; }
    __syncthreads();
    {
        const int tq = t >> 2, qq = t & 3;
#pragma unroll
        for (int rr = 0; rr < 2; ++rr) {
            const int r = rr * 64 + tq;
            const float* hrow = h1 + (size_t)(m0 + r) * 64;
#pragma unroll
            for (int rep = 0; rep < 4; ++rep) {
                const int c4 = qq * 4 + rep * 16;
                float4 v = *(const float4*)(hrow + c4);
                Ft[(c4 + 0) * 128 + r] = fmaxf(0.f, fmaf(v.x, s_sc[c4 + 0], s_sh[c4 + 0]));
                Ft[(c4 + 1) * 128 + r] = fmaxf(0.f, fmaf(v.y, s_sc[c4 + 1], s_sh[c4 + 1]));
                Ft[(c4 + 2) * 128 + r] = fmaxf(0.f, fmaf(v.z, s_sc[c4 + 2], s_sh[c4 + 2]));
                Ft[(c4 + 3) * 128 + r] = fmaxf(0.f, fmaf(v.w, s_sc[c4 + 3], s_sh[c4 + 3]));
            }
        }
    }
    __syncthreads();
    const int rg = t >> 3;
    const int cg = t & 7;
    float4 ba = *(const float4*)(bias1 + cg * 8);
    float4 bb = *(const float4*)(bias1 + cg * 8 + 4);
    float acc[4][8];
#pragma unroll
    for (int j = 0; j < 4; ++j) {
        acc[j][0] = ba.x; acc[j][1] = ba.y; acc[j][2] = ba.z; acc[j][3] = ba.w;
        acc[j][4] = bb.x; acc[j][5] = bb.y; acc[j][6] = bb.z; acc[j][7] = bb.w;
    }
    for (int kk = 0; kk < 64; ++kk) {
        float4 f = *(const float4*)(Ft + kk * 128 + rg * 4);
        float4 wa = *(const float4*)(Ws + kk * 64 + cg * 8);
        float4 wb = *(const float4*)(Ws + kk * 64 + cg * 8 + 4);
        float fv[4] = {f.x, f.y, f.z, f.w};
        float wv[8] = {wa.x, wa.y, wa.z, wa.w, wb.x, wb.y, wb.z, wb.w};
#pragma unroll
        for (int j = 0; j < 4; ++j)
#pragma unroll
            for (int i = 0; i < 8; ++i) acc[j][i] = fmaf(fv[j], wv[i], acc[j][i]);
    }
    float ls[8] = {0,0,0,0,0,0,0,0}, lq[8] = {0,0,0,0,0,0,0,0};
#pragma unroll
    for (int j = 0; j < 4; ++j) {
        int m = m0 + rg * 4 + j;
        float4 oa = {acc[j][0], acc[j][1], acc[j][2], acc[j][3]};
        float4 ob = {acc[j][4], acc[j][5], acc[j][6], acc[j][7]};
        *(float4*)(h2 + (size_t)m * 64 + cg * 8) = oa;
        *(float4*)(h2 + (size_t)m * 64 + cg * 8 + 4) = ob;
#pragma unroll
        for (int i = 0; i < 8; ++i) { float v = acc[j][i]; ls[i] += v; lq[i] += v * v; }
    }
    __syncthreads();
    float* part_s = Ft;
    float* part_q = Ft + 2048;
#pragma unroll
    for (int i = 0; i < 8; ++i) { part_s[rg * 64 + cg * 8 + i] = ls[i]; part_q[rg * 64 + cg * 8 + i] = lq[i]; }
    __syncthreads();
    if (t < 64) {
        float s = 0.f, q = 0.f;
#pragma unroll
        for (int rgi = 0; rgi < 32; ++rgi) { s += part_s[rgi * 64 + t]; q += part_q[rgi * 64 + t]; }
        int cp = blockIdx.x & (NCOPY - 1);
        atomicAdd(&sum1[cp * 64 + t], s);
        atomicAdd(&ssq1[cp * 64 + t], q);
    }
}

// ---------------- layer3: BN2+ReLU + GEMM(64->128) + stats + per-group max/min ----------------
// Pooling trick: max_k relu(a*h+b) == relu(a*max_k h + b) for a>=0 (min_k for a<0),
// exact in fp32 by monotonicity of fmaf/relu. So h3 is never materialized.
__global__ __launch_bounds__(256) void k_layer3(const float* __restrict__ h2,
                                                const float* __restrict__ Wt2,
                                                const float* __restrict__ bias2,
                                                const float* __restrict__ ss2,
                                                float* __restrict__ sum2,
                                                float* __restrict__ ssq2,
                                                float* __restrict__ gmax,
                                                float* __restrict__ gmin)
{
    __shared__ __align__(16) float Ft[64 * 128];
    __shared__ __align__(16) float Ws[64 * 128];
    __shared__ float s_sc[64], s_sh[64];
    const int t = threadIdx.x;
    const int m0 = blockIdx.x * 128;
    for (int i = t; i < 64 * 128; i += 256) Ws[i] = Wt2[i];
    if (t < 64) { s_sc[t] = ss2[t]; s_sh[t] = ss2[64 + t]; }
    __syncthreads();
    {
        const int tq = t >> 2, qq = t & 3;
#pragma unroll
        for (int rr = 0; rr < 2; ++rr) {
            const int r = rr * 64 + tq;
            const float* hrow = h2 + (size_t)(m0 + r) * 64;
#pragma unroll
            for (int rep = 0; rep < 4; ++rep) {
                const int c4 = qq * 4 + rep * 16;
                float4 v = *(const float4*)(hrow + c4);
                Ft[(c4 + 0) * 128 + r] = fmaxf(0.f, fmaf(v.x, s_sc[c4 + 0], s_sh[c4 + 0]));
                Ft[(c4 + 1) * 128 + r] = fmaxf(0.f, fmaf(v.y, s_sc[c4 + 1], s_sh[c4 + 1]));
                Ft[(c4 + 2) * 128 + r] = fmaxf(0.f, fmaf(v.z, s_sc[c4 + 2], s_sh[c4 + 2]));
                Ft[(c4 + 3) * 128 + r] = fmaxf(0.f, fmaf(v.w, s_sc[c4 + 3], s_sh[c4 + 3]));
            }
        }
    }
    __syncthreads();
    const int rg = t >> 4;  // 0..15 -> rows rg*8..+7  (all within group rg>>2)
    const int cg = t & 15;  // 0..15 -> cols cg*8..+7
    float4 ba = *(const float4*)(bias2 + cg * 8);
    float4 bb = *(const float4*)(bias2 + cg * 8 + 4);
    float acc[8][8];
#pragma unroll
    for (int j = 0; j < 8; ++j) {
        acc[j][0] = ba.x; acc[j][1] = ba.y; acc[j][2] = ba.z; acc[j][3] = ba.w;
        acc[j][4] = bb.x; acc[j][5] = bb.y; acc[j][6] = bb.z; acc[j][7] = bb.w;
    }
    for (int kk = 0; kk < 64; ++kk) {
        float4 fa = *(const float4*)(Ft + kk * 128 + rg * 8);
        float4 fb = *(const float4*)(Ft + kk * 128 + rg * 8 + 4);
        float4 wa = *(const float4*)(Ws + kk * 128 + cg * 8);
        float4 wb = *(const float4*)(Ws + kk * 128 + cg * 8 + 4);
        float fv[8] = {fa.x, fa.y, fa.z, fa.w, fb.x, fb.y, fb.z, fb.w};
        float wv[8] = {wa.x, wa.y, wa.z, wa.w, wb.x, wb.y, wb.z, wb.w};
#pragma unroll
        for (int j = 0; j < 8; ++j)
#pragma unroll
            for (int i = 0; i < 8; ++i) acc[j][i] = fmaf(fv[j], wv[i], acc[j][i]);
    }
    float ls[8] = {0,0,0,0,0,0,0,0}, lq[8] = {0,0,0,0,0,0,0,0};
    float pm[8], pn[8];
#pragma unroll
    for (int i = 0; i < 8; ++i) { pm[i] = acc[0][i]; pn[i] = acc[0][i]; }
#pragma unroll
    for (int j = 0; j < 8; ++j)
#pragma unroll
        for (int i = 0; i < 8; ++i) {
            float v = acc[j][i];
            ls[i] += v; lq[i] += v * v;
            pm[i] = fmaxf(pm[i], v); pn[i] = fminf(pn[i], v);
        }
    __syncthreads();
    float* part_s = Ft;        // [16][128]
    float* part_q = Ft + 2048; // [16][128]
    float* part_m = Ft + 4096; // [16][128]
    float* part_n = Ft + 6144; // [16][128]
#pragma unroll
    for (int i = 0; i < 8; ++i) {
        part_s[rg * 128 + cg * 8 + i] = ls[i];
        part_q[rg * 128 + cg * 8 + i] = lq[i];
        part_m[rg * 128 + cg * 8 + i] = pm[i];
        part_n[rg * 128 + cg * 8 + i] = pn[i];
    }
    __syncthreads();
    if (t < 128) {
        float s = 0.f, q = 0.f;
#pragma unroll
        for (int rgi = 0; rgi < 16; ++rgi) { s += part_s[rgi * 128 + t]; q += part_q[rgi * 128 + t]; }
        int cp = blockIdx.x & (NCOPY - 1);
        atomicAdd(&sum2[cp * 128 + t], s);
        atomicAdd(&ssq2[cp * 128 + t], q);
    }
    for (int e = t; e < 512; e += 256) {
        int g = e >> 7, c = e & 127;
        float M = part_m[(g * 4 + 0) * 128 + c];
        M = fmaxf(M, part_m[(g * 4 + 1) * 128 + c]);
        M = fmaxf(M, part_m[(g * 4 + 2) * 128 + c]);
        M = fmaxf(M, part_m[(g * 4 + 3) * 128 + c]);
        float N = part_n[(g * 4 + 0) * 128 + c];
        N = fminf(N, part_n[(g * 4 + 1) * 128 + c]);
        N = fminf(N, part_n[(g * 4 + 2) * 128 + c]);
        N = fminf(N, part_n[(g * 4 + 3) * 128 + c]);
        int grp = blockIdx.x * 4 + g;              // == b*1024 + s
        gmax[(size_t)grp * 128 + c] = M;
        gmin[(size_t)grp * 128 + c] = N;
    }
}

// ---------------- pool2: apply BN3+ReLU to pooled max/min, transposed store ----------------
__global__ __launch_bounds__(256) void k_pool2(const float* __restrict__ gmax,
                                               const float* __restrict__ gmin,
                                               const float* __restrict__ ss3,
                                               float* __restrict__ outp)
{
    int idx = blockIdx.x * 256 + threadIdx.x;      // 1,048,576 = 8*128*1024
    int b = idx >> 17;
    int c = (idx >> 10) & 127;
    int s = idx & 1023;
    int grp = (b << 10) + s;
    float a = ss3[c], sh = ss3[128 + c];
    float m = (a >= 0.f) ? gmax[(size_t)grp * 128 + c] : gmin[(size_t)grp * 128 + c];
    outp[idx] = fmaxf(0.f, fmaf(m, a, sh));
}

// ---------------- finalize BN stats -> scale/shift ----------------
__global__ void k_finalize(const float* __restrict__ sum, const float* __restrict__ ssq,
                           const float* __restrict__ g, const float* __restrict__ beta,
                           float* __restrict__ ss, int nc)
{
    int c = threadIdx.x;
    if (c >= nc) return;
    float s = 0.f, q = 0.f;
    for (int k = 0; k < NCOPY; ++k) { s += sum[k * nc + c]; q += ssq[k * nc + c]; }
    const float inv = 1.0f / 262144.0f;
    float mean = s * inv;
    float var = q * inv - mean * mean;
    float rstd = 1.0f / sqrtf(var + 1e-5f);
    float scale = g[c] * rstd;
    ss[c] = scale;
    ss[nc + c] = beta[c] - mean * scale;
}

extern "C" void kernel_launch(void* const* d_in, const int* in_sizes, int n_in,
                              void* d_out, int out_size, void* d_ws, size_t ws_size,
                              hipStream_t stream)
{
    const float* xyz    = (const float*)d_in[0];
    const float* points = (const float*)d_in[1];
    const float* w0 = (const float*)d_in[2];
    const float* b0 = (const float*)d_in[3];
    const float* gm0 = (const float*)d_in[4];
    const float* bt0 = (const float*)d_in[5];
    const float* w1 = (const float*)d_in[6];
    const float* b1 = (const float*)d_in[7];
    const float* gm1 = (const float*)d_in[8];
    const float* bt1 = (const float*)d_in[9];
    const float* w2 = (const float*)d_in[10];
    const float* b2 = (const float*)d_in[11];
    const float* gm2 = (const float*)d_in[12];
    const float* bt2 = (const float*)d_in[13];
    float* out = (float*)d_out;

    char* p = (char*)d_ws;
    auto alloc = [&](size_t nbytes) -> void* {
        void* r = (void*)p;
        p += (nbytes + 255) & ~(size_t)255;
        return r;
    };
    float* fps_pts = (float*)alloc((size_t)NB * SP * 3 * 4);
    int*   ball_idx = (int*)alloc((size_t)NB * SP * KS * 4);
    float* pts_t = (float*)alloc((size_t)NB * NP * CD * 4);
    float* h1 = (float*)alloc((size_t)MROWS * 64 * 4);
    float* h2 = (float*)alloc((size_t)MROWS * 64 * 4);
    float* gmax = (float*)alloc((size_t)NB * SP * 128 * 4);
    float* gmin = (float*)alloc((size_t)NB * SP * 128 * 4);
    float* Wt0 = (float*)alloc(67 * 64 * 4);
    float* Wt1 = (float*)alloc(64 * 64 * 4);
    float* Wt2 = (float*)alloc(64 * 128 * 4);
    float* stats = (float*)alloc(8192 * 4);
    float* ss1 = (float*)alloc(128 * 4);
    float* ss2 = (float*)alloc(128 * 4);
    float* ss3 = (float*)alloc(256 * 4);

    float* sum0 = stats;
    float* ssq0 = stats + 16 * 64;
    float* sum1 = stats + 2 * 16 * 64;
    float* ssq1 = stats + 3 * 16 * 64;
    float* sum2 = stats + 4 * 16 * 64;
    float* ssq2 = sum2 + 16 * 128;

    k_fps_pre<<<NB + NB * (NP / 64) + 1, 512, 0, stream>>>(
        xyz, fps_pts, out, points, pts_t, w0, w1, w2, Wt0, Wt1, Wt2, stats);
    k_ballquery<<<(NB * SP) / 4, 256, 0, stream>>>(xyz, fps_pts, ball_idx);
    k_layer1<<<MROWS / 128, 256, 0, stream>>>(xyz, pts_t, fps_pts, ball_idx, Wt0, b0, h1, sum0, ssq0);
    k_finalize<<<1, 128, 0, stream>>>(sum0, ssq0, gm0, bt0, ss1, 64);
    k_layer2<<<MROWS / 128, 256, 0, stream>>>(h1, Wt1, b1, ss1, h2, sum1, ssq1);
    k_finalize<<<1, 128, 0, stream>>>(sum1, ssq1, gm1, bt1, ss2, 64);
    k_layer3<<<MROWS / 128, 256, 0, stream>>>(h2, Wt2, b2, ss2, sum2, ssq2, gmax, gmin);
    k_finalize<<<1, 128, 0, stream>>>(sum2, ssq2, gm2, bt2, ss3, 128);
    k_pool2<<<(NB * SP * 128) / 256, 256, 0, stream>>>(gmax, gmin, ss3, out + 24576);
}

// Round 9
// 1187.249 us; speedup vs baseline: 1.0912x; 1.0123x over previous
//
#include <hip/hip_runtime.h>

#define NB 8
#define NP 8192
#define SP 1024
#define KS 32
#define CD 64
#define MROWS (NB*SP*KS)
#define NCOPY 16

typedef float v2f __attribute__((ext_vector_type(2)));
typedef unsigned long long u64;

// one DPP max step on a u64 key: pure VALU, no LDS. ctrl is a template param because
// __builtin_amdgcn_update_dpp requires an immediate. old=src + bound_ctrl=false ->
// lanes with no valid source keep their own value (identity for max).
template <int CTRL>
__device__ __forceinline__ u64 dpp_max_step(u64 x) {
    int lo = (int)(unsigned)(x & 0xffffffffull);
    int hi = (int)(unsigned)(x >> 32);
    int slo = __builtin_amdgcn_update_dpp(lo, lo, CTRL, 0xf, 0xf, false);
    int shi = __builtin_amdgcn_update_dpp(hi, hi, CTRL, 0xf, 0xf, false);
    u64 y = ((u64)(unsigned)shi << 32) | (unsigned)slo;
    return x > y ? x : y;
}

// ---------------- fused FPS (blocks 0..7) + points-transpose (8..1031) + weight-prep (1032) ----------
// FPS r9: r8's Morton-sorted bound-pruned EXACT FPS, with the per-iteration s_barrier replaced
// by a tagged LDS spin-exchange.
// r8 lesson (SIMD-32-corrected counters): VALU issue is only ~550cy of the 2178cy iteration;
// pruning fires (~43% avg wave activity) yet saved ~1%. The floor is the serial chain, and by
// elimination its biggest unexplained piece is s_barrier mechanics (drain+skew+release, 8 waves).
// Spin-exchange design:
//  - key low word: pos=bits 0-12, (8191-gid)=bits 13-25 -> bit 26 is FREE. lane63 publishes
//    wkey | tag<<26 into parity-dbuf'd s_wk[i&1][wid], tag=(i>>1)&1.
//  - every wave poll-reads the 8 slots (volatile ds_read_b64) until all tags match, then
//    ladder-reduces the SAME polled registers (single read, no re-read race).
//  - drift bound: a wave enters iter i+1 only after all waves posted iter i; the parity slot
//    for iter i is overwritten at i+2, by which time all waves finished i. Stale-tag init
//    (bit26=1) blocks iters 0/1 from passing on stale data.
//  - tag bit is identical on all keys within an iteration -> u64 max ordering and pos
//    extraction (&0x1FFF) unaffected -> bit-exact vs r8.
// Everything else (sort, prune bound, distance dag, ladders, captures) is r8-verbatim.
__global__ __launch_bounds__(512, 1) void k_fps_pre(const float* __restrict__ xyz,
                                                    float* __restrict__ fps_pts,
                                                    float* __restrict__ out_nx,
                                                    const float* __restrict__ points,
                                                    float* __restrict__ pts_t,
                                                    const float* __restrict__ w0,
                                                    const float* __restrict__ w1,
                                                    const float* __restrict__ w2,
                                                    float* __restrict__ Wt0,
                                                    float* __restrict__ Wt1,
                                                    float* __restrict__ Wt2,
                                                    float* __restrict__ stats)
{
#pragma clang fp contract(off)
    __shared__ __align__(16) unsigned char smem[131072 + 2560];
    const int blk = blockIdx.x;
    const int t = threadIdx.x;

    if (blk >= NB) {
        if (blk >= NB + NB * (NP / 64)) {
            // weight prep: zero stats, transpose weights to [kk][c]
            for (int i = t; i < 8192; i += 512) stats[i] = 0.f;
            for (int i = t; i < 64 * 67; i += 512) { int c = i / 67, kk = i % 67; Wt0[kk * 64 + c] = w0[i]; }
            for (int i = t; i < 64 * 64; i += 512) { int c = i >> 6, kk = i & 63; Wt1[kk * 64 + c] = w1[i]; }
            for (int i = t; i < 128 * 64; i += 512) { int c = i >> 6, kk = i & 63; Wt2[kk * 128 + c] = w2[i]; }
            return;
        }
        // points transpose (B,64,N) -> (B,N,64), 64x64 tile, 512 threads
        float (*tile)[65] = (float(*)[65])smem;
        const int tblk = blk - NB;
        const int b = tblk >> 7;
        const int n0 = (tblk & 127) << 6;
        const float* pb = points + (size_t)b * CD * NP;
        const int c = t & 63;
        const int dr = t >> 6;                 // 0..7
#pragma unroll
        for (int it = 0; it < 8; ++it) {
            int d = dr + it * 8;
            tile[d][c] = pb[(size_t)d * NP + n0 + c];
        }
        __syncthreads();
#pragma unroll
        for (int it = 0; it < 8; ++it) {
            int nn = dr + it * 8;
            pts_t[((size_t)b * NP + n0 + nn) * CD + c] = tile[c][nn];
        }
        return;
    }

    // ---- FPS path ----
    float4* s_p  = (float4*)smem;                          // 128 KB sorted pts (xyz + gid bits)
    int*    s_cnt = (int*)(smem + 131072);                 // 512 cell counts/offsets
    u64 (*s_wk)[8] = (u64(*)[8])(smem + 131072 + 2048);    // parity-dbuf leader keys (tagged)
    const int b = blk;
    const int lane = t & 63, wid = t >> 6;                 // 8 waves
    const float* xb = xyz + (size_t)b * 3 * NP;

    // -- one-time Morton counting sort (r8-verbatim) --
    float lx[16], ly[16], lz[16];
    int   lcell[16];
    s_cnt[t < 512 ? t : 0] = 0;                            // t in [0,512): zero own slot
    if (t < 16) ((u64*)s_wk)[t] = (u64)1 << 26;            // stale-tag init: iter 0/1 expect tag 0
    __syncthreads();
#pragma unroll
    for (int j = 0; j < 16; ++j) {
        const int n = t + j * 512;                         // r0-coalesced load
        lx[j] = xb[n]; ly[j] = xb[NP + n]; lz[j] = xb[2 * NP + n];
        int ix = (int)(lx[j] * 8.f); ix = ix < 0 ? 0 : (ix > 7 ? 7 : ix);
        int iy = (int)(ly[j] * 8.f); iy = iy < 0 ? 0 : (iy > 7 ? 7 : iy);
        int iz = (int)(lz[j] * 8.f); iz = iz < 0 ? 0 : (iz > 7 ? 7 : iz);
        int sx = ((ix & 4) << 4) | ((ix & 2) << 2) | (ix & 1);
        int sy = ((iy & 4) << 4) | ((iy & 2) << 2) | (iy & 1);
        int sz = ((iz & 4) << 4) | ((iz & 2) << 2) | (iz & 1);
        lcell[j] = (sx << 2) | (sy << 1) | sz;             // Morton id, 0..511
        atomicAdd(&s_cnt[lcell[j]], 1);
    }
    __syncthreads();
    if (t == 0) {                                          // exclusive prefix (one-time ~2us)
        int run = 0;
        for (int c2 = 0; c2 < 512; ++c2) { int v = s_cnt[c2]; s_cnt[c2] = run; run += v; }
    }
    __syncthreads();
#pragma unroll
    for (int j = 0; j < 16; ++j) {
        int pos = atomicAdd(&s_cnt[lcell[j]], 1);
        s_p[pos] = make_float4(lx[j], ly[j], lz[j], __uint_as_float((unsigned)(t + j * 512)));
    }
    __syncthreads();
    // -- reload sorted chunk [16t, 16t+16): coords, key low-words, bbox --
    float px[16], py[16], pz[16], dv16[16];
    unsigned klo[16];
    float blx = 1e30f, bly = 1e30f, blz = 1e30f, bhx = -1e30f, bhy = -1e30f, bhz = -1e30f;
#pragma unroll
    for (int j = 0; j < 16; ++j) {
        float4 v = s_p[16 * t + j];
        px[j] = v.x; py[j] = v.y; pz[j] = v.z;
        unsigned g = __float_as_uint(v.w);                 // original gid (raw bits)
        klo[j] = ((8191u - g) << 13) | (unsigned)(16 * t + j);
        dv16[j] = 1e10f;
        blx = fminf(blx, v.x); bhx = fmaxf(bhx, v.x);
        bly = fminf(bly, v.y); bhy = fmaxf(bhy, v.y);
        blz = fminf(blz, v.z); bhz = fmaxf(bhz, v.z);
    }
    float cx = xb[0], cy = xb[NP], cz = xb[2 * NP];
    float cellmax = 1e10f;                                 // max dv over this thread's chunk
    u64 wkey = 0;                                          // lane63's cached wave key
    float hx0 = 0.f, hy0 = 0.f, hz0 = 0.f;                 // captured centroid of iteration i == t
    float hx1 = 0.f, hy1 = 0.f, hz1 = 0.f;                 // captured centroid of iteration i == t + 512
    __syncthreads();
    for (int i = 0; i < SP; ++i) {
        if (i == t)       { hx0 = cx; hy0 = cy; hz0 = cz; }
        if (i == t + 512) { hx1 = cx; hy1 = cy; hz1 = cz; }
        // conservative bound: skip iff dmin2(c,bbox)*0.999 >= cellmax (slack >> fp32 rounding)
        float ddx = fmaxf(fmaxf(blx - cx, cx - bhx), 0.f);
        float ddy = fmaxf(fmaxf(bly - cy, cy - bhy), 0.f);
        float ddz = fmaxf(fmaxf(blz - cz, cz - bhz), 0.f);
        float dmin = ddx * ddx + ddy * ddy;
        dmin = dmin + ddz * ddz;
        bool act = (dmin * 0.999f < cellmax);
        if (__ballot(act)) {
            // full update for this wave (EXACT fp32: same dag as r0 — sub, mul, (x2+y2)+z2, min)
            u64 bk = 0; float cm = 0.f;
#pragma unroll
            for (int j = 0; j < 16; ++j) {
                float dx = px[j] - cx;
                float dy = py[j] - cy;
                float dz = pz[j] - cz;
                float d = dx * dx + dy * dy;
                d = d + dz * dz;
                float nd = fminf(dv16[j], d);
                dv16[j] = nd;
                cm = fmaxf(cm, nd);
                u64 k = ((u64)__float_as_uint(nd) << 32) | klo[j];
                bk = bk > k ? bk : k;
            }
            cellmax = cm;
            // per-wave DPP max ladder (r0-verbatim); lane 63 ends with the wave max
            bk = dpp_max_step<0x111>(bk);      // row_shr:1
            bk = dpp_max_step<0x112>(bk);      // row_shr:2
            bk = dpp_max_step<0x114>(bk);      // row_shr:4
            bk = dpp_max_step<0x118>(bk);      // row_shr:8
            bk = dpp_max_step<0x142>(bk);      // row_bcast:15
            bk = dpp_max_step<0x143>(bk);      // row_bcast:31
            wkey = bk;
        }
        const int par = i & 1;
        const u64 tagbit = (u64)((unsigned)(i >> 1) & 1u) << 26;
        if (lane == 63)                        // publish tagged key (cached if wave skipped)
            *(volatile u64*)&s_wk[par][wid] = wkey | tagbit;
        // spin-exchange (replaces s_barrier): poll the 8 iter-i slots until all tags match.
        // Single read per pass; the passing read IS the reduce input (no re-read race).
        u64 rk;
        for (;;) {
            rk = *(volatile u64*)&s_wk[par][lane & 7];
            bool bad = ((rk >> 26) & 1ull) != (u64)((unsigned)(i >> 1) & 1u);
            if (!__ballot(bad)) break;
        }
        // cross-wave reduce (r0-verbatim): 8 leader keys replicated twice per 16-lane row
        rk = dpp_max_step<0x111>(rk);
        rk = dpp_max_step<0x112>(rk);
        rk = dpp_max_step<0x114>(rk);
        rk = dpp_max_step<0x118>(rk);
        const int wlo = __builtin_amdgcn_readlane((int)(unsigned)(rk & 0xffffffffull), 15);
        const int wpos = wlo & 0x1FFF;         // sorted position of the winner
        const float4 c = s_p[wpos];            // uniform broadcast ds_read_b128
        cx = c.x; cy = c.y; cz = c.z;
        // drift <=1 guaranteed by the tag protocol; parity slot i is overwritten only at i+2
    }
    // deferred outputs: thread t owns fps points t and t+512
    fps_pts[(b * SP + t) * 3 + 0] = hx0;
    fps_pts[(b * SP + t) * 3 + 1] = hy0;
    fps_pts[(b * SP + t) * 3 + 2] = hz0;
    fps_pts[(b * SP + t + 512) * 3 + 0] = hx1;
    fps_pts[(b * SP + t + 512) * 3 + 1] = hy1;
    fps_pts[(b * SP + t + 512) * 3 + 2] = hz1;
    out_nx[(size_t)b * 3 * SP + 0 * SP + t] = hx0;
    out_nx[(size_t)b * 3 * SP + 1 * SP + t] = hy0;
    out_nx[(size_t)b * 3 * SP + 2 * SP + t] = hz0;
    out_nx[(size_t)b * 3 * SP + 0 * SP + t + 512] = hx1;
    out_nx[(size_t)b * 3 * SP + 1 * SP + t + 512] = hy1;
    out_nx[(size_t)b * 3 * SP + 2 * SP + t + 512] = hz1;
}

// ---------------- ball query: one wave per query, ordered first-32 append (r0-verbatim) --------
__global__ __launch_bounds__(256) void k_ballquery(const float* __restrict__ xyz,
                                                   const float* __restrict__ fps_pts,
                                                   int* __restrict__ ball_idx)
{
    const int wib = threadIdx.x >> 6;
    const int lane = threadIdx.x & 63;
    const int wid = blockIdx.x * 4 + wib;          // b*SP + s
    const int b = wid >> 10;
    const float* xb = xyz + (size_t)b * 3 * NP;
    const float qx = fps_pts[wid * 3 + 0];
    const float qy = fps_pts[wid * 3 + 1];
    const float qz = fps_pts[wid * 3 + 2];
    __shared__ int s_list[4][KS];
    int* list = s_list[wib];
    const float r2 = (float)(0.2 * 0.2);           // 0.039999999f — matches python double->f32
    int found = 0;
    for (int base = 0; base < NP && found < KS; base += 64) {
        int n = base + lane;
        float dx = __fsub_rn(qx, xb[n]);
        float dy = __fsub_rn(qy, xb[NP + n]);
        float dz = __fsub_rn(qz, xb[2 * NP + n]);
        float d = __fadd_rn(__fadd_rn(__fmul_rn(dx, dx), __fmul_rn(dy, dy)), __fmul_rn(dz, dz));
        bool in = !(d > r2);
        unsigned long long m = __ballot(in);
        int before = __popcll(m & ((1ull << lane) - 1ull));
        int pos = found + before;
        if (in && pos < KS) list[pos] = n;
        found += __popcll(m);
    }
    int first = list[0];
    if (lane < KS) {
        int v = (lane < found) ? list[lane] : first;
        ball_idx[wid * KS + lane] = v;
    }
}

// ---------------- layer1: gather(feat 67) + GEMM(67->64) + stats (r0-verbatim) ----------------
__global__ __launch_bounds__(256) void k_layer1(const float* __restrict__ xyz,
                                                const float* __restrict__ pts_t,
                                                const float* __restrict__ fps_pts,
                                                const int* __restrict__ ball_idx,
                                                const float* __restrict__ Wt0,
                                                const float* __restrict__ bias0,
                                                float* __restrict__ h1,
                                                float* __restrict__ sum0,
                                                float* __restrict__ ssq0)
{
    __shared__ __align__(16) float Ft[67 * 128];
    __shared__ __align__(16) float Ws[67 * 64];
    __shared__ int   s_idx[128];
    __shared__ float s_q[4][3];
    const int t = threadIdx.x;
    const int m0 = blockIdx.x * 128;
    const int g0 = m0 >> 5;
    const int b = g0 >> 10;
    if (t < 128) s_idx[t] = ball_idx[g0 * KS + t];
    if (t < 12) ((float*)s_q)[t] = fps_pts[g0 * 3 + t];
    for (int i = t; i < 67 * 64; i += 256) Ws[i] = Wt0[i];
    __syncthreads();
    {
        const int r = t >> 1, half = t & 1;
        const int n = s_idx[r];
        const float* prow = pts_t + ((size_t)b * NP + n) * CD;
#pragma unroll
        for (int rep = 0; rep < 8; ++rep) {
            const int c4 = half * 4 + rep * 8;
            float4 v = *(const float4*)(prow + c4);
            Ft[(3 + c4 + 0) * 128 + r] = v.x;
            Ft[(3 + c4 + 1) * 128 + r] = v.y;
            Ft[(3 + c4 + 2) * 128 + r] = v.z;
            Ft[(3 + c4 + 3) * 128 + r] = v.w;
        }
        if (t < 128) {
            const int n2 = s_idx[t];
            const int g = t >> 5;
            const float* xb = xyz + (size_t)b * 3 * NP;
            Ft[0 * 128 + t] = __fsub_rn(xb[n2],          s_q[g][0]);
            Ft[1 * 128 + t] = __fsub_rn(xb[NP + n2],     s_q[g][1]);
            Ft[2 * 128 + t] = __fsub_rn(xb[2 * NP + n2], s_q[g][2]);
        }
    }
    __syncthreads();
    const int rg = t >> 3;   // 0..31 -> rows rg*4..+3
    const int cg = t & 7;    // 0..7  -> cols cg*8..+7
    float4 ba = *(const float4*)(bias0 + cg * 8);
    float4 bb = *(const float4*)(bias0 + cg * 8 + 4);
    float acc[4][8];
#pragma unroll
    for (int j = 0; j < 4; ++j) {
        acc[j][0] = ba.x; acc[j][1] = ba.y; acc[j][2] = ba.z; acc[j][3] = ba.w;
        acc[j][4] = bb.x; acc[j][5] = bb.y; acc[j][6] = bb.z; acc[j][7] = bb.w;
    }
    for (int kk = 0; kk < 67; ++kk) {
        float4 f = *(const float4*)(Ft + kk * 128 + rg * 4);
        float4 wa = *(const float4*)(Ws + kk * 64 + cg * 8);
        float4 wb = *(const float4*)(Ws + kk * 64 + cg * 8 + 4);
        float fv[4] = {f.x, f.y, f.z, f.w};
        float wv[8] = {wa.x, wa.y, wa.z, wa.w, wb.x, wb.y, wb.z, wb.w};
#pragma unroll
        for (int j = 0; j < 4; ++j)
#pragma unroll
            for (int i = 0; i < 8; ++i) acc[j][i] = fmaf(fv[j], wv[i], acc[j][i]);
    }
    float ls[8] = {0,0,0,0,0,0,0,0}, lq[8] = {0,0,0,0,0,0,0,0};
#pragma unroll
    for (int j = 0; j < 4; ++j) {
        int m = m0 + rg * 4 + j;
        float4 oa = {acc[j][0], acc[j][1], acc[j][2], acc[j][3]};
        float4 ob = {acc[j][4], acc[j][5], acc[j][6], acc[j][7]};
        *(float4*)(h1 + (size_t)m * 64 + cg * 8) = oa;
        *(float4*)(h1 + (size_t)m * 64 + cg * 8 + 4) = ob;
#pragma unroll
        for (int i = 0; i < 8; ++i) { float v = acc[j][i]; ls[i] += v; lq[i] += v * v; }
    }
    __syncthreads();           // Ft reuse for stats partials
    float* part_s = Ft;        // [32][64]
    float* part_q = Ft + 2048; // [32][64]
#pragma unroll
    for (int i = 0; i < 8; ++i) { part_s[rg * 64 + cg * 8 + i] = ls[i]; part_q[rg * 64 + cg * 8 + i] = lq[i]; }
    __syncthreads();
    if (t < 64) {
        float s = 0.f, q = 0.f;
#pragma unroll
        for (int rgi = 0; rgi < 32; ++rgi) { s += part_s[rgi * 64 + t]; q += part_q[rgi * 64 + t]; }
        int cp = blockIdx.x & (NCOPY - 1);
        atomicAdd(&sum0[cp * 64 + t], s);
        atomicAdd(&ssq0[cp * 64 + t], q);
    }
}

// ---------------- layer2: BN1+ReLU on load + GEMM(64->64) + stats ----------------
__global__ __launch_bounds__(256) void k_layer2(const float* __restrict__ h1,
                                                const float* __restrict__ Wt1,
                                                const float* __restrict__ bias1,
                                                const float* __restrict__ ss1,
                                                float* __restrict__ h2,
                                                float* __restrict__ sum1,
                                                float* __restrict__ ssq1)
{
    __shared__ __align__(16) float Ft[64 * 128];
    __shared__ __align__(16) float Ws[64 * 64];
    __shared__ float s_sc[64], s_sh[64];
    const int t = threadIdx.x;
    const int m0 = blockIdx.x * 128;
    for (int i = t; i < 64 * 64; i += 256) Ws[i] = Wt1[i];
    if (t < 64) { s_sc[t] = ss1[t]; s_sh[t] = ss1[64 + t]; }
    __syncthreads();
    {
        const int tq = t >> 2, qq = t & 3;
#pragma unroll
        for (int rr = 0; rr < 2; ++rr) {
            const int r = rr * 64 + tq;
            const float* hrow = h1 + (size_t)(m0 + r) * 64;
#pragma unroll
            for (int rep = 0; rep < 4; ++rep) {
                const int c4 = qq * 4 + rep * 16;
                float4 v = *(const float4*)(hrow + c4);
                Ft[(c4 + 0) * 128 + r] = fmaxf(0.f, fmaf(v.x, s_sc[c4 + 0], s_sh[c4 + 0]));
                Ft[(c4 + 1) * 128 + r] = fmaxf(0.f, fmaf(v.y, s_sc[c4 + 1], s_sh[c4 + 1]));
                Ft[(c4 + 2) * 128 + r] = fmaxf(0.f, fmaf(v.z, s_sc[c4 + 2], s_sh[c4 + 2]));
                Ft[(c4 + 3) * 128 + r] = fmaxf(0.f, fmaf(v.w, s_sc[c4 + 3], s_sh[c4 + 3]));
            }
        }
    }
    __syncthreads();
    const int rg = t >> 3;
    const int cg = t & 7;
    float4 ba = *(const float4*)(bias1 + cg * 8);
    float4 bb = *(const float4*)(bias1 + cg * 8 + 4);
    float acc[4][8];
#pragma unroll
    for (int j = 0; j < 4; ++j) {
        acc[j][0] = ba.x; acc[j][1] = ba.y; acc[j][2] = ba.z; acc[j][3] = ba.w;
        acc[j][4] = bb.x; acc[j][5] = bb.y; acc[j][6] = bb.z; acc[j][7] = bb.w;
    }
    for (int kk = 0; kk < 64; ++kk) {
        float4 f = *(const float4*)(Ft + kk * 128 + rg * 4);
        float4 wa = *(const float4*)(Ws + kk * 64 + cg * 8);
        float4 wb = *(const float4*)(Ws + kk * 64 + cg * 8 + 4);
        float fv[4] = {f.x, f.y, f.z, f.w};
        float wv[8] = {wa.x, wa.y, wa.z, wa.w, wb.x, wb.y, wb.z, wb.w};
#pragma unroll
        for (int j = 0; j < 4; ++j)
#pragma unroll
            for (int i = 0; i < 8; ++i) acc[j][i] = fmaf(fv[j], wv[i], acc[j][i]);
    }
    float ls[8] = {0,0,0,0,0,0,0,0}, lq[8] = {0,0,0,0,0,0,0,0};
#pragma unroll
    for (int j = 0; j < 4; ++j) {
        int m = m0 + rg * 4 + j;
        float4 oa = {acc[j][0], acc[j][1], acc[j][2], acc[j][3]};
        float4 ob = {acc[j][4], acc[j][5], acc[j][6], acc[j][7]};
        *(float4*)(h2 + (size_t)m * 64 + cg * 8) = oa;
        *(float4*)(h2 + (size_t)m * 64 + cg * 8 + 4) = ob;
#pragma unroll
        for (int i = 0; i < 8; ++i) { float v = acc[j][i]; ls[i] += v; lq[i] += v * v; }
    }
    __syncthreads();
    float* part_s = Ft;
    float* part_q = Ft + 2048;
#pragma unroll
    for (int i = 0; i < 8; ++i) { part_s[rg * 64 + cg * 8 + i] = ls[i]; part_q[rg * 64 + cg * 8 + i] = lq[i]; }
    __syncthreads();
    if (t < 64) {
        float s = 0.f, q = 0.f;
#pragma unroll
        for (int rgi = 0; rgi < 32; ++rgi) { s += part_s[rgi * 64 + t]; q += part_q[rgi * 64 + t]; }
        int cp = blockIdx.x & (NCOPY - 1);
        atomicAdd(&sum1[cp * 64 + t], s);
        atomicAdd(&ssq1[cp * 64 + t], q);
    }
}

// ---------------- layer3: BN2+ReLU + GEMM(64->128) + stats + per-group max/min ----------------
// Pooling trick: max_k relu(a*h+b) == relu(a*max_k h + b) for a>=0 (min_k for a<0),
// exact in fp32 by monotonicity of fmaf/relu. So h3 is never materialized.
__global__ __launch_bounds__(256) void k_layer3(const float* __restrict__ h2,
                                                const float* __restrict__ Wt2,
                                                const float* __restrict__ bias2,
                                                const float* __restrict__ ss2,
                                                float* __restrict__ sum2,
                                                float* __restrict__ ssq2,
                                                float* __restrict__ gmax,
                                                float* __restrict__ gmin)
{
    __shared__ __align__(16) float Ft[64 * 128];
    __shared__ __align__(16) float Ws[64 * 128];
    __shared__ float s_sc[64], s_sh[64];
    const int t = threadIdx.x;
    const int m0 = blockIdx.x * 128;
    for (int i = t; i < 64 * 128; i += 256) Ws[i] = Wt2[i];
    if (t < 64) { s_sc[t] = ss2[t]; s_sh[t] = ss2[64 + t]; }
    __syncthreads();
    {
        const int tq = t >> 2, qq = t & 3;
#pragma unroll
        for (int rr = 0; rr < 2; ++rr) {
            const int r = rr * 64 + tq;
            const float* hrow = h2 + (size_t)(m0 + r) * 64;
#pragma unroll
            for (int rep = 0; rep < 4; ++rep) {
                const int c4 = qq * 4 + rep * 16;
                float4 v = *(const float4*)(hrow + c4);
                Ft[(c4 + 0) * 128 + r] = fmaxf(0.f, fmaf(v.x, s_sc[c4 + 0], s_sh[c4 + 0]));
                Ft[(c4 + 1) * 128 + r] = fmaxf(0.f, fmaf(v.y, s_sc[c4 + 1], s_sh[c4 + 1]));
                Ft[(c4 + 2) * 128 + r] = fmaxf(0.f, fmaf(v.z, s_sc[c4 + 2], s_sh[c4 + 2]));
                Ft[(c4 + 3) * 128 + r] = fmaxf(0.f, fmaf(v.w, s_sc[c4 + 3], s_sh[c4 + 3]));
            }
        }
    }
    __syncthreads();
    const int rg = t >> 4;  // 0..15 -> rows rg*8..+7  (all within group rg>>2)
    const int cg = t & 15;  // 0..15 -> cols cg*8..+7
    float4 ba = *(const float4*)(bias2 + cg * 8);
    float4 bb = *(const float4*)(bias2 + cg * 8 + 4);
    float acc[8][8];
#pragma unroll
    for (int j = 0; j < 8; ++j) {
        acc[j][0] = ba.x; acc[j][1] = ba.y; acc[j][2] = ba.z; acc[j][3] = ba.w;
        acc[j][4] = bb.x; acc[j][5] = bb.y; acc[j][6] = bb.z; acc[j][7] = bb.w;
    }
    for (int kk = 0; kk < 64; ++kk) {
        float4 fa = *(const float4*)(Ft + kk * 128 + rg * 8);
        float4 fb = *(const float4*)(Ft + kk * 128 + rg * 8 + 4);
        float4 wa = *(const float4*)(Ws + kk * 128 + cg * 8);
        float4 wb = *(const float4*)(Ws + kk * 128 + cg * 8 + 4);
        float fv[8] = {fa.x, fa.y, fa.z, fa.w, fb.x, fb.y, fb.z, fb.w};
        float wv[8] = {wa.x, wa.y, wa.z, wa.w, wb.x, wb.y, wb.z, wb.w};
#pragma unroll
        for (int j = 0; j < 8; ++j)
#pragma unroll
            for (int i = 0; i < 8; ++i) acc[j][i] = fmaf(fv[j], wv[i], acc[j][i]);
    }
    float ls[8] = {0,0,0,0,0,0,0,0}, lq[8] = {0,0,0,0,0,0,0,0};
    float pm[8], pn[8];
#pragma unroll
    for (int i = 0; i < 8; ++i) { pm[i] = acc[0][i]; pn[i] = acc[0][i]; }
#pragma unroll
    for (int j = 0; j < 8; ++j)
#pragma unroll
        for (int i = 0; i < 8; ++i) {
            float v = acc[j][i];
            ls[i] += v; lq[i] += v * v;
            pm[i] = fmaxf(pm[i], v); pn[i] = fminf(pn[i], v);
        }
    __syncthreads();
    float* part_s = Ft;        // [16][128]
    float* part_q = Ft + 2048; // [16][128]
    float* part_m = Ft + 4096; // [16][128]
    float* part_n = Ft + 6144; // [16][128]
#pragma unroll
    for (int i = 0; i < 8; ++i) {
        part_s[rg * 128 + cg * 8 + i] = ls[i];
        part_q[rg * 128 + cg * 8 + i] = lq[i];
        part_m[rg * 128 + cg * 8 + i] = pm[i];
        part_n[rg * 128 + cg * 8 + i] = pn[i];
    }
    __syncthreads();
    if (t < 128) {
        float s = 0.f, q = 0.f;
#pragma unroll
        for (int rgi = 0; rgi < 16; ++rgi) { s += part_s[rgi * 128 + t]; q += part_q[rgi * 128 + t]; }
        int cp = blockIdx.x & (NCOPY - 1);
        atomicAdd(&sum2[cp * 128 + t], s);
        atomicAdd(&ssq2[cp * 128 + t], q);
    }
    for (int e = t; e < 512; e += 256) {
        int g = e >> 7, c = e & 127;
        float M = part_m[(g * 4 + 0) * 128 + c];
        M = fmaxf(M, part_m[(g * 4 + 1) * 128 + c]);
        M = fmaxf(M, part_m[(g * 4 + 2) * 128 + c]);
        M = fmaxf(M, part_m[(g * 4 + 3) * 128 + c]);
        float N = part_n[(g * 4 + 0) * 128 + c];
        N = fminf(N, part_n[(g * 4 + 1) * 128 + c]);
        N = fminf(N, part_n[(g * 4 + 2) * 128 + c]);
        N = fminf(N, part_n[(g * 4 + 3) * 128 + c]);
        int grp = blockIdx.x * 4 + g;              // == b*1024 + s
        gmax[(size_t)grp * 128 + c] = M;
        gmin[(size_t)grp * 128 + c] = N;
    }
}

// ---------------- pool2: apply BN3+ReLU to pooled max/min, transposed store ----------------
__global__ __launch_bounds__(256) void k_pool2(const float* __restrict__ gmax,
                                               const float* __restrict__ gmin,
                                               const float* __restrict__ ss3,
                                               float* __restrict__ outp)
{
    int idx = blockIdx.x * 256 + threadIdx.x;      // 1,048,576 = 8*128*1024
    int b = idx >> 17;
    int c = (idx >> 10) & 127;
    int s = idx & 1023;
    int grp = (b << 10) + s;
    float a = ss3[c], sh = ss3[128 + c];
    float m = (a >= 0.f) ? gmax[(size_t)grp * 128 + c] : gmin[(size_t)grp * 128 + c];
    outp[idx] = fmaxf(0.f, fmaf(m, a, sh));
}

// ---------------- finalize BN stats -> scale/shift ----------------
__global__ void k_finalize(const float* __restrict__ sum, const float* __restrict__ ssq,
                           const float* __restrict__ g, const float* __restrict__ beta,
                           float* __restrict__ ss, int nc)
{
    int c = threadIdx.x;
    if (c >= nc) return;
    float s = 0.f, q = 0.f;
    for (int k = 0; k < NCOPY; ++k) { s += sum[k * nc + c]; q += ssq[k * nc + c]; }
    const float inv = 1.0f / 262144.0f;
    float mean = s * inv;
    float var = q * inv - mean * mean;
    float rstd = 1.0f / sqrtf(var + 1e-5f);
    float scale = g[c] * rstd;
    ss[c] = scale;
    ss[nc + c] = beta[c] - mean * scale;
}

extern "C" void kernel_launch(void* const* d_in, const int* in_sizes, int n_in,
                              void* d_out, int out_size, void* d_ws, size_t ws_size,
                              hipStream_t stream)
{
    const float* xyz    = (const float*)d_in[0];
    const float* points = (const float*)d_in[1];
    const float* w0 = (const float*)d_in[2];
    const float* b0 = (const float*)d_in[3];
    const float* gm0 = (const float*)d_in[4];
    const float* bt0 = (const float*)d_in[5];
    const float* w1 = (const float*)d_in[6];
    const float* b1 = (const float*)d_in[7];
    const float* gm1 = (const float*)d_in[8];
    const float* bt1 = (const float*)d_in[9];
    const float* w2 = (const float*)d_in[10];
    const float* b2 = (const float*)d_in[11];
    const float* gm2 = (const float*)d_in[12];
    const float* bt2 = (const float*)d_in[13];
    float* out = (float*)d_out;

    char* p = (char*)d_ws;
    auto alloc = [&](size_t nbytes) -> void* {
        void* r = (void*)p;
        p += (nbytes + 255) & ~(size_t)255;
        return r;
    };
    float* fps_pts = (float*)alloc((size_t)NB * SP * 3 * 4);
    int*   ball_idx = (int*)alloc((size_t)NB * SP * KS * 4);
    float* pts_t = (float*)alloc((size_t)NB * NP * CD * 4);
    float* h1 = (float*)alloc((size_t)MROWS * 64 * 4);
    float* h2 = (float*)alloc((size_t)MROWS * 64 * 4);
    float* gmax = (float*)alloc((size_t)NB * SP * 128 * 4);
    float* gmin = (float*)alloc((size_t)NB * SP * 128 * 4);
    float* Wt0 = (float*)alloc(67 * 64 * 4);
    float* Wt1 = (float*)alloc(64 * 64 * 4);
    float* Wt2 = (float*)alloc(64 * 128 * 4);
    float* stats = (float*)alloc(8192 * 4);
    float* ss1 = (float*)alloc(128 * 4);
    float* ss2 = (float*)alloc(128 * 4);
    float* ss3 = (float*)alloc(256 * 4);

    float* sum0 = stats;
    float* ssq0 = stats + 16 * 64;
    float* sum1 = stats + 2 * 16 * 64;
    float* ssq1 = stats + 3 * 16 * 64;
    float* sum2 = stats + 4 * 16 * 64;
    float* ssq2 = sum2 + 16 * 128;

    k_fps_pre<<<NB + NB * (NP / 64) + 1, 512, 0, stream>>>(
        xyz, fps_pts, out, points, pts_t, w0, w1, w2, Wt0, Wt1, Wt2, stats);
    k_ballquery<<<(NB * SP) / 4, 256, 0, stream>>>(xyz, fps_pts, ball_idx);
    k_layer1<<<MROWS / 128, 256, 0, stream>>>(xyz, pts_t, fps_pts, ball_idx, Wt0, b0, h1, sum0, ssq0);
    k_finalize<<<1, 128, 0, stream>>>(sum0, ssq0, gm0, bt0, ss1, 64);
    k_layer2<<<MROWS / 128, 256, 0, stream>>>(h1, Wt1, b1, ss1, h2, sum1, ssq1);
    k_finalize<<<1, 128, 0, stream>>>(sum1, ssq1, gm1, bt1, ss2, 64);
    k_layer3<<<MROWS / 128, 256, 0, stream>>>(h2, Wt2, b2, ss2, sum2, ssq2, gmax, gmin);
    k_finalize<<<1, 128, 0, stream>>>(sum2, ssq2, gm2, bt2, ss3, 128);
    k_pool2<<<(NB * SP * 128) / 256, 256, 0, stream>>>(gmax, gmin, ss3, out + 24576);
}

// Round 10
// 1087.406 us; speedup vs baseline: 1.1914x; 1.0918x over previous
//
#include <hip/hip_runtime.h>

#define NB 8
#define NP 8192
#define SP 1024
#define KS 32
#define CD 64
#define MROWS (NB*SP*KS)
#define NCOPY 16

typedef float v2f __attribute__((ext_vector_type(2)));
typedef unsigned long long u64;

// EXACT u64 max via v_max_f64 on the raw bits. Valid because every key in this kernel has
// bit63==0 and high-word < 0x7FF00000 (dist_bits <= f32(1e10) = 0x501502F9): as f64 the
// values are non-negative and finite (never NaN/Inf); for non-negative finite doubles,
// IEEE bit-pattern order == value order (subnormals included; CDNA f64 never flushes
// denormals); equal keys are identical bits. One v_max_f64 replaces cmp_u64 + 2 cndmask.
__device__ __forceinline__ u64 u64max_f64(u64 a, u64 b) {
    double m = fmax(__longlong_as_double((long long)a), __longlong_as_double((long long)b));
    return (u64)__double_as_longlong(m);
}

// one DPP max step on a u64 key: pure VALU, no LDS. ctrl is a template param because
// __builtin_amdgcn_update_dpp requires an immediate. old=src + bound_ctrl=false ->
// lanes with no valid source keep their own value (identity for max).
template <int CTRL>
__device__ __forceinline__ u64 dpp_max_step(u64 x) {
    int lo = (int)(unsigned)(x & 0xffffffffull);
    int hi = (int)(unsigned)(x >> 32);
    int slo = __builtin_amdgcn_update_dpp(lo, lo, CTRL, 0xf, 0xf, false);
    int shi = __builtin_amdgcn_update_dpp(hi, hi, CTRL, 0xf, 0xf, false);
    u64 y = ((u64)(unsigned)shi << 32) | (unsigned)slo;
    return u64max_f64(x, y);
}

// ---------------- fused FPS (blocks 0..7) + points-transpose (8..1031) + weight-prep (1032) ----------
// FPS r10: r9 (Morton-sort + bound-prune + tagged LDS spin-exchange) with all u64 max
// machinery lowered to v_max_f64 (exactness proof above), and the cross-wave ladder cut
// 4->3 steps + readlane(7) (slot replication covers 0..7 at lane 7 of each 16-row; this
// exact pattern was bit-exact-verified in r1). ~130 -> ~50 instrs/wave/iter of reduce
// machinery; shorter dependent chain. Everything else r9-verbatim.
__global__ __launch_bounds__(512, 1) void k_fps_pre(const float* __restrict__ xyz,
                                                    float* __restrict__ fps_pts,
                                                    float* __restrict__ out_nx,
                                                    const float* __restrict__ points,
                                                    float* __restrict__ pts_t,
                                                    const float* __restrict__ w0,
                                                    const float* __restrict__ w1,
                                                    const float* __restrict__ w2,
                                                    float* __restrict__ Wt0,
                                                    float* __restrict__ Wt1,
                                                    float* __restrict__ Wt2,
                                                    float* __restrict__ stats)
{
#pragma clang fp contract(off)
    __shared__ __align__(16) unsigned char smem[131072 + 2560];
    const int blk = blockIdx.x;
    const int t = threadIdx.x;

    if (blk >= NB) {
        if (blk >= NB + NB * (NP / 64)) {
            // weight prep: zero stats, transpose weights to [kk][c]
            for (int i = t; i < 8192; i += 512) stats[i] = 0.f;
            for (int i = t; i < 64 * 67; i += 512) { int c = i / 67, kk = i % 67; Wt0[kk * 64 + c] = w0[i]; }
            for (int i = t; i < 64 * 64; i += 512) { int c = i >> 6, kk = i & 63; Wt1[kk * 64 + c] = w1[i]; }
            for (int i = t; i < 128 * 64; i += 512) { int c = i >> 6, kk = i & 63; Wt2[kk * 128 + c] = w2[i]; }
            return;
        }
        // points transpose (B,64,N) -> (B,N,64), 64x64 tile, 512 threads
        float (*tile)[65] = (float(*)[65])smem;
        const int tblk = blk - NB;
        const int b = tblk >> 7;
        const int n0 = (tblk & 127) << 6;
        const float* pb = points + (size_t)b * CD * NP;
        const int c = t & 63;
        const int dr = t >> 6;                 // 0..7
#pragma unroll
        for (int it = 0; it < 8; ++it) {
            int d = dr + it * 8;
            tile[d][c] = pb[(size_t)d * NP + n0 + c];
        }
        __syncthreads();
#pragma unroll
        for (int it = 0; it < 8; ++it) {
            int nn = dr + it * 8;
            pts_t[((size_t)b * NP + n0 + nn) * CD + c] = tile[c][nn];
        }
        return;
    }

    // ---- FPS path ----
    float4* s_p  = (float4*)smem;                          // 128 KB sorted pts (xyz + gid bits)
    int*    s_cnt = (int*)(smem + 131072);                 // 512 cell counts/offsets
    u64 (*s_wk)[8] = (u64(*)[8])(smem + 131072 + 2048);    // parity-dbuf leader keys (tagged)
    const int b = blk;
    const int lane = t & 63, wid = t >> 6;                 // 8 waves
    const float* xb = xyz + (size_t)b * 3 * NP;

    // -- one-time Morton counting sort (r8-verbatim) --
    float lx[16], ly[16], lz[16];
    int   lcell[16];
    s_cnt[t < 512 ? t : 0] = 0;                            // t in [0,512): zero own slot
    if (t < 16) ((u64*)s_wk)[t] = (u64)1 << 26;            // stale-tag init: iter 0/1 expect tag 0
    __syncthreads();
#pragma unroll
    for (int j = 0; j < 16; ++j) {
        const int n = t + j * 512;                         // r0-coalesced load
        lx[j] = xb[n]; ly[j] = xb[NP + n]; lz[j] = xb[2 * NP + n];
        int ix = (int)(lx[j] * 8.f); ix = ix < 0 ? 0 : (ix > 7 ? 7 : ix);
        int iy = (int)(ly[j] * 8.f); iy = iy < 0 ? 0 : (iy > 7 ? 7 : iy);
        int iz = (int)(lz[j] * 8.f); iz = iz < 0 ? 0 : (iz > 7 ? 7 : iz);
        int sx = ((ix & 4) << 4) | ((ix & 2) << 2) | (ix & 1);
        int sy = ((iy & 4) << 4) | ((iy & 2) << 2) | (iy & 1);
        int sz = ((iz & 4) << 4) | ((iz & 2) << 2) | (iz & 1);
        lcell[j] = (sx << 2) | (sy << 1) | sz;             // Morton id, 0..511
        atomicAdd(&s_cnt[lcell[j]], 1);
    }
    __syncthreads();
    if (t == 0) {                                          // exclusive prefix (one-time ~2us)
        int run = 0;
        for (int c2 = 0; c2 < 512; ++c2) { int v = s_cnt[c2]; s_cnt[c2] = run; run += v; }
    }
    __syncthreads();
#pragma unroll
    for (int j = 0; j < 16; ++j) {
        int pos = atomicAdd(&s_cnt[lcell[j]], 1);
        s_p[pos] = make_float4(lx[j], ly[j], lz[j], __uint_as_float((unsigned)(t + j * 512)));
    }
    __syncthreads();
    // -- reload sorted chunk [16t, 16t+16): coords, key low-words, bbox --
    float px[16], py[16], pz[16], dv16[16];
    unsigned klo[16];
    float blx = 1e30f, bly = 1e30f, blz = 1e30f, bhx = -1e30f, bhy = -1e30f, bhz = -1e30f;
#pragma unroll
    for (int j = 0; j < 16; ++j) {
        float4 v = s_p[16 * t + j];
        px[j] = v.x; py[j] = v.y; pz[j] = v.z;
        unsigned g = __float_as_uint(v.w);                 // original gid (raw bits)
        klo[j] = ((8191u - g) << 13) | (unsigned)(16 * t + j);
        dv16[j] = 1e10f;
        blx = fminf(blx, v.x); bhx = fmaxf(bhx, v.x);
        bly = fminf(bly, v.y); bhy = fmaxf(bhy, v.y);
        blz = fminf(blz, v.z); bhz = fmaxf(bhz, v.z);
    }
    float cx = xb[0], cy = xb[NP], cz = xb[2 * NP];
    float cellmax = 1e10f;                                 // max dv over this thread's chunk
    u64 wkey = 0;                                          // lane63's cached wave key
    float hx0 = 0.f, hy0 = 0.f, hz0 = 0.f;                 // captured centroid of iteration i == t
    float hx1 = 0.f, hy1 = 0.f, hz1 = 0.f;                 // captured centroid of iteration i == t + 512
    __syncthreads();
    for (int i = 0; i < SP; ++i) {
        if (i == t)       { hx0 = cx; hy0 = cy; hz0 = cz; }
        if (i == t + 512) { hx1 = cx; hy1 = cy; hz1 = cz; }
        // conservative bound: skip iff dmin2(c,bbox)*0.999 >= cellmax (slack >> fp32 rounding)
        float ddx = fmaxf(fmaxf(blx - cx, cx - bhx), 0.f);
        float ddy = fmaxf(fmaxf(bly - cy, cy - bhy), 0.f);
        float ddz = fmaxf(fmaxf(blz - cz, cz - bhz), 0.f);
        float dmin = ddx * ddx + ddy * ddy;
        dmin = dmin + ddz * ddz;
        bool act = (dmin * 0.999f < cellmax);
        if (__ballot(act)) {
            // full update for this wave (EXACT fp32: same dag as r0 — sub, mul, (x2+y2)+z2, min)
            u64 bk = 0; float cm = 0.f;
#pragma unroll
            for (int j = 0; j < 16; ++j) {
                float dx = px[j] - cx;
                float dy = py[j] - cy;
                float dz = pz[j] - cz;
                float d = dx * dx + dy * dy;
                d = d + dz * dz;
                float nd = fminf(dv16[j], d);
                dv16[j] = nd;
                cm = fmaxf(cm, nd);
                u64 k = ((u64)__float_as_uint(nd) << 32) | klo[j];
                bk = u64max_f64(bk, k);        // exact u64 max (proof at u64max_f64)
            }
            cellmax = cm;
            // per-wave DPP max ladder; lane 63 ends with the wave max
            bk = dpp_max_step<0x111>(bk);      // row_shr:1
            bk = dpp_max_step<0x112>(bk);      // row_shr:2
            bk = dpp_max_step<0x114>(bk);      // row_shr:4
            bk = dpp_max_step<0x118>(bk);      // row_shr:8
            bk = dpp_max_step<0x142>(bk);      // row_bcast:15
            bk = dpp_max_step<0x143>(bk);      // row_bcast:31
            wkey = bk;
        }
        const int par = i & 1;
        const u64 tagbit = (u64)((unsigned)(i >> 1) & 1u) << 26;
        if (lane == 63)                        // publish tagged key (cached if wave skipped)
            *(volatile u64*)&s_wk[par][wid] = wkey | tagbit;
        // spin-exchange (replaces s_barrier): poll the 8 iter-i slots until all tags match.
        // Single read per pass; the passing read IS the reduce input (no re-read race).
        u64 rk;
        for (;;) {
            rk = *(volatile u64*)&s_wk[par][lane & 7];
            bool bad = ((rk >> 26) & 1ull) != (u64)((unsigned)(i >> 1) & 1u);
            if (!__ballot(bad)) break;
        }
        // cross-wave reduce: slots replicated twice per 16-lane row; shr 1,2,4 -> lane 7
        // holds max over slots 0..7 (pattern bit-exact-verified in r1); tag bit common to
        // all keys this iteration -> ordering unaffected.
        rk = dpp_max_step<0x111>(rk);
        rk = dpp_max_step<0x112>(rk);
        rk = dpp_max_step<0x114>(rk);
        const int wlo = __builtin_amdgcn_readlane((int)(unsigned)(rk & 0xffffffffull), 7);
        const int wpos = wlo & 0x1FFF;         // sorted position of the winner
        const float4 c = s_p[wpos];            // uniform broadcast ds_read_b128
        cx = c.x; cy = c.y; cz = c.z;
        // drift <=1 guaranteed by the tag protocol; parity slot i is overwritten only at i+2
    }
    // deferred outputs: thread t owns fps points t and t+512
    fps_pts[(b * SP + t) * 3 + 0] = hx0;
    fps_pts[(b * SP + t) * 3 + 1] = hy0;
    fps_pts[(b * SP + t) * 3 + 2] = hz0;
    fps_pts[(b * SP + t + 512) * 3 + 0] = hx1;
    fps_pts[(b * SP + t + 512) * 3 + 1] = hy1;
    fps_pts[(b * SP + t + 512) * 3 + 2] = hz1;
    out_nx[(size_t)b * 3 * SP + 0 * SP + t] = hx0;
    out_nx[(size_t)b * 3 * SP + 1 * SP + t] = hy0;
    out_nx[(size_t)b * 3 * SP + 2 * SP + t] = hz0;
    out_nx[(size_t)b * 3 * SP + 0 * SP + t + 512] = hx1;
    out_nx[(size_t)b * 3 * SP + 1 * SP + t + 512] = hy1;
    out_nx[(size_t)b * 3 * SP + 2 * SP + t + 512] = hz1;
}

// ---------------- ball query: one wave per query, ordered first-32 append (r0-verbatim) --------
__global__ __launch_bounds__(256) void k_ballquery(const float* __restrict__ xyz,
                                                   const float* __restrict__ fps_pts,
                                                   int* __restrict__ ball_idx)
{
    const int wib = threadIdx.x >> 6;
    const int lane = threadIdx.x & 63;
    const int wid = blockIdx.x * 4 + wib;          // b*SP + s
    const int b = wid >> 10;
    const float* xb = xyz + (size_t)b * 3 * NP;
    const float qx = fps_pts[wid * 3 + 0];
    const float qy = fps_pts[wid * 3 + 1];
    const float qz = fps_pts[wid * 3 + 2];
    __shared__ int s_list[4][KS];
    int* list = s_list[wib];
    const float r2 = (float)(0.2 * 0.2);           // 0.039999999f — matches python double->f32
    int found = 0;
    for (int base = 0; base < NP && found < KS; base += 64) {
        int n = base + lane;
        float dx = __fsub_rn(qx, xb[n]);
        float dy = __fsub_rn(qy, xb[NP + n]);
        float dz = __fsub_rn(qz, xb[2 * NP + n]);
        float d = __fadd_rn(__fadd_rn(__fmul_rn(dx, dx), __fmul_rn(dy, dy)), __fmul_rn(dz, dz));
        bool in = !(d > r2);
        unsigned long long m = __ballot(in);
        int before = __popcll(m & ((1ull << lane) - 1ull));
        int pos = found + before;
        if (in && pos < KS) list[pos] = n;
        found += __popcll(m);
    }
    int first = list[0];
    if (lane < KS) {
        int v = (lane < found) ? list[lane] : first;
        ball_idx[wid * KS + lane] = v;
    }
}

// ---------------- layer1: gather(feat 67) + GEMM(67->64) + stats (r0-verbatim) ----------------
__global__ __launch_bounds__(256) void k_layer1(const float* __restrict__ xyz,
                                                const float* __restrict__ pts_t,
                                                const float* __restrict__ fps_pts,
                                                const int* __restrict__ ball_idx,
                                                const float* __restrict__ Wt0,
                                                const float* __restrict__ bias0,
                                                float* __restrict__ h1,
                                                float* __restrict__ sum0,
                                                float* __restrict__ ssq0)
{
    __shared__ __align__(16) float Ft[67 * 128];
    __shared__ __align__(16) float Ws[67 * 64];
    __shared__ int   s_idx[128];
    __shared__ float s_q[4][3];
    const int t = threadIdx.x;
    const int m0 = blockIdx.x * 128;
    const int g0 = m0 >> 5;
    const int b = g0 >> 10;
    if (t < 128) s_idx[t] = ball_idx[g0 * KS + t];
    if (t < 12) ((float*)s_q)[t] = fps_pts[g0 * 3 + t];
    for (int i = t; i < 67 * 64; i += 256) Ws[i] = Wt0[i];
    __syncthreads();
    {
        const int r = t >> 1, half = t & 1;
        const int n = s_idx[r];
        const float* prow = pts_t + ((size_t)b * NP + n) * CD;
#pragma unroll
        for (int rep = 0; rep < 8; ++rep) {
            const int c4 = half * 4 + rep * 8;
            float4 v = *(const float4*)(prow + c4);
            Ft[(3 + c4 + 0) * 128 + r] = v.x;
            Ft[(3 + c4 + 1) * 128 + r] = v.y;
            Ft[(3 + c4 + 2) * 128 + r] = v.z;
            Ft[(3 + c4 + 3) * 128 + r] = v.w;
        }
        if (t < 128) {
            const int n2 = s_idx[t];
            const int g = t >> 5;
            const float* xb = xyz + (size_t)b * 3 * NP;
            Ft[0 * 128 + t] = __fsub_rn(xb[n2],          s_q[g][0]);
            Ft[1 * 128 + t] = __fsub_rn(xb[NP + n2],     s_q[g][1]);
            Ft[2 * 128 + t] = __fsub_rn(xb[2 * NP + n2], s_q[g][2]);
        }
    }
    __syncthreads();
    const int rg = t >> 3;   // 0..31 -> rows rg*4..+3
    const int cg = t & 7;    // 0..7  -> cols cg*8..+7
    float4 ba = *(const float4*)(bias0 + cg * 8);
    float4 bb = *(const float4*)(bias0 + cg * 8 + 4);
    float acc[4][8];
#pragma unroll
    for (int j = 0; j < 4; ++j) {
        acc[j][0] = ba.x; acc[j][1] = ba.y; acc[j][2] = ba.z; acc[j][3] = ba.w;
        acc[j][4] = bb.x; acc[j][5] = bb.y; acc[j][6] = bb.z; acc[j][7] = bb.w;
    }
    for (int kk = 0; kk < 67; ++kk) {
        float4 f = *(const float4*)(Ft + kk * 128 + rg * 4);
        float4 wa = *(const float4*)(Ws + kk * 64 + cg * 8);
        float4 wb = *(const float4*)(Ws + kk * 64 + cg * 8 + 4);
        float fv[4] = {f.x, f.y, f.z, f.w};
        float wv[8] = {wa.x, wa.y, wa.z, wa.w, wb.x, wb.y, wb.z, wb.w};
#pragma unroll
        for (int j = 0; j < 4; ++j)
#pragma unroll
            for (int i = 0; i < 8; ++i) acc[j][i] = fmaf(fv[j], wv[i], acc[j][i]);
    }
    float ls[8] = {0,0,0,0,0,0,0,0}, lq[8] = {0,0,0,0,0,0,0,0};
#pragma unroll
    for (int j = 0; j < 4; ++j) {
        int m = m0 + rg * 4 + j;
        float4 oa = {acc[j][0], acc[j][1], acc[j][2], acc[j][3]};
        float4 ob = {acc[j][4], acc[j][5], acc[j][6], acc[j][7]};
        *(float4*)(h1 + (size_t)m * 64 + cg * 8) = oa;
        *(float4*)(h1 + (size_t)m * 64 + cg * 8 + 4) = ob;
#pragma unroll
        for (int i = 0; i < 8; ++i) { float v = acc[j][i]; ls[i] += v; lq[i] += v * v; }
    }
    __syncthreads();           // Ft reuse for stats partials
    float* part_s = Ft;        // [32][64]
    float* part_q = Ft + 2048; // [32][64]
#pragma unroll
    for (int i = 0; i < 8; ++i) { part_s[rg * 64 + cg * 8 + i] = ls[i]; part_q[rg * 64 + cg * 8 + i] = lq[i]; }
    __syncthreads();
    if (t < 64) {
        float s = 0.f, q = 0.f;
#pragma unroll
        for (int rgi = 0; rgi < 32; ++rgi) { s += part_s[rgi * 64 + t]; q += part_q[rgi * 64 + t]; }
        int cp = blockIdx.x & (NCOPY - 1);
        atomicAdd(&sum0[cp * 64 + t], s);
        atomicAdd(&ssq0[cp * 64 + t], q);
    }
}

// ---------------- layer2: BN1+ReLU on load + GEMM(64->64) + stats ----------------
__global__ __launch_bounds__(256) void k_layer2(const float* __restrict__ h1,
                                                const float* __restrict__ Wt1,
                                                const float* __restrict__ bias1,
                                                const float* __restrict__ ss1,
                                                float* __restrict__ h2,
                                                float* __restrict__ sum1,
                                                float* __restrict__ ssq1)
{
    __shared__ __align__(16) float Ft[64 * 128];
    __shared__ __align__(16) float Ws[64 * 64];
    __shared__ float s_sc[64], s_sh[64];
    const int t = threadIdx.x;
    const int m0 = blockIdx.x * 128;
    for (int i = t; i < 64 * 64; i += 256) Ws[i] = Wt1[i];
    if (t < 64) { s_sc[t] = ss1[t]; s_sh[t] = ss1[64 + t]; }
    __syncthreads();
    {
        const int tq = t >> 2, qq = t & 3;
#pragma unroll
        for (int rr = 0; rr < 2; ++rr) {
            const int r = rr * 64 + tq;
            const float* hrow = h1 + (size_t)(m0 + r) * 64;
#pragma unroll
            for (int rep = 0; rep < 4; ++rep) {
                const int c4 = qq * 4 + rep * 16;
                float4 v = *(const float4*)(hrow + c4);
                Ft[(c4 + 0) * 128 + r] = fmaxf(0.f, fmaf(v.x, s_sc[c4 + 0], s_sh[c4 + 0]));
                Ft[(c4 + 1) * 128 + r] = fmaxf(0.f, fmaf(v.y, s_sc[c4 + 1], s_sh[c4 + 1]));
                Ft[(c4 + 2) * 128 + r] = fmaxf(0.f, fmaf(v.z, s_sc[c4 + 2], s_sh[c4 + 2]));
                Ft[(c4 + 3) * 128 + r] = fmaxf(0.f, fmaf(v.w, s_sc[c4 + 3], s_sh[c4 + 3]));
            }
        }
    }
    __syncthreads();
    const int rg = t >> 3;
    const int cg = t & 7;
    float4 ba = *(const float4*)(bias1 + cg * 8);
    float4 bb = *(const float4*)(bias1 + cg * 8 + 4);
    float acc[4][8];
#pragma unroll
    for (int j = 0; j < 4; ++j) {
        acc[j][0] = ba.x; acc[j][1] = ba.y; acc[j][2] = ba.z; acc[j][3] = ba.w;
        acc[j][4] = bb.x; acc[j][5] = bb.y; acc[j][6] = bb.z; acc[j][7] = bb.w;
    }
    for (int kk = 0; kk < 64; ++kk) {
        float4 f = *(const float4*)(Ft + kk * 128 + rg * 4);
        float4 wa = *(const float4*)(Ws + kk * 64 + cg * 8);
        float4 wb = *(const float4*)(Ws + kk * 64 + cg * 8 + 4);
        float fv[4] = {f.x, f.y, f.z, f.w};
        float wv[8] = {wa.x, wa.y, wa.z, wa.w, wb.x, wb.y, wb.z, wb.w};
#pragma unroll
        for (int j = 0; j < 4; ++j)
#pragma unroll
            for (int i = 0; i < 8; ++i) acc[j][i] = fmaf(fv[j], wv[i], acc[j][i]);
    }
    float ls[8] = {0,0,0,0,0,0,0,0}, lq[8] = {0,0,0,0,0,0,0,0};
#pragma unroll
    for (int j = 0; j < 4; ++j) {
        int m = m0 + rg * 4 + j;
        float4 oa = {acc[j][0], acc[j][1], acc[j][2], acc[j][3]};
        float4 ob = {acc[j][4], acc[j][5], acc[j][6], acc[j][7]};
        *(float4*)(h2 + (size_t)m * 64 + cg * 8) = oa;
        *(float4*)(h2 + (size_t)m * 64 + cg * 8 + 4) = ob;
#pragma unroll
        for (int i = 0; i < 8; ++i) { float v = acc[j][i]; ls[i] += v; lq[i] += v * v; }
    }
    __syncthreads();
    float* part_s = Ft;
    float* part_q = Ft + 2048;
#pragma unroll
    for (int i = 0; i < 8; ++i) { part_s[rg * 64 + cg * 8 + i] = ls[i]; part_q[rg * 64 + cg * 8 + i] = lq[i]; }
    __syncthreads();
    if (t < 64) {
        float s = 0.f, q = 0.f;
#pragma unroll
        for (int rgi = 0; rgi < 32; ++rgi) { s += part_s[rgi * 64 + t]; q += part_q[rgi * 64 + t]; }
        int cp = blockIdx.x & (NCOPY - 1);
        atomicAdd(&sum1[cp * 64 + t], s);
        atomicAdd(&ssq1[cp * 64 + t], q);
    }
}

// ---------------- layer3: BN2+ReLU + GEMM(64->128) + stats + per-group max/min ----------------
// Pooling trick: max_k relu(a*h+b) == relu(a*max_k h + b) for a>=0 (min_k for a<0),
// exact in fp32 by monotonicity of fmaf/relu. So h3 is never materialized.
__global__ __launch_bounds__(256) void k_layer3(const float* __restrict__ h2,
                                                const float* __restrict__ Wt2,
                                                const float* __restrict__ bias2,
                                                const float* __restrict__ ss2,
                                                float* __restrict__ sum2,
                                                float* __restrict__ ssq2,
                                                float* __restrict__ gmax,
                                                float* __restrict__ gmin)
{
    __shared__ __align__(16) float Ft[64 * 128];
    __shared__ __align__(16) float Ws[64 * 128];
    __shared__ float s_sc[64], s_sh[64];
    const int t = threadIdx.x;
    const int m0 = blockIdx.x * 128;
    for (int i = t; i < 64 * 128; i += 256) Ws[i] = Wt2[i];
    if (t < 64) { s_sc[t] = ss2[t]; s_sh[t] = ss2[64 + t]; }
    __syncthreads();
    {
        const int tq = t >> 2, qq = t & 3;
#pragma unroll
        for (int rr = 0; rr < 2; ++rr) {
            const int r = rr * 64 + tq;
            const float* hrow = h2 + (size_t)(m0 + r) * 64;
#pragma unroll
            for (int rep = 0; rep < 4; ++rep) {
                const int c4 = qq * 4 + rep * 16;
                float4 v = *(const float4*)(hrow + c4);
                Ft[(c4 + 0) * 128 + r] = fmaxf(0.f, fmaf(v.x, s_sc[c4 + 0], s_sh[c4 + 0]));
                Ft[(c4 + 1) * 128 + r] = fmaxf(0.f, fmaf(v.y, s_sc[c4 + 1], s_sh[c4 + 1]));
                Ft[(c4 + 2) * 128 + r] = fmaxf(0.f, fmaf(v.z, s_sc[c4 + 2], s_sh[c4 + 2]));
                Ft[(c4 + 3) * 128 + r] = fmaxf(0.f, fmaf(v.w, s_sc[c4 + 3], s_sh[c4 + 3]));
            }
        }
    }
    __syncthreads();
    const int rg = t >> 4;  // 0..15 -> rows rg*8..+7  (all within group rg>>2)
    const int cg = t & 15;  // 0..15 -> cols cg*8..+7
    float4 ba = *(const float4*)(bias2 + cg * 8);
    float4 bb = *(const float4*)(bias2 + cg * 8 + 4);
    float acc[8][8];
#pragma unroll
    for (int j = 0; j < 8; ++j) {
        acc[j][0] = ba.x; acc[j][1] = ba.y; acc[j][2] = ba.z; acc[j][3] = ba.w;
        acc[j][4] = bb.x; acc[j][5] = bb.y; acc[j][6] = bb.z; acc[j][7] = bb.w;
    }
    for (int kk = 0; kk < 64; ++kk) {
        float4 fa = *(const float4*)(Ft + kk * 128 + rg * 8);
        float4 fb = *(const float4*)(Ft + kk * 128 + rg * 8 + 4);
        float4 wa = *(const float4*)(Ws + kk * 128 + cg * 8);
        float4 wb = *(const float4*)(Ws + kk * 128 + cg * 8 + 4);
        float fv[8] = {fa.x, fa.y, fa.z, fa.w, fb.x, fb.y, fb.z, fb.w};
        float wv[8] = {wa.x, wa.y, wa.z, wa.w, wb.x, wb.y, wb.z, wb.w};
#pragma unroll
        for (int j = 0; j < 8; ++j)
#pragma unroll
            for (int i = 0; i < 8; ++i) acc[j][i] = fmaf(fv[j], wv[i], acc[j][i]);
    }
    float ls[8] = {0,0,0,0,0,0,0,0}, lq[8] = {0,0,0,0,0,0,0,0};
    float pm[8], pn[8];
#pragma unroll
    for (int i = 0; i < 8; ++i) { pm[i] = acc[0][i]; pn[i] = acc[0][i]; }
#pragma unroll
    for (int j = 0; j < 8; ++j)
#pragma unroll
        for (int i = 0; i < 8; ++i) {
            float v = acc[j][i];
            ls[i] += v; lq[i] += v * v;
            pm[i] = fmaxf(pm[i], v); pn[i] = fminf(pn[i], v);
        }
    __syncthreads();
    float* part_s = Ft;        // [16][128]
    float* part_q = Ft + 2048; // [16][128]
    float* part_m = Ft + 4096; // [16][128]
    float* part_n = Ft + 6144; // [16][128]
#pragma unroll
    for (int i = 0; i < 8; ++i) {
        part_s[rg * 128 + cg * 8 + i] = ls[i];
        part_q[rg * 128 + cg * 8 + i] = lq[i];
        part_m[rg * 128 + cg * 8 + i] = pm[i];
        part_n[rg * 128 + cg * 8 + i] = pn[i];
    }
    __syncthreads();
    if (t < 128) {
        float s = 0.f, q = 0.f;
#pragma unroll
        for (int rgi = 0; rgi < 16; ++rgi) { s += part_s[rgi * 128 + t]; q += part_q[rgi * 128 + t]; }
        int cp = blockIdx.x & (NCOPY - 1);
        atomicAdd(&sum2[cp * 128 + t], s);
        atomicAdd(&ssq2[cp * 128 + t], q);
    }
    for (int e = t; e < 512; e += 256) {
        int g = e >> 7, c = e & 127;
        float M = part_m[(g * 4 + 0) * 128 + c];
        M = fmaxf(M, part_m[(g * 4 + 1) * 128 + c]);
        M = fmaxf(M, part_m[(g * 4 + 2) * 128 + c]);
        M = fmaxf(M, part_m[(g * 4 + 3) * 128 + c]);
        float N = part_n[(g * 4 + 0) * 128 + c];
        N = fminf(N, part_n[(g * 4 + 1) * 128 + c]);
        N = fminf(N, part_n[(g * 4 + 2) * 128 + c]);
        N = fminf(N, part_n[(g * 4 + 3) * 128 + c]);
        int grp = blockIdx.x * 4 + g;              // == b*1024 + s
        gmax[(size_t)grp * 128 + c] = M;
        gmin[(size_t)grp * 128 + c] = N;
    }
}

// ---------------- pool2: apply BN3+ReLU to pooled max/min, transposed store ----------------
__global__ __launch_bounds__(256) void k_pool2(const float* __restrict__ gmax,
                                               const float* __restrict__ gmin,
                                               const float* __restrict__ ss3,
                                               float* __restrict__ outp)
{
    int idx = blockIdx.x * 256 + threadIdx.x;      // 1,048,576 = 8*128*1024
    int b = idx >> 17;
    int c = (idx >> 10) & 127;
    int s = idx & 1023;
    int grp = (b << 10) + s;
    float a = ss3[c], sh = ss3[128 + c];
    float m = (a >= 0.f) ? gmax[(size_t)grp * 128 + c] : gmin[(size_t)grp * 128 + c];
    outp[idx] = fmaxf(0.f, fmaf(m, a, sh));
}

// ---------------- finalize BN stats -> scale/shift ----------------
__global__ void k_finalize(const float* __restrict__ sum, const float* __restrict__ ssq,
                           const float* __restrict__ g, const float* __restrict__ beta,
                           float* __restrict__ ss, int nc)
{
    int c = threadIdx.x;
    if (c >= nc) return;
    float s = 0.f, q = 0.f;
    for (int k = 0; k < NCOPY; ++k) { s += sum[k * nc + c]; q += ssq[k * nc + c]; }
    const float inv = 1.0f / 262144.0f;
    float mean = s * inv;
    float var = q * inv - mean * mean;
    float rstd = 1.0f / sqrtf(var + 1e-5f);
    float scale = g[c] * rstd;
    ss[c] = scale;
    ss[nc + c] = beta[c] - mean * scale;
}

extern "C" void kernel_launch(void* const* d_in, const int* in_sizes, int n_in,
                              void* d_out, int out_size, void* d_ws, size_t ws_size,
                              hipStream_t stream)
{
    const float* xyz    = (const float*)d_in[0];
    const float* points = (const float*)d_in[1];
    const float* w0 = (const float*)d_in[2];
    const float* b0 = (const float*)d_in[3];
    const float* gm0 = (const float*)d_in[4];
    const float* bt0 = (const float*)d_in[5];
    const float* w1 = (const float*)d_in[6];
    const float* b1 = (const float*)d_in[7];
    const float* gm1 = (const float*)d_in[8];
    const float* bt1 = (const float*)d_in[9];
    const float* w2 = (const float*)d_in[10];
    const float* b2 = (const float*)d_in[11];
    const float* gm2 = (const float*)d_in[12];
    const float* bt2 = (const float*)d_in[13];
    float* out = (float*)d_out;

    char* p = (char*)d_ws;
    auto alloc = [&](size_t nbytes) -> void* {
        void* r = (void*)p;
        p += (nbytes + 255) & ~(size_t)255;
        return r;
    };
    float* fps_pts = (float*)alloc((size_t)NB * SP * 3 * 4);
    int*   ball_idx = (int*)alloc((size_t)NB * SP * KS * 4);
    float* pts_t = (float*)alloc((size_t)NB * NP * CD * 4);
    float* h1 = (float*)alloc((size_t)MROWS * 64 * 4);
    float* h2 = (float*)alloc((size_t)MROWS * 64 * 4);
    float* gmax = (float*)alloc((size_t)NB * SP * 128 * 4);
    float* gmin = (float*)alloc((size_t)NB * SP * 128 * 4);
    float* Wt0 = (float*)alloc(67 * 64 * 4);
    float* Wt1 = (float*)alloc(64 * 64 * 4);
    float* Wt2 = (float*)alloc(64 * 128 * 4);
    float* stats = (float*)alloc(8192 * 4);
    float* ss1 = (float*)alloc(128 * 4);
    float* ss2 = (float*)alloc(128 * 4);
    float* ss3 = (float*)alloc(256 * 4);

    float* sum0 = stats;
    float* ssq0 = stats + 16 * 64;
    float* sum1 = stats + 2 * 16 * 64;
    float* ssq1 = stats + 3 * 16 * 64;
    float* sum2 = stats + 4 * 16 * 64;
    float* ssq2 = sum2 + 16 * 128;

    k_fps_pre<<<NB + NB * (NP / 64) + 1, 512, 0, stream>>>(
        xyz, fps_pts, out, points, pts_t, w0, w1, w2, Wt0, Wt1, Wt2, stats);
    k_ballquery<<<(NB * SP) / 4, 256, 0, stream>>>(xyz, fps_pts, ball_idx);
    k_layer1<<<MROWS / 128, 256, 0, stream>>>(xyz, pts_t, fps_pts, ball_idx, Wt0, b0, h1, sum0, ssq0);
    k_finalize<<<1, 128, 0, stream>>>(sum0, ssq0, gm0, bt0, ss1, 64);
    k_layer2<<<MROWS / 128, 256, 0, stream>>>(h1, Wt1, b1, ss1, h2, sum1, ssq1);
    k_finalize<<<1, 128, 0, stream>>>(sum1, ssq1, gm1, bt1, ss2, 64);
    k_layer3<<<MROWS / 128, 256, 0, stream>>>(h2, Wt2, b2, ss2, sum2, ssq2, gmax, gmin);
    k_finalize<<<1, 128, 0, stream>>>(sum2, ssq2, gm2, bt2, ss3, 128);
    k_pool2<<<(NB * SP * 128) / 256, 256, 0, stream>>>(gmax, gmin, ss3, out + 24576);
}

// Round 11
// 1073.591 us; speedup vs baseline: 1.2067x; 1.0129x over previous
//
#include <hip/hip_runtime.h>

#define NB 8
#define NP 8192
#define SP 1024
#define KS 32
#define CD 64
#define MROWS (NB*SP*KS)
#define NCOPY 16

typedef float v2f __attribute__((ext_vector_type(2)));
typedef unsigned long long u64;

// EXACT u64 max via v_max_f64 on the raw bits. Valid because every key in this kernel has
// bit63==0 and high-word < 0x7FF00000 (dist_bits <= f32(1e10) = 0x501502F9): as f64 the
// values are non-negative and finite (never NaN/Inf); for non-negative finite doubles,
// IEEE bit-pattern order == value order (subnormals included; CDNA f64 never flushes
// denormals); equal keys are identical bits. One v_max_f64 replaces cmp_u64 + 2 cndmask.
__device__ __forceinline__ u64 u64max_f64(u64 a, u64 b) {
    double m = fmax(__longlong_as_double((long long)a), __longlong_as_double((long long)b));
    return (u64)__double_as_longlong(m);
}

// one DPP max step on a u64 key: pure VALU, no LDS. ctrl is a template param because
// __builtin_amdgcn_update_dpp requires an immediate. old=src + bound_ctrl=false ->
// lanes with no valid source keep their own value (identity for max).
template <int CTRL>
__device__ __forceinline__ u64 dpp_max_step(u64 x) {
    int lo = (int)(unsigned)(x & 0xffffffffull);
    int hi = (int)(unsigned)(x >> 32);
    int slo = __builtin_amdgcn_update_dpp(lo, lo, CTRL, 0xf, 0xf, false);
    int shi = __builtin_amdgcn_update_dpp(hi, hi, CTRL, 0xf, 0xf, false);
    u64 y = ((u64)(unsigned)shi << 32) | (unsigned)slo;
    return u64max_f64(x, y);
}

// in-block BN finalize (replaces the k_finalize kernel; r11): EXACT k_finalize arithmetic —
// sequential k=0..15 adds, then mean/var/rstd/scale/shift in the same dag -> bit-identical
// scale/shift in every block.
__device__ __forceinline__ void bn_finalize_ch(const float* __restrict__ sum,
                                               const float* __restrict__ ssq,
                                               const float* __restrict__ g,
                                               const float* __restrict__ beta,
                                               int nc, int c, float* sc, float* sh)
{
    float s = 0.f, q = 0.f;
#pragma unroll
    for (int k = 0; k < NCOPY; ++k) { s += sum[k * nc + c]; q += ssq[k * nc + c]; }
    const float inv = 1.0f / 262144.0f;
    float mean = s * inv;
    float var = q * inv - mean * mean;
    float rstd = 1.0f / sqrtf(var + 1e-5f);
    float scale = g[c] * rstd;
    *sc = scale;
    *sh = beta[c] - mean * scale;
}

// ---------------- fused FPS (blocks 0..7) + points-transpose (8..1031) + weight-prep (1032) ----------
// FPS r10 (unchanged, certified 811us): Morton-sort + bound-prune + tagged LDS spin-exchange
// + v_max_f64 key reduction. Do not touch.
__global__ __launch_bounds__(512, 1) void k_fps_pre(const float* __restrict__ xyz,
                                                    float* __restrict__ fps_pts,
                                                    float* __restrict__ out_nx,
                                                    const float* __restrict__ points,
                                                    float* __restrict__ pts_t,
                                                    const float* __restrict__ w0,
                                                    const float* __restrict__ w1,
                                                    const float* __restrict__ w2,
                                                    float* __restrict__ Wt0,
                                                    float* __restrict__ Wt1,
                                                    float* __restrict__ Wt2,
                                                    float* __restrict__ stats)
{
#pragma clang fp contract(off)
    __shared__ __align__(16) unsigned char smem[131072 + 2560];
    const int blk = blockIdx.x;
    const int t = threadIdx.x;

    if (blk >= NB) {
        if (blk >= NB + NB * (NP / 64)) {
            // weight prep: zero stats, transpose weights to [kk][c]
            for (int i = t; i < 8192; i += 512) stats[i] = 0.f;
            for (int i = t; i < 64 * 67; i += 512) { int c = i / 67, kk = i % 67; Wt0[kk * 64 + c] = w0[i]; }
            for (int i = t; i < 64 * 64; i += 512) { int c = i >> 6, kk = i & 63; Wt1[kk * 64 + c] = w1[i]; }
            for (int i = t; i < 128 * 64; i += 512) { int c = i >> 6, kk = i & 63; Wt2[kk * 128 + c] = w2[i]; }
            return;
        }
        // points transpose (B,64,N) -> (B,N,64), 64x64 tile, 512 threads
        float (*tile)[65] = (float(*)[65])smem;
        const int tblk = blk - NB;
        const int b = tblk >> 7;
        const int n0 = (tblk & 127) << 6;
        const float* pb = points + (size_t)b * CD * NP;
        const int c = t & 63;
        const int dr = t >> 6;                 // 0..7
#pragma unroll
        for (int it = 0; it < 8; ++it) {
            int d = dr + it * 8;
            tile[d][c] = pb[(size_t)d * NP + n0 + c];
        }
        __syncthreads();
#pragma unroll
        for (int it = 0; it < 8; ++it) {
            int nn = dr + it * 8;
            pts_t[((size_t)b * NP + n0 + nn) * CD + c] = tile[c][nn];
        }
        return;
    }

    // ---- FPS path ----
    float4* s_p  = (float4*)smem;                          // 128 KB sorted pts (xyz + gid bits)
    int*    s_cnt = (int*)(smem + 131072);                 // 512 cell counts/offsets
    u64 (*s_wk)[8] = (u64(*)[8])(smem + 131072 + 2048);    // parity-dbuf leader keys (tagged)
    const int b = blk;
    const int lane = t & 63, wid = t >> 6;                 // 8 waves
    const float* xb = xyz + (size_t)b * 3 * NP;

    // -- one-time Morton counting sort --
    float lx[16], ly[16], lz[16];
    int   lcell[16];
    s_cnt[t < 512 ? t : 0] = 0;                            // t in [0,512): zero own slot
    if (t < 16) ((u64*)s_wk)[t] = (u64)1 << 26;            // stale-tag init: iter 0/1 expect tag 0
    __syncthreads();
#pragma unroll
    for (int j = 0; j < 16; ++j) {
        const int n = t + j * 512;                         // r0-coalesced load
        lx[j] = xb[n]; ly[j] = xb[NP + n]; lz[j] = xb[2 * NP + n];
        int ix = (int)(lx[j] * 8.f); ix = ix < 0 ? 0 : (ix > 7 ? 7 : ix);
        int iy = (int)(ly[j] * 8.f); iy = iy < 0 ? 0 : (iy > 7 ? 7 : iy);
        int iz = (int)(lz[j] * 8.f); iz = iz < 0 ? 0 : (iz > 7 ? 7 : iz);
        int sx = ((ix & 4) << 4) | ((ix & 2) << 2) | (ix & 1);
        int sy = ((iy & 4) << 4) | ((iy & 2) << 2) | (iy & 1);
        int sz = ((iz & 4) << 4) | ((iz & 2) << 2) | (iz & 1);
        lcell[j] = (sx << 2) | (sy << 1) | sz;             // Morton id, 0..511
        atomicAdd(&s_cnt[lcell[j]], 1);
    }
    __syncthreads();
    if (t == 0) {                                          // exclusive prefix (one-time ~2us)
        int run = 0;
        for (int c2 = 0; c2 < 512; ++c2) { int v = s_cnt[c2]; s_cnt[c2] = run; run += v; }
    }
    __syncthreads();
#pragma unroll
    for (int j = 0; j < 16; ++j) {
        int pos = atomicAdd(&s_cnt[lcell[j]], 1);
        s_p[pos] = make_float4(lx[j], ly[j], lz[j], __uint_as_float((unsigned)(t + j * 512)));
    }
    __syncthreads();
    // -- reload sorted chunk [16t, 16t+16): coords, key low-words, bbox --
    float px[16], py[16], pz[16], dv16[16];
    unsigned klo[16];
    float blx = 1e30f, bly = 1e30f, blz = 1e30f, bhx = -1e30f, bhy = -1e30f, bhz = -1e30f;
#pragma unroll
    for (int j = 0; j < 16; ++j) {
        float4 v = s_p[16 * t + j];
        px[j] = v.x; py[j] = v.y; pz[j] = v.z;
        unsigned g = __float_as_uint(v.w);                 // original gid (raw bits)
        klo[j] = ((8191u - g) << 13) | (unsigned)(16 * t + j);
        dv16[j] = 1e10f;
        blx = fminf(blx, v.x); bhx = fmaxf(bhx, v.x);
        bly = fminf(bly, v.y); bhy = fmaxf(bhy, v.y);
        blz = fminf(blz, v.z); bhz = fmaxf(bhz, v.z);
    }
    float cx = xb[0], cy = xb[NP], cz = xb[2 * NP];
    float cellmax = 1e10f;                                 // max dv over this thread's chunk
    u64 wkey = 0;                                          // lane63's cached wave key
    float hx0 = 0.f, hy0 = 0.f, hz0 = 0.f;                 // captured centroid of iteration i == t
    float hx1 = 0.f, hy1 = 0.f, hz1 = 0.f;                 // captured centroid of iteration i == t + 512
    __syncthreads();
    for (int i = 0; i < SP; ++i) {
        if (i == t)       { hx0 = cx; hy0 = cy; hz0 = cz; }
        if (i == t + 512) { hx1 = cx; hy1 = cy; hz1 = cz; }
        // conservative bound: skip iff dmin2(c,bbox)*0.999 >= cellmax (slack >> fp32 rounding)
        float ddx = fmaxf(fmaxf(blx - cx, cx - bhx), 0.f);
        float ddy = fmaxf(fmaxf(bly - cy, cy - bhy), 0.f);
        float ddz = fmaxf(fmaxf(blz - cz, cz - bhz), 0.f);
        float dmin = ddx * ddx + ddy * ddy;
        dmin = dmin + ddz * ddz;
        bool act = (dmin * 0.999f < cellmax);
        if (__ballot(act)) {
            // full update for this wave (EXACT fp32: same dag as r0 — sub, mul, (x2+y2)+z2, min)
            u64 bk = 0; float cm = 0.f;
#pragma unroll
            for (int j = 0; j < 16; ++j) {
                float dx = px[j] - cx;
                float dy = py[j] - cy;
                float dz = pz[j] - cz;
                float d = dx * dx + dy * dy;
                d = d + dz * dz;
                float nd = fminf(dv16[j], d);
                dv16[j] = nd;
                cm = fmaxf(cm, nd);
                u64 k = ((u64)__float_as_uint(nd) << 32) | klo[j];
                bk = u64max_f64(bk, k);        // exact u64 max (proof at u64max_f64)
            }
            cellmax = cm;
            // per-wave DPP max ladder; lane 63 ends with the wave max
            bk = dpp_max_step<0x111>(bk);      // row_shr:1
            bk = dpp_max_step<0x112>(bk);      // row_shr:2
            bk = dpp_max_step<0x114>(bk);      // row_shr:4
            bk = dpp_max_step<0x118>(bk);      // row_shr:8
            bk = dpp_max_step<0x142>(bk);      // row_bcast:15
            bk = dpp_max_step<0x143>(bk);      // row_bcast:31
            wkey = bk;
        }
        const int par = i & 1;
        const u64 tagbit = (u64)((unsigned)(i >> 1) & 1u) << 26;
        if (lane == 63)                        // publish tagged key (cached if wave skipped)
            *(volatile u64*)&s_wk[par][wid] = wkey | tagbit;
        // spin-exchange (replaces s_barrier): poll the 8 iter-i slots until all tags match.
        // Single read per pass; the passing read IS the reduce input (no re-read race).
        u64 rk;
        for (;;) {
            rk = *(volatile u64*)&s_wk[par][lane & 7];
            bool bad = ((rk >> 26) & 1ull) != (u64)((unsigned)(i >> 1) & 1u);
            if (!__ballot(bad)) break;
        }
        // cross-wave reduce: slots replicated twice per 16-lane row; shr 1,2,4 -> lane 7
        // holds max over slots 0..7 (pattern bit-exact-verified in r1); tag bit common to
        // all keys this iteration -> ordering unaffected.
        rk = dpp_max_step<0x111>(rk);
        rk = dpp_max_step<0x112>(rk);
        rk = dpp_max_step<0x114>(rk);
        const int wlo = __builtin_amdgcn_readlane((int)(unsigned)(rk & 0xffffffffull), 7);
        const int wpos = wlo & 0x1FFF;         // sorted position of the winner
        const float4 c = s_p[wpos];            // uniform broadcast ds_read_b128
        cx = c.x; cy = c.y; cz = c.z;
        // drift <=1 guaranteed by the tag protocol; parity slot i is overwritten only at i+2
    }
    // deferred outputs: thread t owns fps points t and t+512
    fps_pts[(b * SP + t) * 3 + 0] = hx0;
    fps_pts[(b * SP + t) * 3 + 1] = hy0;
    fps_pts[(b * SP + t) * 3 + 2] = hz0;
    fps_pts[(b * SP + t + 512) * 3 + 0] = hx1;
    fps_pts[(b * SP + t + 512) * 3 + 1] = hy1;
    fps_pts[(b * SP + t + 512) * 3 + 2] = hz1;
    out_nx[(size_t)b * 3 * SP + 0 * SP + t] = hx0;
    out_nx[(size_t)b * 3 * SP + 1 * SP + t] = hy0;
    out_nx[(size_t)b * 3 * SP + 2 * SP + t] = hz0;
    out_nx[(size_t)b * 3 * SP + 0 * SP + t + 512] = hx1;
    out_nx[(size_t)b * 3 * SP + 1 * SP + t + 512] = hy1;
    out_nx[(size_t)b * 3 * SP + 2 * SP + t + 512] = hz1;
}

// ---------------- ball query: one wave per query, ordered first-32 append (r0-verbatim) --------
__global__ __launch_bounds__(256) void k_ballquery(const float* __restrict__ xyz,
                                                   const float* __restrict__ fps_pts,
                                                   int* __restrict__ ball_idx)
{
    const int wib = threadIdx.x >> 6;
    const int lane = threadIdx.x & 63;
    const int wid = blockIdx.x * 4 + wib;          // b*SP + s
    const int b = wid >> 10;
    const float* xb = xyz + (size_t)b * 3 * NP;
    const float qx = fps_pts[wid * 3 + 0];
    const float qy = fps_pts[wid * 3 + 1];
    const float qz = fps_pts[wid * 3 + 2];
    __shared__ int s_list[4][KS];
    int* list = s_list[wib];
    const float r2 = (float)(0.2 * 0.2);           // 0.039999999f — matches python double->f32
    int found = 0;
    for (int base = 0; base < NP && found < KS; base += 64) {
        int n = base + lane;
        float dx = __fsub_rn(qx, xb[n]);
        float dy = __fsub_rn(qy, xb[NP + n]);
        float dz = __fsub_rn(qz, xb[2 * NP + n]);
        float d = __fadd_rn(__fadd_rn(__fmul_rn(dx, dx), __fmul_rn(dy, dy)), __fmul_rn(dz, dz));
        bool in = !(d > r2);
        unsigned long long m = __ballot(in);
        int before = __popcll(m & ((1ull << lane) - 1ull));
        int pos = found + before;
        if (in && pos < KS) list[pos] = n;
        found += __popcll(m);
    }
    int first = list[0];
    if (lane < KS) {
        int v = (lane < found) ? list[lane] : first;
        ball_idx[wid * KS + lane] = v;
    }
}

// ---------------- layer1: gather(feat 67) + GEMM(67->64) + stats (r0-verbatim) ----------------
__global__ __launch_bounds__(256) void k_layer1(const float* __restrict__ xyz,
                                                const float* __restrict__ pts_t,
                                                const float* __restrict__ fps_pts,
                                                const int* __restrict__ ball_idx,
                                                const float* __restrict__ Wt0,
                                                const float* __restrict__ bias0,
                                                float* __restrict__ h1,
                                                float* __restrict__ sum0,
                                                float* __restrict__ ssq0)
{
    __shared__ __align__(16) float Ft[67 * 128];
    __shared__ __align__(16) float Ws[67 * 64];
    __shared__ int   s_idx[128];
    __shared__ float s_q[4][3];
    const int t = threadIdx.x;
    const int m0 = blockIdx.x * 128;
    const int g0 = m0 >> 5;
    const int b = g0 >> 10;
    if (t < 128) s_idx[t] = ball_idx[g0 * KS + t];
    if (t < 12) ((float*)s_q)[t] = fps_pts[g0 * 3 + t];
    for (int i = t; i < 67 * 64; i += 256) Ws[i] = Wt0[i];
    __syncthreads();
    {
        const int r = t >> 1, half = t & 1;
        const int n = s_idx[r];
        const float* prow = pts_t + ((size_t)b * NP + n) * CD;
#pragma unroll
        for (int rep = 0; rep < 8; ++rep) {
            const int c4 = half * 4 + rep * 8;
            float4 v = *(const float4*)(prow + c4);
            Ft[(3 + c4 + 0) * 128 + r] = v.x;
            Ft[(3 + c4 + 1) * 128 + r] = v.y;
            Ft[(3 + c4 + 2) * 128 + r] = v.z;
            Ft[(3 + c4 + 3) * 128 + r] = v.w;
        }
        if (t < 128) {
            const int n2 = s_idx[t];
            const int g = t >> 5;
            const float* xb = xyz + (size_t)b * 3 * NP;
            Ft[0 * 128 + t] = __fsub_rn(xb[n2],          s_q[g][0]);
            Ft[1 * 128 + t] = __fsub_rn(xb[NP + n2],     s_q[g][1]);
            Ft[2 * 128 + t] = __fsub_rn(xb[2 * NP + n2], s_q[g][2]);
        }
    }
    __syncthreads();
    const int rg = t >> 3;   // 0..31 -> rows rg*4..+3
    const int cg = t & 7;    // 0..7  -> cols cg*8..+7
    float4 ba = *(const float4*)(bias0 + cg * 8);
    float4 bb = *(const float4*)(bias0 + cg * 8 + 4);
    float acc[4][8];
#pragma unroll
    for (int j = 0; j < 4; ++j) {
        acc[j][0] = ba.x; acc[j][1] = ba.y; acc[j][2] = ba.z; acc[j][3] = ba.w;
        acc[j][4] = bb.x; acc[j][5] = bb.y; acc[j][6] = bb.z; acc[j][7] = bb.w;
    }
    for (int kk = 0; kk < 67; ++kk) {
        float4 f = *(const float4*)(Ft + kk * 128 + rg * 4);
        float4 wa = *(const float4*)(Ws + kk * 64 + cg * 8);
        float4 wb = *(const float4*)(Ws + kk * 64 + cg * 8 + 4);
        float fv[4] = {f.x, f.y, f.z, f.w};
        float wv[8] = {wa.x, wa.y, wa.z, wa.w, wb.x, wb.y, wb.z, wb.w};
#pragma unroll
        for (int j = 0; j < 4; ++j)
#pragma unroll
            for (int i = 0; i < 8; ++i) acc[j][i] = fmaf(fv[j], wv[i], acc[j][i]);
    }
    float ls[8] = {0,0,0,0,0,0,0,0}, lq[8] = {0,0,0,0,0,0,0,0};
#pragma unroll
    for (int j = 0; j < 4; ++j) {
        int m = m0 + rg * 4 + j;
        float4 oa = {acc[j][0], acc[j][1], acc[j][2], acc[j][3]};
        float4 ob = {acc[j][4], acc[j][5], acc[j][6], acc[j][7]};
        *(float4*)(h1 + (size_t)m * 64 + cg * 8) = oa;
        *(float4*)(h1 + (size_t)m * 64 + cg * 8 + 4) = ob;
#pragma unroll
        for (int i = 0; i < 8; ++i) { float v = acc[j][i]; ls[i] += v; lq[i] += v * v; }
    }
    __syncthreads();           // Ft reuse for stats partials
    float* part_s = Ft;        // [32][64]
    float* part_q = Ft + 2048; // [32][64]
#pragma unroll
    for (int i = 0; i < 8; ++i) { part_s[rg * 64 + cg * 8 + i] = ls[i]; part_q[rg * 64 + cg * 8 + i] = lq[i]; }
    __syncthreads();
    if (t < 64) {
        float s = 0.f, q = 0.f;
#pragma unroll
        for (int rgi = 0; rgi < 32; ++rgi) { s += part_s[rgi * 64 + t]; q += part_q[rgi * 64 + t]; }
        int cp = blockIdx.x & (NCOPY - 1);
        atomicAdd(&sum0[cp * 64 + t], s);
        atomicAdd(&ssq0[cp * 64 + t], q);
    }
}

// ---------------- layer2: in-block BN finalize + BN1+ReLU on load + GEMM(64->64) + stats -------
__global__ __launch_bounds__(256) void k_layer2(const float* __restrict__ h1,
                                                const float* __restrict__ Wt1,
                                                const float* __restrict__ bias1,
                                                const float* __restrict__ csum,
                                                const float* __restrict__ cssq,
                                                const float* __restrict__ cg_,
                                                const float* __restrict__ cbeta,
                                                float* __restrict__ h2,
                                                float* __restrict__ sum1,
                                                float* __restrict__ ssq1)
{
    __shared__ __align__(16) float Ft[64 * 128];
    __shared__ __align__(16) float Ws[64 * 64];
    __shared__ float s_sc[64], s_sh[64];
    const int t = threadIdx.x;
    const int m0 = blockIdx.x * 128;
    for (int i = t; i < 64 * 64; i += 256) Ws[i] = Wt1[i];
    if (t < 64) bn_finalize_ch(csum, cssq, cg_, cbeta, 64, t, &s_sc[t], &s_sh[t]);
    __syncthreads();
    {
        const int tq = t >> 2, qq = t & 3;
#pragma unroll
        for (int rr = 0; rr < 2; ++rr) {
            const int r = rr * 64 + tq;
            const float* hrow = h1 + (size_t)(m0 + r) * 64;
#pragma unroll
            for (int rep = 0; rep < 4; ++rep) {
                const int c4 = qq * 4 + rep * 16;
                float4 v = *(const float4*)(hrow + c4);
                Ft[(c4 + 0) * 128 + r] = fmaxf(0.f, fmaf(v.x, s_sc[c4 + 0], s_sh[c4 + 0]));
                Ft[(c4 + 1) * 128 + r] = fmaxf(0.f, fmaf(v.y, s_sc[c4 + 1], s_sh[c4 + 1]));
                Ft[(c4 + 2) * 128 + r] = fmaxf(0.f, fmaf(v.z, s_sc[c4 + 2], s_sh[c4 + 2]));
                Ft[(c4 + 3) * 128 + r] = fmaxf(0.f, fmaf(v.w, s_sc[c4 + 3], s_sh[c4 + 3]));
            }
        }
    }
    __syncthreads();
    const int rg = t >> 3;
    const int cg = t & 7;
    float4 ba = *(const float4*)(bias1 + cg * 8);
    float4 bb = *(const float4*)(bias1 + cg * 8 + 4);
    float acc[4][8];
#pragma unroll
    for (int j = 0; j < 4; ++j) {
        acc[j][0] = ba.x; acc[j][1] = ba.y; acc[j][2] = ba.z; acc[j][3] = ba.w;
        acc[j][4] = bb.x; acc[j][5] = bb.y; acc[j][6] = bb.z; acc[j][7] = bb.w;
    }
    for (int kk = 0; kk < 64; ++kk) {
        float4 f = *(const float4*)(Ft + kk * 128 + rg * 4);
        float4 wa = *(const float4*)(Ws + kk * 64 + cg * 8);
        float4 wb = *(const float4*)(Ws + kk * 64 + cg * 8 + 4);
        float fv[4] = {f.x, f.y, f.z, f.w};
        float wv[8] = {wa.x, wa.y, wa.z, wa.w, wb.x, wb.y, wb.z, wb.w};
#pragma unroll
        for (int j = 0; j < 4; ++j)
#pragma unroll
            for (int i = 0; i < 8; ++i) acc[j][i] = fmaf(fv[j], wv[i], acc[j][i]);
    }
    float ls[8] = {0,0,0,0,0,0,0,0}, lq[8] = {0,0,0,0,0,0,0,0};
#pragma unroll
    for (int j = 0; j < 4; ++j) {
        int m = m0 + rg * 4 + j;
        float4 oa = {acc[j][0], acc[j][1], acc[j][2], acc[j][3]};
        float4 ob = {acc[j][4], acc[j][5], acc[j][6], acc[j][7]};
        *(float4*)(h2 + (size_t)m * 64 + cg * 8) = oa;
        *(float4*)(h2 + (size_t)m * 64 + cg * 8 + 4) = ob;
#pragma unroll
        for (int i = 0; i < 8; ++i) { float v = acc[j][i]; ls[i] += v; lq[i] += v * v; }
    }
    __syncthreads();
    float* part_s = Ft;
    float* part_q = Ft + 2048;
#pragma unroll
    for (int i = 0; i < 8; ++i) { part_s[rg * 64 + cg * 8 + i] = ls[i]; part_q[rg * 64 + cg * 8 + i] = lq[i]; }
    __syncthreads();
    if (t < 64) {
        float s = 0.f, q = 0.f;
#pragma unroll
        for (int rgi = 0; rgi < 32; ++rgi) { s += part_s[rgi * 64 + t]; q += part_q[rgi * 64 + t]; }
        int cp = blockIdx.x & (NCOPY - 1);
        atomicAdd(&sum1[cp * 64 + t], s);
        atomicAdd(&ssq1[cp * 64 + t], q);
    }
}

// ---------------- layer3: in-block BN finalize + BN2+ReLU + GEMM(64->128) + stats + max/min ----
// Pooling trick: max_k relu(a*h+b) == relu(a*max_k h + b) for a>=0 (min_k for a<0),
// exact in fp32 by monotonicity of fmaf/relu. So h3 is never materialized.
__global__ __launch_bounds__(256) void k_layer3(const float* __restrict__ h2,
                                                const float* __restrict__ Wt2,
                                                const float* __restrict__ bias2,
                                                const float* __restrict__ csum,
                                                const float* __restrict__ cssq,
                                                const float* __restrict__ cg_,
                                                const float* __restrict__ cbeta,
                                                float* __restrict__ sum2,
                                                float* __restrict__ ssq2,
                                                float* __restrict__ gmax,
                                                float* __restrict__ gmin)
{
    __shared__ __align__(16) float Ft[64 * 128];
    __shared__ __align__(16) float Ws[64 * 128];
    __shared__ float s_sc[64], s_sh[64];
    const int t = threadIdx.x;
    const int m0 = blockIdx.x * 128;
    for (int i = t; i < 64 * 128; i += 256) Ws[i] = Wt2[i];
    if (t < 64) bn_finalize_ch(csum, cssq, cg_, cbeta, 64, t, &s_sc[t], &s_sh[t]);
    __syncthreads();
    {
        const int tq = t >> 2, qq = t & 3;
#pragma unroll
        for (int rr = 0; rr < 2; ++rr) {
            const int r = rr * 64 + tq;
            const float* hrow = h2 + (size_t)(m0 + r) * 64;
#pragma unroll
            for (int rep = 0; rep < 4; ++rep) {
                const int c4 = qq * 4 + rep * 16;
                float4 v = *(const float4*)(hrow + c4);
                Ft[(c4 + 0) * 128 + r] = fmaxf(0.f, fmaf(v.x, s_sc[c4 + 0], s_sh[c4 + 0]));
                Ft[(c4 + 1) * 128 + r] = fmaxf(0.f, fmaf(v.y, s_sc[c4 + 1], s_sh[c4 + 1]));
                Ft[(c4 + 2) * 128 + r] = fmaxf(0.f, fmaf(v.z, s_sc[c4 + 2], s_sh[c4 + 2]));
                Ft[(c4 + 3) * 128 + r] = fmaxf(0.f, fmaf(v.w, s_sc[c4 + 3], s_sh[c4 + 3]));
            }
        }
    }
    __syncthreads();
    const int rg = t >> 4;  // 0..15 -> rows rg*8..+7  (all within group rg>>2)
    const int cg = t & 15;  // 0..15 -> cols cg*8..+7
    float4 ba = *(const float4*)(bias2 + cg * 8);
    float4 bb = *(const float4*)(bias2 + cg * 8 + 4);
    float acc[8][8];
#pragma unroll
    for (int j = 0; j < 8; ++j) {
        acc[j][0] = ba.x; acc[j][1] = ba.y; acc[j][2] = ba.z; acc[j][3] = ba.w;
        acc[j][4] = bb.x; acc[j][5] = bb.y; acc[j][6] = bb.z; acc[j][7] = bb.w;
    }
    for (int kk = 0; kk < 64; ++kk) {
        float4 fa = *(const float4*)(Ft + kk * 128 + rg * 8);
        float4 fb = *(const float4*)(Ft + kk * 128 + rg * 8 + 4);
        float4 wa = *(const float4*)(Ws + kk * 128 + cg * 8);
        float4 wb = *(const float4*)(Ws + kk * 128 + cg * 8 + 4);
        float fv[8] = {fa.x, fa.y, fa.z, fa.w, fb.x, fb.y, fb.z, fb.w};
        float wv[8] = {wa.x, wa.y, wa.z, wa.w, wb.x, wb.y, wb.z, wb.w};
#pragma unroll
        for (int j = 0; j < 8; ++j)
#pragma unroll
            for (int i = 0; i < 8; ++i) acc[j][i] = fmaf(fv[j], wv[i], acc[j][i]);
    }
    float ls[8] = {0,0,0,0,0,0,0,0}, lq[8] = {0,0,0,0,0,0,0,0};
    float pm[8], pn[8];
#pragma unroll
    for (int i = 0; i < 8; ++i) { pm[i] = acc[0][i]; pn[i] = acc[0][i]; }
#pragma unroll
    for (int j = 0; j < 8; ++j)
#pragma unroll
        for (int i = 0; i < 8; ++i) {
            float v = acc[j][i];
            ls[i] += v; lq[i] += v * v;
            pm[i] = fmaxf(pm[i], v); pn[i] = fminf(pn[i], v);
        }
    __syncthreads();
    float* part_s = Ft;        // [16][128]
    float* part_q = Ft + 2048; // [16][128]
    float* part_m = Ft + 4096; // [16][128]
    float* part_n = Ft + 6144; // [16][128]
#pragma unroll
    for (int i = 0; i < 8; ++i) {
        part_s[rg * 128 + cg * 8 + i] = ls[i];
        part_q[rg * 128 + cg * 8 + i] = lq[i];
        part_m[rg * 128 + cg * 8 + i] = pm[i];
        part_n[rg * 128 + cg * 8 + i] = pn[i];
    }
    __syncthreads();
    if (t < 128) {
        float s = 0.f, q = 0.f;
#pragma unroll
        for (int rgi = 0; rgi < 16; ++rgi) { s += part_s[rgi * 128 + t]; q += part_q[rgi * 128 + t]; }
        int cp = blockIdx.x & (NCOPY - 1);
        atomicAdd(&sum2[cp * 128 + t], s);
        atomicAdd(&ssq2[cp * 128 + t], q);
    }
    for (int e = t; e < 512; e += 256) {
        int g = e >> 7, c = e & 127;
        float M = part_m[(g * 4 + 0) * 128 + c];
        M = fmaxf(M, part_m[(g * 4 + 1) * 128 + c]);
        M = fmaxf(M, part_m[(g * 4 + 2) * 128 + c]);
        M = fmaxf(M, part_m[(g * 4 + 3) * 128 + c]);
        float N = part_n[(g * 4 + 0) * 128 + c];
        N = fminf(N, part_n[(g * 4 + 1) * 128 + c]);
        N = fminf(N, part_n[(g * 4 + 2) * 128 + c]);
        N = fminf(N, part_n[(g * 4 + 3) * 128 + c]);
        int grp = blockIdx.x * 4 + g;              // == b*1024 + s
        gmax[(size_t)grp * 128 + c] = M;
        gmin[(size_t)grp * 128 + c] = N;
    }
}

// ---------------- pool2: in-block BN finalize (1 channel) + BN3+ReLU on pooled max/min --------
// c = (blockIdx>>2)&127 is BLOCK-UNIFORM (256 consecutive idx never cross a 1024 boundary),
// so one thread computes the single needed channel's scale/shift (exact k_finalize dag).
__global__ __launch_bounds__(256) void k_pool2(const float* __restrict__ gmax,
                                               const float* __restrict__ gmin,
                                               const float* __restrict__ csum,
                                               const float* __restrict__ cssq,
                                               const float* __restrict__ cg_,
                                               const float* __restrict__ cbeta,
                                               float* __restrict__ outp)
{
    __shared__ float sh_a, sh_b;
    const int t = threadIdx.x;
    if (t == 0) {
        int c = (blockIdx.x >> 2) & 127;
        float a, sh;
        bn_finalize_ch(csum, cssq, cg_, cbeta, 128, c, &a, &sh);
        sh_a = a; sh_b = sh;
    }
    __syncthreads();
    int idx = blockIdx.x * 256 + t;                // 1,048,576 = 8*128*1024
    int b = idx >> 17;
    int c = (idx >> 10) & 127;
    int s = idx & 1023;
    int grp = (b << 10) + s;
    float a = sh_a, sh = sh_b;
    float m = (a >= 0.f) ? gmax[(size_t)grp * 128 + c] : gmin[(size_t)grp * 128 + c];
    outp[idx] = fmaxf(0.f, fmaf(m, a, sh));
}

extern "C" void kernel_launch(void* const* d_in, const int* in_sizes, int n_in,
                              void* d_out, int out_size, void* d_ws, size_t ws_size,
                              hipStream_t stream)
{
    const float* xyz    = (const float*)d_in[0];
    const float* points = (const float*)d_in[1];
    const float* w0 = (const float*)d_in[2];
    const float* b0 = (const float*)d_in[3];
    const float* gm0 = (const float*)d_in[4];
    const float* bt0 = (const float*)d_in[5];
    const float* w1 = (const float*)d_in[6];
    const float* b1 = (const float*)d_in[7];
    const float* gm1 = (const float*)d_in[8];
    const float* bt1 = (const float*)d_in[9];
    const float* w2 = (const float*)d_in[10];
    const float* b2 = (const float*)d_in[11];
    const float* gm2 = (const float*)d_in[12];
    const float* bt2 = (const float*)d_in[13];
    float* out = (float*)d_out;

    char* p = (char*)d_ws;
    auto alloc = [&](size_t nbytes) -> void* {
        void* r = (void*)p;
        p += (nbytes + 255) & ~(size_t)255;
        return r;
    };
    float* fps_pts = (float*)alloc((size_t)NB * SP * 3 * 4);
    int*   ball_idx = (int*)alloc((size_t)NB * SP * KS * 4);
    float* pts_t = (float*)alloc((size_t)NB * NP * CD * 4);
    float* h1 = (float*)alloc((size_t)MROWS * 64 * 4);
    float* h2 = (float*)alloc((size_t)MROWS * 64 * 4);
    float* gmax = (float*)alloc((size_t)NB * SP * 128 * 4);
    float* gmin = (float*)alloc((size_t)NB * SP * 128 * 4);
    float* Wt0 = (float*)alloc(67 * 64 * 4);
    float* Wt1 = (float*)alloc(64 * 64 * 4);
    float* Wt2 = (float*)alloc(64 * 128 * 4);
    float* stats = (float*)alloc(8192 * 4);

    float* sum0 = stats;
    float* ssq0 = stats + 16 * 64;
    float* sum1 = stats + 2 * 16 * 64;
    float* ssq1 = stats + 3 * 16 * 64;
    float* sum2 = stats + 4 * 16 * 64;
    float* ssq2 = sum2 + 16 * 128;

    k_fps_pre<<<NB + NB * (NP / 64) + 1, 512, 0, stream>>>(
        xyz, fps_pts, out, points, pts_t, w0, w1, w2, Wt0, Wt1, Wt2, stats);
    k_ballquery<<<(NB * SP) / 4, 256, 0, stream>>>(xyz, fps_pts, ball_idx);
    k_layer1<<<MROWS / 128, 256, 0, stream>>>(xyz, pts_t, fps_pts, ball_idx, Wt0, b0, h1, sum0, ssq0);
    k_layer2<<<MROWS / 128, 256, 0, stream>>>(h1, Wt1, b1, sum0, ssq0, gm0, bt0, h2, sum1, ssq1);
    k_layer3<<<MROWS / 128, 256, 0, stream>>>(h2, Wt2, b2, sum1, ssq1, gm1, bt1, sum2, ssq2, gmax, gmin);
    k_pool2<<<(NB * SP * 128) / 256, 256, 0, stream>>>(gmax, gmin, sum2, ssq2, gm2, bt2, out + 24576);
}